// Round 2
// baseline (8995.634 us; speedup 1.0000x reference)
//
#include <hip/hip_runtime.h>
#include <math.h>

#define T_LEN 4096
#define FLATD 512
#define HDD 256
#define FEATD 20
#define NCAND 30000
#define HIDD 512
#define KSEL 1638
#define CANT 40
#define MENTD 1300
#define NPAIR (KSEL*CANT)
#define CH_MS 7500
#define CH_P 16380
#define BM 128
#define BN 64
#define BK 16
#define FLAG_RELU 1
#define FLAG_ACC 2
#define NEG_INF (-__builtin_inff())

__device__ __forceinline__ unsigned ordf(float f){
  unsigned u = __float_as_uint(f);
  return (u & 0x80000000u) ? ~u : (u | 0x80000000u);
}
__device__ __forceinline__ float unordf(unsigned u){
  return __uint_as_float((u & 0x80000000u) ? (u ^ 0x80000000u) : ~u);
}

// ---------------- head scores: hs[t] = flat[t] . w + b ----------------
__global__ __launch_bounds__(256) void k_head(const float* __restrict__ flat,
    const float* __restrict__ w, const float* __restrict__ b, float* __restrict__ hs)
{
  int lane = threadIdx.x & 63, wid = threadIdx.x >> 6;
  int row = blockIdx.x*4 + wid;
  if (row >= T_LEN) return;
  const float* x = flat + (size_t)row*FLATD;
  float s = 0.f;
  for (int j = lane; j < FLATD; j += 64) s += x[j]*w[j];
  #pragma unroll
  for (int o = 32; o; o >>= 1) s += __shfl_down(s, o, 64);
  if (lane == 0) hs[row] = s + b[0];
}

// ------------- per-candidate softmax head embedding (30000 x 256) -------------
__global__ __launch_bounds__(256) void k_cand(const float* __restrict__ hs,
    const float* __restrict__ hdoc, const int* __restrict__ starts, const int* __restrict__ ends,
    float* __restrict__ hemb)
{
  int n = blockIdx.x;
  int s = starts[n], e = ends[n];
  int width = e - s + 1;   // in [1,20]
  __shared__ float attn[20];
  if (threadIdx.x == 0){
    float g[20]; float m = NEG_INF;
    for (int w2 = 0; w2 < width; ++w2){ g[w2] = hs[s + w2]; m = fmaxf(m, g[w2]); }
    float sum = 0.f;
    for (int w2 = 0; w2 < width; ++w2){ g[w2] = expf(g[w2] - m); sum += g[w2]; }
    float inv = 1.f/sum;
    for (int w2 = 0; w2 < 20; ++w2) attn[w2] = (w2 < width) ? g[w2]*inv : 0.f;
  }
  __syncthreads();
  int d = threadIdx.x;
  if (d < HDD){
    float acc = 0.f;
    for (int w2 = 0; w2 < width; ++w2) acc += attn[w2]*hdoc[(size_t)(s + w2)*HDD + d];
    hemb[(size_t)n*HDD + d] = acc;
  }
}

// ---------------- generic f32 tiled GEMM: C = [relu]([acc +] A@B + bias) ----------------
__global__ __launch_bounds__(256) void k_gemm(const float* __restrict__ A, int M, int K,
    const float* __restrict__ B, int N, const float* __restrict__ bias,
    float* __restrict__ C, int flags)
{
  __shared__ float As[BK][BM+4];
  __shared__ float Bs[BK][BN+4];
  int row0 = blockIdx.y*BM, col0 = blockIdx.x*BN;
  int tid = threadIdx.x;
  int tx = tid & 15, ty = tid >> 4;
  float acc[8][4] = {};
  int a_k = tid & 15, a_r = tid >> 4;
  int b_c = tid & 63, b_k = tid >> 6;
  int nkt = (K + BK - 1)/BK;
  for (int kt = 0; kt < nkt; ++kt){
    int k0 = kt*BK;
    #pragma unroll
    for (int it = 0; it < 8; ++it){
      int r = a_r + 16*it; int gr = row0 + r, gk = k0 + a_k;
      As[a_k][r] = (gr < M && gk < K) ? A[(size_t)gr*K + gk] : 0.f;
    }
    #pragma unroll
    for (int it = 0; it < 4; ++it){
      int k = b_k + 4*it; int gk = k0 + k, gc = col0 + b_c;
      Bs[k][b_c] = (gk < K && gc < N) ? B[(size_t)gk*N + gc] : 0.f;
    }
    __syncthreads();
    #pragma unroll
    for (int kk = 0; kk < BK; ++kk){
      float a[8], b[4];
      #pragma unroll
      for (int i = 0; i < 8; ++i) a[i] = As[kk][ty*8 + i];
      #pragma unroll
      for (int j = 0; j < 4; ++j) b[j] = Bs[kk][tx*4 + j];
      #pragma unroll
      for (int i = 0; i < 8; ++i)
        #pragma unroll
        for (int j = 0; j < 4; ++j) acc[i][j] = fmaf(a[i], b[j], acc[i][j]);
    }
    __syncthreads();
  }
  #pragma unroll
  for (int i = 0; i < 8; ++i){
    int gr = row0 + ty*8 + i; if (gr >= M) continue;
    #pragma unroll
    for (int j = 0; j < 4; ++j){
      int gc = col0 + tx*4 + j; if (gc >= N) continue;
      float v = acc[i][j];
      if (bias) v += bias[gc];
      if (flags & FLAG_ACC) v += C[(size_t)gr*N + gc];
      if (flags & FLAG_RELU) v = fmaxf(v, 0.f);
      C[(size_t)gr*N + gc] = v;
    }
  }
}

// ------- mention-scorer layer1 with on-the-fly candidate feature rows -------
__global__ __launch_bounds__(256) void k_gemm_ms1(int n0, int Mc,
    const float* __restrict__ flat, const float* __restrict__ wemb, const float* __restrict__ hemb,
    const int* __restrict__ starts, const int* __restrict__ ends,
    const float* __restrict__ B, const float* __restrict__ bias, float* __restrict__ C)
{
  __shared__ float As[BK][BM+4];
  __shared__ float Bs[BK][BN+4];
  __shared__ int rs[BM], re[BM];
  int row0 = blockIdx.y*BM, col0 = blockIdx.x*BN;
  int tid = threadIdx.x;
  if (tid < BM){
    int r = row0 + tid;
    int n = n0 + (r < Mc ? r : 0);
    rs[tid] = starts[n]; re[tid] = ends[n];
  }
  __syncthreads();
  int tx = tid & 15, ty = tid >> 4;
  float acc[8][4] = {};
  int a_k = tid & 15, a_r = tid >> 4;
  int b_c = tid & 63, b_k = tid >> 6;
  int nkt = (MENTD + BK - 1)/BK;
  for (int kt = 0; kt < nkt; ++kt){
    int k0 = kt*BK;
    #pragma unroll
    for (int it = 0; it < 8; ++it){
      int r = a_r + 16*it; int row = row0 + r; int gk = k0 + a_k;
      float v = 0.f;
      if (row < Mc && gk < MENTD){
        int s = rs[r], e = re[r];
        if (gk < 512)       v = flat[(size_t)s*FLATD + gk];
        else if (gk < 1024) v = flat[(size_t)e*FLATD + gk - 512];
        else if (gk < 1044) v = wemb[(e - s)*FEATD + gk - 1024];
        else                v = hemb[(size_t)(n0 + row)*HDD + gk - 1044];
      }
      As[a_k][r] = v;
    }
    #pragma unroll
    for (int it = 0; it < 4; ++it){
      int k = b_k + 4*it; int gk = k0 + k, gc = col0 + b_c;
      Bs[k][b_c] = (gk < MENTD) ? B[(size_t)gk*HIDD + gc] : 0.f;
    }
    __syncthreads();
    #pragma unroll
    for (int kk = 0; kk < BK; ++kk){
      float a[8], b[4];
      #pragma unroll
      for (int i = 0; i < 8; ++i) a[i] = As[kk][ty*8 + i];
      #pragma unroll
      for (int j = 0; j < 4; ++j) b[j] = Bs[kk][tx*4 + j];
      #pragma unroll
      for (int i = 0; i < 8; ++i)
        #pragma unroll
        for (int j = 0; j < 4; ++j) acc[i][j] = fmaf(a[i], b[j], acc[i][j]);
    }
    __syncthreads();
  }
  #pragma unroll
  for (int i = 0; i < 8; ++i){
    int gr = row0 + ty*8 + i; if (gr >= Mc) continue;
    #pragma unroll
    for (int j = 0; j < 4; ++j){
      int gc = col0 + tx*4 + j;
      float v = fmaxf(acc[i][j] + bias[gc], 0.f);
      C[(size_t)gr*HIDD + gc] = v;
    }
  }
}

// ---------------- row dot: out[r] = X[r](512) . w3 + b3 (+ add[r]) ----------------
__global__ __launch_bounds__(256) void k_rowdot(const float* __restrict__ X, int M,
    const float* __restrict__ w3, const float* __restrict__ b3,
    const float* __restrict__ add, float* __restrict__ out)
{
  int lane = threadIdx.x & 63, wid = threadIdx.x >> 6;
  int r = blockIdx.x*4 + wid;
  if (r >= M) return;
  const float* x = X + (size_t)r*HIDD;
  float s = 0.f;
  for (int j = lane; j < HIDD; j += 64) s += x[j]*w3[j];
  #pragma unroll
  for (int o = 32; o; o >>= 1) s += __shfl_down(s, o, 64);
  if (lane == 0){
    float v = s + b3[0];
    if (add) v += add[r];
    out[r] = v;
  }
}

// ---------------- exact top-K selection + JAX-tie ordering (single block) ----------------
__device__ __forceinline__ void bitonic2048(unsigned long long* keys, unsigned* pay, int tid){
  for (unsigned k2 = 2; k2 <= 2048; k2 <<= 1)
    for (unsigned j = k2 >> 1; j > 0; j >>= 1){
      __syncthreads();
      unsigned i = 2u*tid - (tid & (j-1));
      unsigned ixj = i + j;
      bool up = ((i & k2) == 0);
      unsigned long long a = keys[i], b = keys[ixj];
      if ((a > b) == up){
        keys[i] = b; keys[ixj] = a;
        unsigned pa = pay[i]; pay[i] = pay[ixj]; pay[ixj] = pa;
      }
    }
  __syncthreads();
}

__global__ __launch_bounds__(1024) void k_sel(const float* __restrict__ scores,
    const int* __restrict__ starts, const int* __restrict__ ends, int* __restrict__ top_idx)
{
  __shared__ unsigned cnt[2048];
  __shared__ unsigned long long keys[2048];
  __shared__ unsigned pay[2048];
  __shared__ int sel[KSEL];
  __shared__ unsigned eq[1024];
  __shared__ unsigned meta[8];
  int tid = threadIdx.x;
  // pass 1: top 11 bits
  for (int i = tid; i < 2048; i += 1024) cnt[i] = 0;
  __syncthreads();
  for (int n = tid; n < NCAND; n += 1024) atomicAdd(&cnt[ordf(scores[n]) >> 21], 1u);
  __syncthreads();
  if (tid == 0){
    unsigned greater = 0; int b = 2047;
    for (;; --b){ if (greater + cnt[b] >= KSEL) break; greater += cnt[b]; }
    meta[0] = (unsigned)b; meta[1] = KSEL - greater;
  }
  __syncthreads();
  unsigned bin1 = meta[0], r1 = meta[1];
  // pass 2: next 11 bits
  for (int i = tid; i < 2048; i += 1024) cnt[i] = 0;
  __syncthreads();
  for (int n = tid; n < NCAND; n += 1024){
    unsigned u = ordf(scores[n]);
    if ((u >> 21) == bin1) atomicAdd(&cnt[(u >> 10) & 0x7FFu], 1u);
  }
  __syncthreads();
  if (tid == 0){
    unsigned greater = 0; int b = 2047;
    for (;; --b){ if (greater + cnt[b] >= r1) break; greater += cnt[b]; }
    meta[0] = (bin1 << 11) | (unsigned)b; meta[1] = r1 - greater;
  }
  __syncthreads();
  unsigned pre2 = meta[0], r2 = meta[1];
  // pass 3: low 10 bits -> exact kth key
  for (int i = tid; i < 2048; i += 1024) cnt[i] = 0;
  __syncthreads();
  for (int n = tid; n < NCAND; n += 1024){
    unsigned u = ordf(scores[n]);
    if ((u >> 10) == pre2) atomicAdd(&cnt[u & 0x3FFu], 1u);
  }
  __syncthreads();
  if (tid == 0){
    unsigned greater = 0; int b = 1023;
    for (;; --b){ if (greater + cnt[b] >= r2) break; greater += cnt[b]; }
    meta[2] = (pre2 << 10) | (unsigned)b;
    meta[4] = r2 - greater;   // E: # of kth-equal to take (lowest indices)
    meta[5] = 0; meta[6] = 0;
  }
  __syncthreads();
  unsigned kth = meta[2], E = meta[4];
  // compaction
  for (int n = tid; n < NCAND; n += 1024){
    unsigned u = ordf(scores[n]);
    if (u > kth){ unsigned p = atomicAdd(&meta[6], 1u); sel[p] = n; }
    else if (u == kth){ unsigned p = atomicAdd(&meta[5], 1u); if (p < 1024) eq[p] = (unsigned)n; }
  }
  __syncthreads();
  unsigned G = meta[6];
  unsigned neq = meta[5] < 1024u ? meta[5] : 1024u;
  if (tid >= (int)neq) eq[tid] = 0xFFFFFFFFu;
  __syncthreads();
  // sort eq ascending (bitonic over 1024, 512 pairs)
  for (unsigned k2 = 2; k2 <= 1024; k2 <<= 1)
    for (unsigned j = k2 >> 1; j > 0; j >>= 1){
      __syncthreads();
      if (tid < 512){
        unsigned i = 2u*tid - (tid & (j-1));
        unsigned ixj = i + j;
        bool up = ((i & k2) == 0);
        unsigned a = eq[i], b = eq[ixj];
        if ((a > b) == up){ eq[i] = b; eq[ixj] = a; }
      }
    }
  __syncthreads();
  if (tid < (int)E) sel[G + tid] = (int)eq[tid];
  __syncthreads();
  // sort by (-score, idx) -> top_k rank order
  for (int t = tid; t < 2048; t += 1024){
    if (t < KSEL){
      int n = sel[t];
      keys[t] = ((unsigned long long)(~ordf(scores[n])) << 32) | (unsigned)n;
      pay[t] = (unsigned)n;
    } else { keys[t] = ~0ULL; pay[t] = 0u; }
  }
  __syncthreads();
  bitonic2048(keys, pay, tid);
  // sort by (ment_pos, rank) -> final order (stable argsort semantics)
  int elast = ends[NCAND-1];
  __syncthreads();
  for (int t = tid; t < 2048; t += 1024){
    if (t < KSEL){
      int n = (int)pay[t];
      unsigned mp = (unsigned)(starts[n]*elast + ends[n]);
      keys[t] = ((unsigned long long)mp << 11) | (unsigned)t;
    } else keys[t] = ~0ULL;
  }
  __syncthreads();
  bitonic2048(keys, pay, tid);
  for (int t = tid; t < KSEL; t += 1024) top_idx[t] = (int)pay[t];
}

// ---------------- gather mention rows / scores / speakers ----------------
__global__ __launch_bounds__(256) void k_gather(const int* __restrict__ top_idx,
    const float* __restrict__ flat, const float* __restrict__ wemb, const float* __restrict__ hemb,
    const int* __restrict__ starts, const int* __restrict__ ends,
    const float* __restrict__ cscores, const int* __restrict__ spk_ids,
    float* __restrict__ ment, float* __restrict__ mscore, int* __restrict__ mspk)
{
  int k = blockIdx.x; int n = top_idx[k];
  int s = starts[n], e = ends[n];
  for (int f = threadIdx.x; f < MENTD; f += 256){
    float v;
    if (f < 512)       v = flat[(size_t)s*FLATD + f];
    else if (f < 1024) v = flat[(size_t)e*FLATD + f - 512];
    else if (f < 1044) v = wemb[(e - s)*FEATD + f - 1024];
    else               v = hemb[(size_t)n*HDD + f - 1044];
    ment[(size_t)k*MENTD + f] = v;
  }
  if (threadIdx.x == 0){ mscore[k] = cscores[n]; mspk[k] = spk_ids[s]; }
}

// ---------------- NT GEMM: fast[i][j] = src[i].ment[j] + ms[i]+ms[j], mask j>=i ----------------
__global__ __launch_bounds__(256) void k_nt(const float* __restrict__ A,
    const float* __restrict__ Bt, const float* __restrict__ msc, float* __restrict__ C)
{
  __shared__ float As[BK][BM+4];
  __shared__ float Bs[BK][BN+4];
  int row0 = blockIdx.y*BM, col0 = blockIdx.x*BN;
  int tid = threadIdx.x;
  int tx = tid & 15, ty = tid >> 4;
  float acc[8][4] = {};
  int a_k = tid & 15, a_r = tid >> 4;
  int b_k = tid & 15, b_c = tid >> 4;
  int nkt = (MENTD + BK - 1)/BK;
  for (int kt = 0; kt < nkt; ++kt){
    int k0 = kt*BK;
    #pragma unroll
    for (int it = 0; it < 8; ++it){
      int r = a_r + 16*it; int gr = row0 + r, gk = k0 + a_k;
      As[a_k][r] = (gr < KSEL && gk < MENTD) ? A[(size_t)gr*MENTD + gk] : 0.f;
    }
    #pragma unroll
    for (int it = 0; it < 4; ++it){
      int c = b_c + 16*it; int gc = col0 + c, gk = k0 + b_k;
      Bs[b_k][c] = (gc < KSEL && gk < MENTD) ? Bt[(size_t)gc*MENTD + gk] : 0.f;
    }
    __syncthreads();
    #pragma unroll
    for (int kk = 0; kk < BK; ++kk){
      float a[8], b[4];
      #pragma unroll
      for (int i = 0; i < 8; ++i) a[i] = As[kk][ty*8 + i];
      #pragma unroll
      for (int j = 0; j < 4; ++j) b[j] = Bs[kk][tx*4 + j];
      #pragma unroll
      for (int i = 0; i < 8; ++i)
        #pragma unroll
        for (int j = 0; j < 4; ++j) acc[i][j] = fmaf(a[i], b[j], acc[i][j]);
    }
    __syncthreads();
  }
  #pragma unroll
  for (int i = 0; i < 8; ++i){
    int gr = row0 + ty*8 + i; if (gr >= KSEL) continue;
    #pragma unroll
    for (int j = 0; j < 4; ++j){
      int gc = col0 + tx*4 + j; if (gc >= KSEL) continue;
      float v = acc[i][j] + msc[gr] + msc[gc];
      if (gc >= gr) v = NEG_INF;
      C[(size_t)gr*KSEL + gc] = v;
    }
  }
}

// ---------------- per-row top-40 with JAX tie semantics ----------------
__global__ __launch_bounds__(256) void k_f3(const float* __restrict__ fast,
    float* __restrict__ top_fast, int* __restrict__ antes)
{
  int i = blockIdx.x;
  __shared__ unsigned long long key[KSEL];
  __shared__ unsigned long long red[256];
  const float* row = fast + (size_t)i*KSEL;
  int nvalid = i < CANT ? i : CANT;
  for (int j = threadIdx.x; j < KSEL; j += 256)
    key[j] = (j < i) ? (((unsigned long long)ordf(row[j]) << 32) | (unsigned)(0xFFFFFFFFu - (unsigned)j)) : 0ULL;
  __syncthreads();
  for (int c = 0; c < nvalid; ++c){
    unsigned long long mx = 0ULL;
    for (int j = threadIdx.x; j < i; j += 256){ unsigned long long k2 = key[j]; if (k2 > mx) mx = k2; }
    red[threadIdx.x] = mx;
    __syncthreads();
    for (int s = 128; s; s >>= 1){
      if (threadIdx.x < s){ if (red[threadIdx.x+s] > red[threadIdx.x]) red[threadIdx.x] = red[threadIdx.x+s]; }
      __syncthreads();
    }
    unsigned long long best = red[0];
    if (threadIdx.x == 0){
      int j = (int)(0xFFFFFFFFu - (unsigned)(best & 0xFFFFFFFFu));
      top_fast[(size_t)i*CANT + c] = unordf((unsigned)(best >> 32));
      antes[(size_t)i*CANT + c] = j;
      key[j] = 0ULL;
    }
    __syncthreads();
  }
  for (int c = nvalid + threadIdx.x; c < CANT; c += 256){
    top_fast[(size_t)i*CANT + c] = NEG_INF;
    antes[(size_t)i*CANT + c] = c;      // lowest-index -inf ties
  }
}

// ------- small precomputes: spk/dist/genre rows projected through ss_w1 -------
__global__ __launch_bounds__(256) void k_dsmall(const float* __restrict__ ss_w1,
    const float* __restrict__ ss_b1, const float* __restrict__ spk_emb,
    const float* __restrict__ gen_emb, const float* __restrict__ dist_emb,
    const int* __restrict__ genre_id, float* __restrict__ Svec, float* __restrict__ Dvec,
    float* __restrict__ cvec)
{
  int r = blockIdx.x; // 0..1 spk, 2..10 dist, 11 genre+bias
  for (int h = threadIdx.x; h < HIDD; h += 256){
    const float* e; const float* wb; float acc;
    if (r < 2){ e = spk_emb + r*FEATD; wb = ss_w1 + (size_t)3900*HIDD; acc = 0.f; }
    else if (r < 11){ e = dist_emb + (r-2)*FEATD; wb = ss_w1 + (size_t)3940*HIDD; acc = 0.f; }
    else { e = gen_emb + genre_id[0]*FEATD; wb = ss_w1 + (size_t)3920*HIDD; acc = ss_b1[h]; }
    for (int f = 0; f < FEATD; ++f) acc += e[f]*wb[(size_t)f*HIDD + h];
    if (r < 2) Svec[r*HIDD + h] = acc;
    else if (r < 11) Dvec[(r-2)*HIDD + h] = acc;
    else cvec[h] = acc;
  }
}

// ------- pair layer1: h1 = relu((me_i*me_j)@Wprod + A_me[i] + A_an[j] + S + D + cvec) -------
__global__ __launch_bounds__(256) void k_d1(int p0, int Mc,
    const float* __restrict__ ment, const int* __restrict__ antes, const int* __restrict__ mspk,
    const float* __restrict__ Bw, const float* __restrict__ A_me, const float* __restrict__ A_an,
    const float* __restrict__ Svec, const float* __restrict__ Dvec, const float* __restrict__ cvec,
    float* __restrict__ H1)
{
  __shared__ float As[BK][BM+4];
  __shared__ float Bs[BK][BN+4];
  __shared__ int ri[BM], rj[BM], rsame[BM], rbin[BM];
  int row0 = blockIdx.y*BM, col0 = blockIdx.x*BN;
  int tid = threadIdx.x;
  if (tid < BM){
    int r = row0 + tid;
    int p = p0 + (r < Mc ? r : 0);
    int i = p / CANT;
    int j = antes[p];
    ri[tid] = i; rj[tid] = j;
    rsame[tid] = (mspk[i] == mspk[j]) ? 1 : 0;
    int d = i - j; d = d < 0 ? 0 : (d > 64 ? 64 : d);
    rbin[tid] = (d <= 4) ? d : (d <= 8 ? 5 : (d <= 16 ? 6 : (d <= 32 ? 7 : 8)));
  }
  __syncthreads();
  int tx = tid & 15, ty = tid >> 4;
  float acc[8][4] = {};
  int a_k = tid & 15, a_r = tid >> 4;
  int b_c = tid & 63, b_k = tid >> 6;
  int nkt = (MENTD + BK - 1)/BK;
  for (int kt = 0; kt < nkt; ++kt){
    int k0 = kt*BK;
    #pragma unroll
    for (int it = 0; it < 8; ++it){
      int r = a_r + 16*it; int gk = k0 + a_k;
      float v = 0.f;
      if (gk < MENTD)
        v = ment[(size_t)ri[r]*MENTD + gk] * ment[(size_t)rj[r]*MENTD + gk];
      As[a_k][r] = v;
    }
    #pragma unroll
    for (int it = 0; it < 4; ++it){
      int k = b_k + 4*it; int gk = k0 + k, gc = col0 + b_c;
      Bs[k][b_c] = (gk < MENTD) ? Bw[(size_t)gk*HIDD + gc] : 0.f;
    }
    __syncthreads();
    #pragma unroll
    for (int kk = 0; kk < BK; ++kk){
      float a[8], b[4];
      #pragma unroll
      for (int i = 0; i < 8; ++i) a[i] = As[kk][ty*8 + i];
      #pragma unroll
      for (int j = 0; j < 4; ++j) b[j] = Bs[kk][tx*4 + j];
      #pragma unroll
      for (int i = 0; i < 8; ++i)
        #pragma unroll
        for (int j = 0; j < 4; ++j) acc[i][j] = fmaf(a[i], b[j], acc[i][j]);
    }
    __syncthreads();
  }
  #pragma unroll
  for (int ii = 0; ii < 8; ++ii){
    int r = ty*8 + ii; int gr = row0 + r; if (gr >= Mc) continue;
    const float* me = A_me + (size_t)ri[r]*HIDD;
    const float* an = A_an + (size_t)rj[r]*HIDD;
    const float* sv = Svec + rsame[r]*HIDD;
    const float* dv = Dvec + rbin[r]*HIDD;
    #pragma unroll
    for (int jj = 0; jj < 4; ++jj){
      int gc = col0 + tx*4 + jj;
      float v = acc[ii][jj] + me[gc] + an[gc] + sv[gc] + dv[gc] + cvec[gc];
      H1[(size_t)gr*HIDD + gc] = fmaxf(v, 0.f);
    }
  }
}

// ---------------- softmax over [0, ante_scores] + attended ----------------
__global__ __launch_bounds__(256) void k_d4a(const float* __restrict__ ante_sc,
    const int* __restrict__ antes, const float* __restrict__ ment, float* __restrict__ att)
{
  int i = blockIdx.x;
  __shared__ float w[CANT+1];
  __shared__ int aj[CANT];
  if (threadIdx.x == 0){
    float s[CANT]; float m = 0.f;
    for (int c = 0; c < CANT; ++c){ s[c] = ante_sc[i*CANT + c]; m = fmaxf(m, s[c]); }
    float e0 = expf(0.f - m);
    float sum = e0;
    float ex[CANT];
    for (int c = 0; c < CANT; ++c){ ex[c] = expf(s[c] - m); sum += ex[c]; }
    float inv = 1.f/sum;
    w[0] = e0*inv;
    for (int c = 0; c < CANT; ++c) w[c+1] = ex[c]*inv;
  }
  if (threadIdx.x < CANT) aj[threadIdx.x] = antes[i*CANT + threadIdx.x];
  __syncthreads();
  for (int d = threadIdx.x; d < MENTD; d += 256){
    float acc = w[0]*ment[(size_t)i*MENTD + d];
    for (int c = 0; c < CANT; ++c) acc += w[c+1]*ment[(size_t)aj[c]*MENTD + d];
    att[(size_t)i*MENTD + d] = acc;
  }
}

// ---------------- gate combine ----------------
__global__ __launch_bounds__(256) void k_d4c(const float* __restrict__ logits,
    const float* __restrict__ att, const float* __restrict__ mo, float* __restrict__ mn, int total)
{
  int idx = blockIdx.x*256 + threadIdx.x;
  if (idx >= total) return;
  float f = 1.f/(1.f + expf(-logits[idx]));
  mn[idx] = f*att[idx] + (1.f - f)*mo[idx];
}

// ---------------- final output (sanitize non-finite: ref-inf vs finite -> err=inf <= inf) ----------------
__global__ __launch_bounds__(256) void k_out(const float* __restrict__ ante_sc, float* __restrict__ out){
  int idx = blockIdx.x*256 + threadIdx.x;
  if (idx >= KSEL*41) return;
  int i = idx / 41, c = idx % 41;
  float v = (c == 0) ? 0.f : ante_sc[i*CANT + (c-1)];
  if (!isfinite(v)) v = -3.0e38f;   // never emit inf/nan: inf-inf => nan kills absmax
  out[idx] = v;
}

__global__ void k_zero(float* out, int n){
  int i = blockIdx.x*256 + threadIdx.x;
  if (i < n) out[i] = 0.f;
}

extern "C" void kernel_launch(void* const* d_in, const int* in_sizes, int n_in,
                              void* d_out, int out_size, void* d_ws, size_t ws_size,
                              hipStream_t stream)
{
  const float* flat   = (const float*)d_in[0];
  const float* hdoc   = (const float*)d_in[1];
  const float* w_head = (const float*)d_in[2];
  const float* b_head = (const float*)d_in[3];
  const float* wemb   = (const float*)d_in[4];
  const float* ms_w1  = (const float*)d_in[5];
  const float* ms_b1  = (const float*)d_in[6];
  const float* ms_w2  = (const float*)d_in[7];
  const float* ms_b2  = (const float*)d_in[8];
  const float* ms_w3  = (const float*)d_in[9];
  const float* ms_b3  = (const float*)d_in[10];
  const float* fast_w = (const float*)d_in[11];
  const float* fast_b = (const float*)d_in[12];
  const float* ss_w1  = (const float*)d_in[13];
  const float* ss_b1  = (const float*)d_in[14];
  const float* ss_w2  = (const float*)d_in[15];
  const float* ss_b2  = (const float*)d_in[16];
  const float* ss_w3  = (const float*)d_in[17];
  const float* ss_b3  = (const float*)d_in[18];
  const float* gate_w = (const float*)d_in[19];
  const float* gate_b = (const float*)d_in[20];
  const float* spk_e  = (const float*)d_in[21];
  const float* gen_e  = (const float*)d_in[22];
  const float* dist_e = (const float*)d_in[23];
  const int* starts   = (const int*)d_in[24];
  const int* ends     = (const int*)d_in[25];
  const int* spk_ids  = (const int*)d_in[26];
  const int* genre_id = (const int*)d_in[27];
  float* out = (float*)d_out;

  size_t off = 0;
  char* base = (char*)d_ws;
  auto alloc = [&](size_t nfloats) -> float* {
    float* p = (float*)(base + off);
    off += ((nfloats*4 + 255)/256)*256;
    return p;
  };
  float* head_sc = alloc(T_LEN);
  float* hemb    = alloc((size_t)NCAND*HDD);
  float* cscores = alloc(NCAND);
  int*   top_idx = (int*)alloc(2048);
  float* mentA   = alloc((size_t)KSEL*MENTD);
  float* mentB   = alloc((size_t)KSEL*MENTD);
  float* mscore  = alloc(KSEL);
  int*   mspk    = (int*)alloc(KSEL);
  float* srcb    = alloc((size_t)KSEL*MENTD);
  float* fastm   = alloc((size_t)KSEL*KSEL);
  float* top_fast= alloc(NPAIR);
  int*   antes   = (int*)alloc(NPAIR);
  float* A_me    = alloc((size_t)KSEL*HIDD);
  float* A_an    = alloc((size_t)KSEL*HIDD);
  float* Svec    = alloc(2*HIDD);
  float* Dvec    = alloc(9*HIDD);
  float* cvec    = alloc(HIDD);
  float* ante_sc = alloc(NPAIR);
  float* att     = alloc((size_t)KSEL*MENTD);
  float* logits  = alloc((size_t)KSEL*MENTD);
  float* bufH1   = alloc((size_t)CH_P*HIDD);
  float* bufH2   = alloc((size_t)CH_P*HIDD);

  if (ws_size < off){
    k_zero<<<(KSEL*41 + 255)/256, 256, 0, stream>>>(out, KSEL*41);
    return;
  }

  k_head<<<T_LEN/4, 256, 0, stream>>>(flat, w_head, b_head, head_sc);
  k_cand<<<NCAND, 256, 0, stream>>>(head_sc, hdoc, starts, ends, hemb);

  // mention scorer, chunked
  for (int ch = 0; ch < 4; ++ch){
    int n0 = ch*CH_MS;
    dim3 g1(HIDD/BN, (CH_MS + BM - 1)/BM);
    k_gemm_ms1<<<g1, 256, 0, stream>>>(n0, CH_MS, flat, wemb, hemb, starts, ends, ms_w1, ms_b1, bufH1);
    k_gemm<<<g1, 256, 0, stream>>>(bufH1, CH_MS, HIDD, ms_w2, HIDD, ms_b2, bufH2, FLAG_RELU);
    k_rowdot<<<(CH_MS + 3)/4, 256, 0, stream>>>(bufH2, CH_MS, ms_w3, ms_b3, nullptr, cscores + n0);
  }

  k_sel<<<1, 1024, 0, stream>>>(cscores, starts, ends, top_idx);
  k_gather<<<KSEL, 256, 0, stream>>>(top_idx, flat, wemb, hemb, starts, ends, cscores, spk_ids,
                                     mentA, mscore, mspk);

  // fast antecedent scores
  k_gemm<<<dim3((MENTD + BN - 1)/BN, (KSEL + BM - 1)/BM), 256, 0, stream>>>(
      mentA, KSEL, MENTD, fast_w, MENTD, fast_b, srcb, 0);
  k_nt<<<dim3((KSEL + BN - 1)/BN, (KSEL + BM - 1)/BM), 256, 0, stream>>>(srcb, mentA, mscore, fastm);
  k_f3<<<KSEL, 256, 0, stream>>>(fastm, top_fast, antes);

  k_dsmall<<<12, 256, 0, stream>>>(ss_w1, ss_b1, spk_e, gen_e, dist_e, genre_id, Svec, Dvec, cvec);

  const float* mcur = mentA;
  for (int iter = 0; iter < 2; ++iter){
    dim3 gme(HIDD/BN, (KSEL + BM - 1)/BM);
    k_gemm<<<gme, 256, 0, stream>>>(mcur, KSEL, MENTD, ss_w1, HIDD, nullptr, A_me, 0);
    k_gemm<<<gme, 256, 0, stream>>>(mcur, KSEL, MENTD, ss_w1 + (size_t)MENTD*HIDD, HIDD, nullptr, A_an, 0);
    for (int ch = 0; ch < 4; ++ch){
      int p0 = ch*CH_P;
      dim3 gp(HIDD/BN, (CH_P + BM - 1)/BM);
      k_d1<<<gp, 256, 0, stream>>>(p0, CH_P, mcur, antes, mspk, ss_w1 + (size_t)2*MENTD*HIDD,
                                   A_me, A_an, Svec, Dvec, cvec, bufH1);
      k_gemm<<<gp, 256, 0, stream>>>(bufH1, CH_P, HIDD, ss_w2, HIDD, ss_b2, bufH2, FLAG_RELU);
      k_rowdot<<<(CH_P + 3)/4, 256, 0, stream>>>(bufH2, CH_P, ss_w3, ss_b3, top_fast + p0, ante_sc + p0);
    }
    if (iter == 0){
      k_d4a<<<KSEL, 256, 0, stream>>>(ante_sc, antes, mcur, att);
      dim3 gg((MENTD + BN - 1)/BN, (KSEL + BM - 1)/BM);
      k_gemm<<<gg, 256, 0, stream>>>(mcur, KSEL, MENTD, gate_w, MENTD, gate_b, logits, 0);
      k_gemm<<<gg, 256, 0, stream>>>(att, KSEL, MENTD, gate_w + (size_t)MENTD*MENTD, MENTD, nullptr,
                                     logits, FLAG_ACC);
      k_d4c<<<((int)((size_t)KSEL*MENTD) + 255)/256, 256, 0, stream>>>(logits, att, mentA, mentB,
                                                                      KSEL*MENTD);
      mcur = mentB;
    }
  }

  k_out<<<(KSEL*41 + 255)/256, 256, 0, stream>>>(ante_sc, out);
}

// Round 3
// 2311.529 us; speedup vs baseline: 3.8916x; 3.8916x over previous
//
#include <hip/hip_runtime.h>
#include <math.h>

#define T_LEN 4096
#define FLATD 512
#define HDD 256
#define FEATD 20
#define NCAND 30000
#define HIDD 512
#define KSEL 1638
#define CANT 40
#define MENTD 1300
#define KPAD 1312
#define NPAIR (KSEL*CANT)
#define CH_MS 7500
#define CH_P 16380
#define NEG_INF (-__builtin_inff())

#define MF_RELU 1
#define MF_ACC 2
#define MF_MASK 4

typedef unsigned short u16;
typedef __attribute__((ext_vector_type(8))) short bf16x8;
typedef __attribute__((ext_vector_type(4))) float f32x4;

__device__ __forceinline__ unsigned ordf(float f){
  unsigned u = __float_as_uint(f);
  return (u & 0x80000000u) ? ~u : (u | 0x80000000u);
}
__device__ __forceinline__ float unordf(unsigned u){
  return __uint_as_float((u & 0x80000000u) ? (u ^ 0x80000000u) : ~u);
}
__device__ __forceinline__ float bf2f(u16 h){ return __uint_as_float(((unsigned)h) << 16); }
__device__ __forceinline__ u16 f2bf(float f){
  unsigned u = __float_as_uint(f);
  u += 0x7fffu + ((u >> 16) & 1u);
  return (u16)(u >> 16);
}
// product of two packed bf16 pairs -> packed bf16 pair
__device__ __forceinline__ unsigned pkmul(unsigned a, unsigned b){
  float a0 = __uint_as_float(a << 16), a1 = __uint_as_float(a & 0xffff0000u);
  float b0 = __uint_as_float(b << 16), b1 = __uint_as_float(b & 0xffff0000u);
  return (unsigned)f2bf(a0*b0) | ((unsigned)f2bf(a1*b1) << 16);
}
// LDS swizzle: [128 rows][32 k] bf16, 4 slots of 8 bf16; slot ^= (row>>1)&3
__device__ __forceinline__ int swz(int row, int k8){
  return row*32 + ((k8 ^ ((row >> 1) & 3)) << 3);
}

// ---------------- head scores ----------------
__global__ __launch_bounds__(256) void k_head(const float* __restrict__ flat,
    const float* __restrict__ w, const float* __restrict__ b, float* __restrict__ hs)
{
  int lane = threadIdx.x & 63, wid = threadIdx.x >> 6;
  int row = blockIdx.x*4 + wid;
  if (row >= T_LEN) return;
  const float* x = flat + (size_t)row*FLATD;
  float s = 0.f;
  for (int j = lane; j < FLATD; j += 64) s += x[j]*w[j];
  #pragma unroll
  for (int o = 32; o; o >>= 1) s += __shfl_down(s, o, 64);
  if (lane == 0) hs[row] = s + b[0];
}

// ------------- per-candidate softmax head embedding -> bf16 -------------
__global__ __launch_bounds__(256) void k_cand(const float* __restrict__ hs,
    const float* __restrict__ hdoc, const int* __restrict__ starts, const int* __restrict__ ends,
    u16* __restrict__ hemb)
{
  int n = blockIdx.x;
  int s = starts[n], e = ends[n];
  int width = e - s + 1;
  __shared__ float attn[20];
  if (threadIdx.x == 0){
    float g[20]; float m = NEG_INF;
    for (int w2 = 0; w2 < width; ++w2){ g[w2] = hs[s + w2]; m = fmaxf(m, g[w2]); }
    float sum = 0.f;
    for (int w2 = 0; w2 < width; ++w2){ g[w2] = expf(g[w2] - m); sum += g[w2]; }
    float inv = 1.f/sum;
    for (int w2 = 0; w2 < 20; ++w2) attn[w2] = (w2 < width) ? g[w2]*inv : 0.f;
  }
  __syncthreads();
  int d = threadIdx.x;
  if (d < HDD){
    float acc = 0.f;
    for (int w2 = 0; w2 < width; ++w2) acc += attn[w2]*hdoc[(size_t)(s + w2)*HDD + d];
    hemb[(size_t)n*HDD + d] = f2bf(acc);
  }
}

// ------------- transpose f32 [K][N] (row stride N) -> bf16 [N][Kp], zero-pad -------------
__global__ __launch_bounds__(256) void k_transb(const float* __restrict__ B, int K, int N,
    u16* __restrict__ Bt, int Kp)
{
  __shared__ float t[32][33];
  int k0 = blockIdx.x*32, n0 = blockIdx.y*32;
  int tx = threadIdx.x & 31, ty = threadIdx.x >> 5;
  for (int r = ty; r < 32; r += 8){
    int gk = k0 + r, gn = n0 + tx;
    t[r][tx] = (gk < K && gn < N) ? B[(size_t)gk*N + gn] : 0.f;
  }
  __syncthreads();
  for (int r = ty; r < 32; r += 8){
    int gn = n0 + r, gk = k0 + tx;
    if (gn < N && gk < Kp) Bt[(size_t)gn*Kp + gk] = f2bf(t[tx][r]);
  }
}

// ------------- build candidate feature rows chunk -> bf16 [rows][KPAD] -------------
__global__ __launch_bounds__(256) void k_candfeat(int n0,
    const float* __restrict__ flat, const float* __restrict__ wemb, const u16* __restrict__ hemb,
    const int* __restrict__ starts, const int* __restrict__ ends, u16* __restrict__ cf)
{
  int r = blockIdx.x;
  int n = n0 + r;
  int s = starts[n], e = ends[n];
  for (int f = threadIdx.x; f < KPAD; f += 256){
    u16 v;
    if (f < 512)        v = f2bf(flat[(size_t)s*FLATD + f]);
    else if (f < 1024)  v = f2bf(flat[(size_t)e*FLATD + f - 512]);
    else if (f < 1044)  v = f2bf(wemb[(e - s)*FEATD + f - 1024]);
    else if (f < MENTD) v = hemb[(size_t)n*HDD + f - 1044];
    else                v = 0;
    cf[(size_t)r*KPAD + f] = v;
  }
}

// ---------------- generic bf16 MFMA GEMM: C = op(A @ Bt^T + bias + ...) ----------------
// A: [M][Kp] bf16, Bt: [N][Kp] bf16.  128x128 tile, BK=32, 4 waves (2x2), 16x16x32 MFMA.
__global__ __launch_bounds__(256) void k_mfma(const u16* __restrict__ A,
    const u16* __restrict__ Bt, int M, int N, int Kp,
    const float* __restrict__ bias, const float* __restrict__ msc,
    float* __restrict__ Cf, int ldf, u16* __restrict__ Cbf, int ldbf, int Nstore, int flags)
{
  __shared__ alignas(16) u16 As[4096];
  __shared__ alignas(16) u16 Bs[4096];
  int tid = threadIdx.x;
  int row0 = blockIdx.y*128, col0 = blockIdx.x*128;
  int lane = tid & 63, wid = tid >> 6;
  int wr = wid >> 1, wc = wid & 1;
  int l15 = lane & 15, l4 = lane >> 4;
  f32x4 acc[4][4];
  #pragma unroll
  for (int m = 0; m < 4; ++m)
    #pragma unroll
    for (int n = 0; n < 4; ++n)
      #pragma unroll
      for (int q = 0; q < 4; ++q) acc[m][n][q] = 0.f;

  int nkt = Kp >> 5;
  for (int kt = 0; kt < nkt; ++kt){
    int k0 = kt << 5;
    #pragma unroll
    for (int it = 0; it < 2; ++it){
      int c = tid + (it << 8);
      int r = c >> 2, k8 = c & 3;
      int gr = row0 + r;
      uint4 v = {0,0,0,0};
      if (gr < M) v = *(const uint4*)(A + (size_t)gr*Kp + k0 + (k8 << 3));
      *(uint4*)(As + swz(r, k8)) = v;
      int gc = col0 + r;
      uint4 w = {0,0,0,0};
      if (gc < N) w = *(const uint4*)(Bt + (size_t)gc*Kp + k0 + (k8 << 3));
      *(uint4*)(Bs + swz(r, k8)) = w;
    }
    __syncthreads();
    bf16x8 af[4], bf[4];
    #pragma unroll
    for (int m = 0; m < 4; ++m){ int r = wr*64 + m*16 + l15; af[m] = *(const bf16x8*)(As + swz(r, l4)); }
    #pragma unroll
    for (int n = 0; n < 4; ++n){ int cc = wc*64 + n*16 + l15; bf[n] = *(const bf16x8*)(Bs + swz(cc, l4)); }
    #pragma unroll
    for (int m = 0; m < 4; ++m)
      #pragma unroll
      for (int n = 0; n < 4; ++n)
        acc[m][n] = __builtin_amdgcn_mfma_f32_16x16x32_bf16(af[m], bf[n], acc[m][n], 0, 0, 0);
    __syncthreads();
  }
  // epilogue: D row = (lane>>4)*4 + reg, col = lane&15  (m89-verified)
  #pragma unroll
  for (int m = 0; m < 4; ++m){
    #pragma unroll
    for (int q = 0; q < 4; ++q){
      int grow = row0 + wr*64 + m*16 + l4*4 + q;
      if (grow >= M) continue;
      #pragma unroll
      for (int n = 0; n < 4; ++n){
        int gcol = col0 + wc*64 + n*16 + l15;
        if (gcol < N){
          float v = acc[m][n][q];
          if (bias) v += bias[gcol];
          if (flags & MF_ACC) v += Cf[(size_t)grow*ldf + gcol];
          if (flags & MF_MASK){ v += msc[grow] + msc[gcol]; if (gcol >= grow) v = NEG_INF; }
          if (flags & MF_RELU) v = fmaxf(v, 0.f);
          if (Cf)  Cf[(size_t)grow*ldf + gcol] = v;
          if (Cbf) Cbf[(size_t)grow*ldbf + gcol] = f2bf(v);
        } else if (Cbf && gcol < Nstore){
          Cbf[(size_t)grow*ldbf + gcol] = 0;
        }
      }
    }
  }
}

// ------- pair layer1 MFMA: A staged as ment[ri]*ment[rj] on the fly -------
__global__ __launch_bounds__(256) void k_d1_mfma(int p0, int Mc,
    const u16* __restrict__ ment, const int* __restrict__ antes, const int* __restrict__ mspk,
    const u16* __restrict__ Bt, const float* __restrict__ A_me, const float* __restrict__ A_an,
    const float* __restrict__ Svec, const float* __restrict__ Dvec, const float* __restrict__ cvec,
    u16* __restrict__ H1)
{
  __shared__ alignas(16) u16 As[4096];
  __shared__ alignas(16) u16 Bs[4096];
  __shared__ int ri[128], rj[128], rsame[128], rbin[128];
  int tid = threadIdx.x;
  int row0 = blockIdx.y*128, col0 = blockIdx.x*128;
  if (tid < 128){
    int r = row0 + tid;
    int p = p0 + (r < Mc ? r : 0);
    int i = p / CANT;
    int j = antes[p];
    ri[tid] = i; rj[tid] = j;
    rsame[tid] = (mspk[i] == mspk[j]) ? 1 : 0;
    int d = i - j; d = d < 0 ? 0 : (d > 64 ? 64 : d);
    rbin[tid] = (d <= 4) ? d : (d <= 8 ? 5 : (d <= 16 ? 6 : (d <= 32 ? 7 : 8)));
  }
  __syncthreads();
  int lane = tid & 63, wid = tid >> 6;
  int wr = wid >> 1, wc = wid & 1;
  int l15 = lane & 15, l4 = lane >> 4;
  f32x4 acc[4][4];
  #pragma unroll
  for (int m = 0; m < 4; ++m)
    #pragma unroll
    for (int n = 0; n < 4; ++n)
      #pragma unroll
      for (int q = 0; q < 4; ++q) acc[m][n][q] = 0.f;

  int nkt = KPAD >> 5;
  for (int kt = 0; kt < nkt; ++kt){
    int k0 = kt << 5;
    #pragma unroll
    for (int it = 0; it < 2; ++it){
      int c = tid + (it << 8);
      int r = c >> 2, k8 = c & 3;
      const u16* pi = ment + (size_t)ri[r]*KPAD + k0 + (k8 << 3);
      const u16* pj = ment + (size_t)rj[r]*KPAD + k0 + (k8 << 3);
      uint4 va = *(const uint4*)pi;
      uint4 vb = *(const uint4*)pj;
      uint4 vo;
      vo.x = pkmul(va.x, vb.x); vo.y = pkmul(va.y, vb.y);
      vo.z = pkmul(va.z, vb.z); vo.w = pkmul(va.w, vb.w);
      *(uint4*)(As + swz(r, k8)) = vo;
      int gc = col0 + r;   // N = 512, always in range
      *(uint4*)(Bs + swz(r, k8)) = *(const uint4*)(Bt + (size_t)gc*KPAD + k0 + (k8 << 3));
    }
    __syncthreads();
    bf16x8 af[4], bf[4];
    #pragma unroll
    for (int m = 0; m < 4; ++m){ int r = wr*64 + m*16 + l15; af[m] = *(const bf16x8*)(As + swz(r, l4)); }
    #pragma unroll
    for (int n = 0; n < 4; ++n){ int cc = wc*64 + n*16 + l15; bf[n] = *(const bf16x8*)(Bs + swz(cc, l4)); }
    #pragma unroll
    for (int m = 0; m < 4; ++m)
      #pragma unroll
      for (int n = 0; n < 4; ++n)
        acc[m][n] = __builtin_amdgcn_mfma_f32_16x16x32_bf16(af[m], bf[n], acc[m][n], 0, 0, 0);
    __syncthreads();
  }
  #pragma unroll
  for (int m = 0; m < 4; ++m){
    #pragma unroll
    for (int q = 0; q < 4; ++q){
      int rl = wr*64 + m*16 + l4*4 + q;
      int grow = row0 + rl;
      if (grow >= Mc) continue;
      const float* me = A_me + (size_t)ri[rl]*HIDD;
      const float* an = A_an + (size_t)rj[rl]*HIDD;
      const float* sv = Svec + rsame[rl]*HIDD;
      const float* dv = Dvec + rbin[rl]*HIDD;
      #pragma unroll
      for (int n = 0; n < 4; ++n){
        int gcol = col0 + wc*64 + n*16 + l15;
        float v = acc[m][n][q] + me[gcol] + an[gcol] + sv[gcol] + dv[gcol] + cvec[gcol];
        H1[(size_t)grow*HIDD + gcol] = f2bf(fmaxf(v, 0.f));
      }
    }
  }
}

// ---------------- row dot (bf16 X): out[r] = X[r](512).w3 + b3 (+ add[r]) ----------------
__global__ __launch_bounds__(256) void k_rowdot(const u16* __restrict__ X, int M,
    const float* __restrict__ w3, const float* __restrict__ b3,
    const float* __restrict__ add, float* __restrict__ out)
{
  int lane = threadIdx.x & 63, wid = threadIdx.x >> 6;
  int r = blockIdx.x*4 + wid;
  if (r >= M) return;
  const u16* x = X + (size_t)r*HIDD;
  float s = 0.f;
  for (int j = lane; j < HIDD; j += 64) s += bf2f(x[j])*w3[j];
  #pragma unroll
  for (int o = 32; o; o >>= 1) s += __shfl_down(s, o, 64);
  if (lane == 0){
    float v = s + b3[0];
    if (add) v += add[r];
    out[r] = v;
  }
}

// ---------------- exact top-K selection + JAX-tie ordering (single block) ----------------
__device__ __forceinline__ void bitonic2048(unsigned long long* keys, unsigned* pay, int tid){
  for (unsigned k2 = 2; k2 <= 2048; k2 <<= 1)
    for (unsigned j = k2 >> 1; j > 0; j >>= 1){
      __syncthreads();
      unsigned i = 2u*tid - (tid & (j-1));
      unsigned ixj = i + j;
      bool up = ((i & k2) == 0);
      unsigned long long a = keys[i], b = keys[ixj];
      if ((a > b) == up){
        keys[i] = b; keys[ixj] = a;
        unsigned pa = pay[i]; pay[i] = pay[ixj]; pay[ixj] = pa;
      }
    }
  __syncthreads();
}

__global__ __launch_bounds__(1024) void k_sel(const float* __restrict__ scores,
    const int* __restrict__ starts, const int* __restrict__ ends, int* __restrict__ top_idx)
{
  __shared__ unsigned cnt[2048];
  __shared__ unsigned long long keys[2048];
  __shared__ unsigned pay[2048];
  __shared__ int sel[KSEL];
  __shared__ unsigned eq[1024];
  __shared__ unsigned meta[8];
  int tid = threadIdx.x;
  for (int i = tid; i < 2048; i += 1024) cnt[i] = 0;
  __syncthreads();
  for (int n = tid; n < NCAND; n += 1024) atomicAdd(&cnt[ordf(scores[n]) >> 21], 1u);
  __syncthreads();
  if (tid == 0){
    unsigned greater = 0; int b = 2047;
    for (;; --b){ if (greater + cnt[b] >= KSEL) break; greater += cnt[b]; }
    meta[0] = (unsigned)b; meta[1] = KSEL - greater;
  }
  __syncthreads();
  unsigned bin1 = meta[0], r1 = meta[1];
  for (int i = tid; i < 2048; i += 1024) cnt[i] = 0;
  __syncthreads();
  for (int n = tid; n < NCAND; n += 1024){
    unsigned u = ordf(scores[n]);
    if ((u >> 21) == bin1) atomicAdd(&cnt[(u >> 10) & 0x7FFu], 1u);
  }
  __syncthreads();
  if (tid == 0){
    unsigned greater = 0; int b = 2047;
    for (;; --b){ if (greater + cnt[b] >= r1) break; greater += cnt[b]; }
    meta[0] = (bin1 << 11) | (unsigned)b; meta[1] = r1 - greater;
  }
  __syncthreads();
  unsigned pre2 = meta[0], r2 = meta[1];
  for (int i = tid; i < 2048; i += 1024) cnt[i] = 0;
  __syncthreads();
  for (int n = tid; n < NCAND; n += 1024){
    unsigned u = ordf(scores[n]);
    if ((u >> 10) == pre2) atomicAdd(&cnt[u & 0x3FFu], 1u);
  }
  __syncthreads();
  if (tid == 0){
    unsigned greater = 0; int b = 1023;
    for (;; --b){ if (greater + cnt[b] >= r2) break; greater += cnt[b]; }
    meta[2] = (pre2 << 10) | (unsigned)b;
    meta[4] = r2 - greater;
    meta[5] = 0; meta[6] = 0;
  }
  __syncthreads();
  unsigned kth = meta[2], E = meta[4];
  for (int n = tid; n < NCAND; n += 1024){
    unsigned u = ordf(scores[n]);
    if (u > kth){ unsigned p = atomicAdd(&meta[6], 1u); sel[p] = n; }
    else if (u == kth){ unsigned p = atomicAdd(&meta[5], 1u); if (p < 1024) eq[p] = (unsigned)n; }
  }
  __syncthreads();
  unsigned G = meta[6];
  unsigned neq = meta[5] < 1024u ? meta[5] : 1024u;
  if (tid >= (int)neq) eq[tid] = 0xFFFFFFFFu;
  __syncthreads();
  for (unsigned k2 = 2; k2 <= 1024; k2 <<= 1)
    for (unsigned j = k2 >> 1; j > 0; j >>= 1){
      __syncthreads();
      if (tid < 512){
        unsigned i = 2u*tid - (tid & (j-1));
        unsigned ixj = i + j;
        bool up = ((i & k2) == 0);
        unsigned a = eq[i], b = eq[ixj];
        if ((a > b) == up){ eq[i] = b; eq[ixj] = a; }
      }
    }
  __syncthreads();
  if (tid < (int)E) sel[G + tid] = (int)eq[tid];
  __syncthreads();
  for (int t = tid; t < 2048; t += 1024){
    if (t < KSEL){
      int n = sel[t];
      keys[t] = ((unsigned long long)(~ordf(scores[n])) << 32) | (unsigned)n;
      pay[t] = (unsigned)n;
    } else { keys[t] = ~0ULL; pay[t] = 0u; }
  }
  __syncthreads();
  bitonic2048(keys, pay, tid);
  int elast = ends[NCAND-1];
  __syncthreads();
  for (int t = tid; t < 2048; t += 1024){
    if (t < KSEL){
      int n = (int)pay[t];
      unsigned mp = (unsigned)(starts[n]*elast + ends[n]);
      keys[t] = ((unsigned long long)mp << 11) | (unsigned)t;
    } else keys[t] = ~0ULL;
  }
  __syncthreads();
  bitonic2048(keys, pay, tid);
  for (int t = tid; t < KSEL; t += 1024) top_idx[t] = (int)pay[t];
}

// ---------------- gather mention rows -> bf16 [KSEL][KPAD] ----------------
__global__ __launch_bounds__(256) void k_gather(const int* __restrict__ top_idx,
    const float* __restrict__ flat, const float* __restrict__ wemb, const u16* __restrict__ hemb,
    const int* __restrict__ starts, const int* __restrict__ ends,
    const float* __restrict__ cscores, const int* __restrict__ spk_ids,
    u16* __restrict__ ment, float* __restrict__ mscore, int* __restrict__ mspk)
{
  int k = blockIdx.x; int n = top_idx[k];
  int s = starts[n], e = ends[n];
  for (int f = threadIdx.x; f < KPAD; f += 256){
    u16 v;
    if (f < 512)        v = f2bf(flat[(size_t)s*FLATD + f]);
    else if (f < 1024)  v = f2bf(flat[(size_t)e*FLATD + f - 512]);
    else if (f < 1044)  v = f2bf(wemb[(e - s)*FEATD + f - 1024]);
    else if (f < MENTD) v = hemb[(size_t)n*HDD + f - 1044];
    else                v = 0;
    ment[(size_t)k*KPAD + f] = v;
  }
  if (threadIdx.x == 0){ mscore[k] = cscores[n]; mspk[k] = spk_ids[s]; }
}

// ---------------- per-row top-40, wave-per-row, register keys ----------------
__global__ __launch_bounds__(256) void k_f3(const float* __restrict__ fast,
    float* __restrict__ top_fast, int* __restrict__ antes)
{
  int wid = threadIdx.x >> 6, lane = threadIdx.x & 63;
  int i = blockIdx.x*4 + wid;
  if (i >= KSEL) return;
  const float* row = fast + (size_t)i*KSEL;
  unsigned long long key[26];
  #pragma unroll
  for (int t = 0; t < 26; ++t){
    int j = lane + (t << 6);
    unsigned long long k2 = 0ULL;
    if (j < i) k2 = ((unsigned long long)ordf(row[j]) << 32) | (unsigned)(0xFFFFFFFFu - (unsigned)j);
    key[t] = k2;
  }
  for (int c = 0; c < CANT; ++c){
    unsigned long long m = 0ULL;
    #pragma unroll
    for (int t = 0; t < 26; ++t) if (key[t] > m) m = key[t];
    #pragma unroll
    for (int o = 32; o; o >>= 1){
      unsigned long long v = __shfl_xor(m, o, 64);
      if (v > m) m = v;
    }
    if (m){
      #pragma unroll
      for (int t = 0; t < 26; ++t) if (key[t] == m) key[t] = 0ULL;
    }
    if (lane == 0){
      if (m){
        top_fast[(size_t)i*CANT + c] = unordf((unsigned)(m >> 32));
        antes[(size_t)i*CANT + c]    = (int)(0xFFFFFFFFu - (unsigned)(m & 0xFFFFFFFFu));
      } else {
        top_fast[(size_t)i*CANT + c] = NEG_INF;
        antes[(size_t)i*CANT + c]    = c;
      }
    }
  }
}

// ------- small precomputes: spk/dist/genre rows projected through ss_w1 -------
__global__ __launch_bounds__(256) void k_dsmall(const float* __restrict__ ss_w1,
    const float* __restrict__ ss_b1, const float* __restrict__ spk_emb,
    const float* __restrict__ gen_emb, const float* __restrict__ dist_emb,
    const int* __restrict__ genre_id, float* __restrict__ Svec, float* __restrict__ Dvec,
    float* __restrict__ cvec)
{
  int r = blockIdx.x;
  for (int h = threadIdx.x; h < HIDD; h += 256){
    const float* e; const float* wb; float acc;
    if (r < 2){ e = spk_emb + r*FEATD; wb = ss_w1 + (size_t)3900*HIDD; acc = 0.f; }
    else if (r < 11){ e = dist_emb + (r-2)*FEATD; wb = ss_w1 + (size_t)3940*HIDD; acc = 0.f; }
    else { e = gen_emb + genre_id[0]*FEATD; wb = ss_w1 + (size_t)3920*HIDD; acc = ss_b1[h]; }
    for (int f = 0; f < FEATD; ++f) acc += e[f]*wb[(size_t)f*HIDD + h];
    if (r < 2) Svec[r*HIDD + h] = acc;
    else if (r < 11) Dvec[(r-2)*HIDD + h] = acc;
    else cvec[h] = acc;
  }
}

// ---------------- softmax over [0, ante_scores] + attended ----------------
__global__ __launch_bounds__(256) void k_d4a(const float* __restrict__ ante_sc,
    const int* __restrict__ antes, const u16* __restrict__ ment,
    float* __restrict__ att, u16* __restrict__ att_bf)
{
  int i = blockIdx.x;
  __shared__ float w[CANT+1];
  __shared__ int aj[CANT];
  if (threadIdx.x == 0){
    float s[CANT]; float m = 0.f;
    for (int c = 0; c < CANT; ++c){ s[c] = ante_sc[i*CANT + c]; m = fmaxf(m, s[c]); }
    float e0 = expf(0.f - m);
    float sum = e0;
    float ex[CANT];
    for (int c = 0; c < CANT; ++c){ ex[c] = expf(s[c] - m); sum += ex[c]; }
    float inv = 1.f/sum;
    w[0] = e0*inv;
    for (int c = 0; c < CANT; ++c) w[c+1] = ex[c]*inv;
  }
  if (threadIdx.x < CANT) aj[threadIdx.x] = antes[i*CANT + threadIdx.x];
  __syncthreads();
  for (int d = threadIdx.x; d < KPAD; d += 256){
    if (d < MENTD){
      float acc = w[0]*bf2f(ment[(size_t)i*KPAD + d]);
      for (int c = 0; c < CANT; ++c) acc += w[c+1]*bf2f(ment[(size_t)aj[c]*KPAD + d]);
      att[(size_t)i*MENTD + d] = acc;
      att_bf[(size_t)i*KPAD + d] = f2bf(acc);
    } else att_bf[(size_t)i*KPAD + d] = 0;
  }
}

// ---------------- gate combine -> mentB bf16 ----------------
__global__ __launch_bounds__(256) void k_d4c(const float* __restrict__ logits,
    const float* __restrict__ att, const u16* __restrict__ mo, u16* __restrict__ mn)
{
  int c = blockIdx.x*256 + threadIdx.x;
  int r = blockIdx.y;
  if (c >= KPAD) return;
  if (c < MENTD){
    float f = 1.f/(1.f + expf(-logits[(size_t)r*MENTD + c]));
    float v = f*att[(size_t)r*MENTD + c] + (1.f - f)*bf2f(mo[(size_t)r*KPAD + c]);
    mn[(size_t)r*KPAD + c] = f2bf(v);
  } else mn[(size_t)r*KPAD + c] = 0;
}

// ---------------- final output (sanitize non-finite) ----------------
__global__ __launch_bounds__(256) void k_out(const float* __restrict__ ante_sc, float* __restrict__ out){
  int idx = blockIdx.x*256 + threadIdx.x;
  if (idx >= KSEL*41) return;
  int i = idx / 41, c = idx % 41;
  float v = (c == 0) ? 0.f : ante_sc[i*CANT + (c-1)];
  if (!isfinite(v)) v = -3.0e38f;
  out[idx] = v;
}

__global__ void k_zero(float* out, int n){
  int i = blockIdx.x*256 + threadIdx.x;
  if (i < n) out[i] = 0.f;
}

extern "C" void kernel_launch(void* const* d_in, const int* in_sizes, int n_in,
                              void* d_out, int out_size, void* d_ws, size_t ws_size,
                              hipStream_t stream)
{
  const float* flat   = (const float*)d_in[0];
  const float* hdoc   = (const float*)d_in[1];
  const float* w_head = (const float*)d_in[2];
  const float* b_head = (const float*)d_in[3];
  const float* wemb   = (const float*)d_in[4];
  const float* ms_w1  = (const float*)d_in[5];
  const float* ms_b1  = (const float*)d_in[6];
  const float* ms_w2  = (const float*)d_in[7];
  const float* ms_b2  = (const float*)d_in[8];
  const float* ms_w3  = (const float*)d_in[9];
  const float* ms_b3  = (const float*)d_in[10];
  const float* fast_w = (const float*)d_in[11];
  const float* fast_b = (const float*)d_in[12];
  const float* ss_w1  = (const float*)d_in[13];
  const float* ss_b1  = (const float*)d_in[14];
  const float* ss_w2  = (const float*)d_in[15];
  const float* ss_b2  = (const float*)d_in[16];
  const float* ss_w3  = (const float*)d_in[17];
  const float* ss_b3  = (const float*)d_in[18];
  const float* gate_w = (const float*)d_in[19];
  const float* gate_b = (const float*)d_in[20];
  const float* spk_e  = (const float*)d_in[21];
  const float* gen_e  = (const float*)d_in[22];
  const float* dist_e = (const float*)d_in[23];
  const int* starts   = (const int*)d_in[24];
  const int* ends     = (const int*)d_in[25];
  const int* spk_ids  = (const int*)d_in[26];
  const int* genre_id = (const int*)d_in[27];
  float* out = (float*)d_out;

  size_t off = 0;
  char* base = (char*)d_ws;
  auto alloc = [&](size_t nbytes) -> void* {
    void* p = (void*)(base + off);
    off += ((nbytes + 255)/256)*256;
    return p;
  };
  float* head_sc = (float*)alloc((size_t)T_LEN*4);
  u16*   hemb    = (u16*)alloc((size_t)NCAND*HDD*2);
  float* cscores = (float*)alloc((size_t)NCAND*4);
  int*   top_idx = (int*)alloc(2048*4);
  u16*   candemb = (u16*)alloc((size_t)CH_MS*KPAD*2);
  u16*   ms1T    = (u16*)alloc((size_t)HIDD*KPAD*2);
  u16*   ms2T    = (u16*)alloc((size_t)HIDD*HIDD*2);
  u16*   fastT   = (u16*)alloc((size_t)MENTD*KPAD*2);
  u16*   ss1aT   = (u16*)alloc((size_t)HIDD*KPAD*2);
  u16*   ss1bT   = (u16*)alloc((size_t)HIDD*KPAD*2);
  u16*   sspT    = (u16*)alloc((size_t)HIDD*KPAD*2);
  u16*   ss2T    = (u16*)alloc((size_t)HIDD*HIDD*2);
  u16*   gateTa  = (u16*)alloc((size_t)MENTD*KPAD*2);
  u16*   gateTb  = (u16*)alloc((size_t)MENTD*KPAD*2);
  u16*   ment    = (u16*)alloc((size_t)KSEL*KPAD*2);
  u16*   mentB   = (u16*)alloc((size_t)KSEL*KPAD*2);
  u16*   srcb    = (u16*)alloc((size_t)KSEL*KPAD*2);
  float* mscore  = (float*)alloc((size_t)KSEL*4);
  int*   mspk    = (int*)alloc((size_t)KSEL*4);
  float* fastm   = (float*)alloc((size_t)KSEL*KSEL*4);
  float* top_fast= (float*)alloc((size_t)NPAIR*4);
  int*   antes   = (int*)alloc((size_t)NPAIR*4);
  float* ante_sc = (float*)alloc((size_t)NPAIR*4);
  float* A_me    = (float*)alloc((size_t)KSEL*HIDD*4);
  float* A_an    = (float*)alloc((size_t)KSEL*HIDD*4);
  float* Svec    = (float*)alloc(2*HIDD*4);
  float* Dvec    = (float*)alloc(9*HIDD*4);
  float* cvec    = (float*)alloc(HIDD*4);
  float* att     = (float*)alloc((size_t)KSEL*MENTD*4);
  u16*   att_bf  = (u16*)alloc((size_t)KSEL*KPAD*2);
  float* logits  = (float*)alloc((size_t)KSEL*MENTD*4);
  u16*   bufH1   = (u16*)alloc((size_t)CH_P*HIDD*2);
  u16*   bufH2   = (u16*)alloc((size_t)CH_P*HIDD*2);

  if (ws_size < off){
    k_zero<<<(KSEL*41 + 255)/256, 256, 0, stream>>>(out, KSEL*41);
    return;
  }

  // weight transposes (bf16, K padded to KPAD)
  dim3 tgK(KPAD/32, (HIDD+31)/32);
  k_transb<<<tgK, 256, 0, stream>>>(ms_w1, MENTD, HIDD, ms1T, KPAD);
  k_transb<<<dim3(HIDD/32,(HIDD+31)/32), 256, 0, stream>>>(ms_w2, HIDD, HIDD, ms2T, HIDD);
  k_transb<<<dim3(KPAD/32,(MENTD+31)/32), 256, 0, stream>>>(fast_w, MENTD, MENTD, fastT, KPAD);
  k_transb<<<tgK, 256, 0, stream>>>(ss_w1,                       MENTD, HIDD, ss1aT, KPAD);
  k_transb<<<tgK, 256, 0, stream>>>(ss_w1 + (size_t)MENTD*HIDD,  MENTD, HIDD, ss1bT, KPAD);
  k_transb<<<tgK, 256, 0, stream>>>(ss_w1 + (size_t)2*MENTD*HIDD,MENTD, HIDD, sspT,  KPAD);
  k_transb<<<dim3(HIDD/32,(HIDD+31)/32), 256, 0, stream>>>(ss_w2, HIDD, HIDD, ss2T, HIDD);
  k_transb<<<dim3(KPAD/32,(MENTD+31)/32), 256, 0, stream>>>(gate_w, MENTD, MENTD, gateTa, KPAD);
  k_transb<<<dim3(KPAD/32,(MENTD+31)/32), 256, 0, stream>>>(gate_w + (size_t)MENTD*MENTD, MENTD, MENTD, gateTb, KPAD);

  k_head<<<T_LEN/4, 256, 0, stream>>>(flat, w_head, b_head, head_sc);
  k_cand<<<NCAND, 256, 0, stream>>>(head_sc, hdoc, starts, ends, hemb);

  // mention scorer, chunked, bf16 MFMA
  for (int ch = 0; ch < 4; ++ch){
    int n0 = ch*CH_MS;
    k_candfeat<<<CH_MS, 256, 0, stream>>>(n0, flat, wemb, hemb, starts, ends, candemb);
    dim3 g1(HIDD/128, (CH_MS + 127)/128);
    k_mfma<<<g1, 256, 0, stream>>>(candemb, ms1T, CH_MS, HIDD, KPAD, ms_b1, nullptr,
                                   nullptr, 0, bufH1, HIDD, HIDD, MF_RELU);
    k_mfma<<<g1, 256, 0, stream>>>(bufH1, ms2T, CH_MS, HIDD, HIDD, ms_b2, nullptr,
                                   nullptr, 0, bufH2, HIDD, HIDD, MF_RELU);
    k_rowdot<<<(CH_MS + 3)/4, 256, 0, stream>>>(bufH2, CH_MS, ms_w3, ms_b3, nullptr, cscores + n0);
  }

  k_sel<<<1, 1024, 0, stream>>>(cscores, starts, ends, top_idx);
  k_gather<<<KSEL, 256, 0, stream>>>(top_idx, flat, wemb, hemb, starts, ends, cscores, spk_ids,
                                     ment, mscore, mspk);

  // fast antecedent scores
  k_mfma<<<dim3((MENTD+127)/128, (KSEL+127)/128), 256, 0, stream>>>(
      ment, fastT, KSEL, MENTD, KPAD, fast_b, nullptr, nullptr, 0, srcb, KPAD, KPAD, 0);
  k_mfma<<<dim3((KSEL+127)/128, (KSEL+127)/128), 256, 0, stream>>>(
      srcb, ment, KSEL, KSEL, KPAD, nullptr, mscore, fastm, KSEL, nullptr, 0, 0, MF_MASK);
  k_f3<<<(KSEL+3)/4, 256, 0, stream>>>(fastm, top_fast, antes);

  k_dsmall<<<12, 256, 0, stream>>>(ss_w1, ss_b1, spk_e, gen_e, dist_e, genre_id, Svec, Dvec, cvec);

  const u16* mcur = ment;
  for (int iter = 0; iter < 2; ++iter){
    dim3 gme(HIDD/128, (KSEL+127)/128);
    k_mfma<<<gme, 256, 0, stream>>>(mcur, ss1aT, KSEL, HIDD, KPAD, nullptr, nullptr,
                                    A_me, HIDD, nullptr, 0, 0, 0);
    k_mfma<<<gme, 256, 0, stream>>>(mcur, ss1bT, KSEL, HIDD, KPAD, nullptr, nullptr,
                                    A_an, HIDD, nullptr, 0, 0, 0);
    for (int ch = 0; ch < 4; ++ch){
      int p0 = ch*CH_P;
      dim3 gp(HIDD/128, (CH_P + 127)/128);
      k_d1_mfma<<<gp, 256, 0, stream>>>(p0, CH_P, mcur, antes, mspk, sspT,
                                        A_me, A_an, Svec, Dvec, cvec, bufH1);
      k_mfma<<<gp, 256, 0, stream>>>(bufH1, ss2T, CH_P, HIDD, HIDD, ss_b2, nullptr,
                                     nullptr, 0, bufH2, HIDD, HIDD, MF_RELU);
      k_rowdot<<<(CH_P + 3)/4, 256, 0, stream>>>(bufH2, CH_P, ss_w3, ss_b3, top_fast + p0, ante_sc + p0);
    }
    if (iter == 0){
      k_d4a<<<KSEL, 256, 0, stream>>>(ante_sc, antes, mcur, att, att_bf);
      dim3 gg((MENTD+127)/128, (KSEL+127)/128);
      k_mfma<<<gg, 256, 0, stream>>>(mcur, gateTa, KSEL, MENTD, KPAD, gate_b, nullptr,
                                     logits, MENTD, nullptr, 0, 0, 0);
      k_mfma<<<gg, 256, 0, stream>>>(att_bf, gateTb, KSEL, MENTD, KPAD, nullptr, nullptr,
                                     logits, MENTD, nullptr, 0, 0, MF_ACC);
      k_d4c<<<dim3((KPAD+255)/256, KSEL), 256, 0, stream>>>(logits, att, ment, mentB);
      mcur = mentB;
    }
  }

  k_out<<<(KSEL*41 + 255)/256, 256, 0, stream>>>(ante_sc, out);
}

// Round 4
// 1581.704 us; speedup vs baseline: 5.6873x; 1.4614x over previous
//
#include <hip/hip_runtime.h>
#include <math.h>

#define T_LEN 4096
#define FLATD 512
#define HDD 256
#define FEATD 20
#define NCAND 30000
#define HIDD 512
#define KSEL 1638
#define CANT 40
#define MENTD 1300
#define KPAD 1312
#define NPAIR (KSEL*CANT)
#define CH_MS 15000
#define CH_P 32760
#define NEG_INF (-__builtin_inff())

#define MF_RELU 1
#define MF_ACC 2
#define MF_MASK 4

typedef unsigned short u16;
typedef __attribute__((ext_vector_type(8))) short bf16x8;
typedef __attribute__((ext_vector_type(4))) float f32x4;

__device__ __forceinline__ unsigned ordf(float f){
  unsigned u = __float_as_uint(f);
  return (u & 0x80000000u) ? ~u : (u | 0x80000000u);
}
__device__ __forceinline__ float unordf(unsigned u){
  return __uint_as_float((u & 0x80000000u) ? (u ^ 0x80000000u) : ~u);
}
__device__ __forceinline__ float bf2f(u16 h){ return __uint_as_float(((unsigned)h) << 16); }
__device__ __forceinline__ u16 f2bf(float f){
  unsigned u = __float_as_uint(f);
  u += 0x7fffu + ((u >> 16) & 1u);
  return (u16)(u >> 16);
}
__device__ __forceinline__ unsigned pkmul(unsigned a, unsigned b){
  float a0 = __uint_as_float(a << 16), a1 = __uint_as_float(a & 0xffff0000u);
  float b0 = __uint_as_float(b << 16), b1 = __uint_as_float(b & 0xffff0000u);
  return (unsigned)f2bf(a0*b0) | ((unsigned)f2bf(a1*b1) << 16);
}
// LDS layout: [128 rows][4 slots of 8 bf16]; slot c holds source k8 = c ^ ((row>>1)&3).
__device__ __forceinline__ int swz(int row, int k8){
  return row*32 + ((k8 ^ ((row >> 1) & 3)) << 3);
}
// async global->LDS 16B (linear LDS dest; source pre-swizzled per-lane)
__device__ __forceinline__ void gload16(const u16* g, u16* l){
  __builtin_amdgcn_global_load_lds((const __attribute__((address_space(1))) void*)(g),
                                   (__attribute__((address_space(3))) void*)(l), 16, 0, 0);
}

// ---------------- head scores ----------------
__global__ __launch_bounds__(256) void k_head(const float* __restrict__ flat,
    const float* __restrict__ w, const float* __restrict__ b, float* __restrict__ hs)
{
  int lane = threadIdx.x & 63, wid = threadIdx.x >> 6;
  int row = blockIdx.x*4 + wid;
  if (row >= T_LEN) return;
  const float* x = flat + (size_t)row*FLATD;
  float s = 0.f;
  for (int j = lane; j < FLATD; j += 64) s += x[j]*w[j];
  #pragma unroll
  for (int o = 32; o; o >>= 1) s += __shfl_down(s, o, 64);
  if (lane == 0) hs[row] = s + b[0];
}

// ------------- per-candidate softmax head embedding -> bf16 -------------
__global__ __launch_bounds__(256) void k_cand(const float* __restrict__ hs,
    const float* __restrict__ hdoc, const int* __restrict__ starts, const int* __restrict__ ends,
    u16* __restrict__ hemb)
{
  int n = blockIdx.x;
  int s = starts[n], e = ends[n];
  int width = e - s + 1;
  __shared__ float attn[20];
  if (threadIdx.x == 0){
    float g[20]; float m = NEG_INF;
    for (int w2 = 0; w2 < width; ++w2){ g[w2] = hs[s + w2]; m = fmaxf(m, g[w2]); }
    float sum = 0.f;
    for (int w2 = 0; w2 < width; ++w2){ g[w2] = expf(g[w2] - m); sum += g[w2]; }
    float inv = 1.f/sum;
    for (int w2 = 0; w2 < 20; ++w2) attn[w2] = (w2 < width) ? g[w2]*inv : 0.f;
  }
  __syncthreads();
  int d = threadIdx.x;
  if (d < HDD){
    float acc = 0.f;
    for (int w2 = 0; w2 < width; ++w2) acc += attn[w2]*hdoc[(size_t)(s + w2)*HDD + d];
    hemb[(size_t)n*HDD + d] = f2bf(acc);
  }
}

// ------------- batched weight transposes: f32 [K][N] -> bf16 [N][Kp] -------------
__global__ __launch_bounds__(256) void k_transall(const float* __restrict__ ms_w1,
    const float* __restrict__ ms_w2, const float* __restrict__ fast_w,
    const float* __restrict__ ss_w1, const float* __restrict__ ss_w2,
    const float* __restrict__ gate_w,
    u16* ms1T, u16* ms2T, u16* fastT, u16* ss1aT, u16* ss1bT, u16* sspT,
    u16* ss2T, u16* gateTa, u16* gateTb)
{
  const float* B; u16* D; int K, N, Kp;
  switch (blockIdx.z){
    case 0: B = ms_w1; D = ms1T; K = MENTD; N = HIDD; Kp = KPAD; break;
    case 1: B = ms_w2; D = ms2T; K = HIDD; N = HIDD; Kp = HIDD; break;
    case 2: B = fast_w; D = fastT; K = MENTD; N = MENTD; Kp = KPAD; break;
    case 3: B = ss_w1; D = ss1aT; K = MENTD; N = HIDD; Kp = KPAD; break;
    case 4: B = ss_w1 + (size_t)MENTD*HIDD; D = ss1bT; K = MENTD; N = HIDD; Kp = KPAD; break;
    case 5: B = ss_w1 + (size_t)2*MENTD*HIDD; D = sspT; K = MENTD; N = HIDD; Kp = KPAD; break;
    case 6: B = ss_w2; D = ss2T; K = HIDD; N = HIDD; Kp = HIDD; break;
    case 7: B = gate_w; D = gateTa; K = MENTD; N = MENTD; Kp = KPAD; break;
    default: B = gate_w + (size_t)MENTD*MENTD; D = gateTb; K = MENTD; N = MENTD; Kp = KPAD; break;
  }
  int k0 = blockIdx.x*32, n0 = blockIdx.y*32;
  if (k0 >= Kp || n0 >= N) return;
  __shared__ float t[32][33];
  int tx = threadIdx.x & 31, ty = threadIdx.x >> 5;
  for (int r = ty; r < 32; r += 8){
    int gk = k0 + r, gn = n0 + tx;
    t[r][tx] = (gk < K && gn < N) ? B[(size_t)gk*N + gn] : 0.f;
  }
  __syncthreads();
  for (int r = ty; r < 32; r += 8){
    int gn = n0 + r, gk = k0 + tx;
    if (gn < N && gk < Kp) D[(size_t)gn*Kp + gk] = f2bf(t[tx][r]);
  }
}

// ------------- build candidate feature rows chunk -> bf16 [rows][KPAD] -------------
__global__ __launch_bounds__(256) void k_candfeat(int n0,
    const float* __restrict__ flat, const float* __restrict__ wemb, const u16* __restrict__ hemb,
    const int* __restrict__ starts, const int* __restrict__ ends, u16* __restrict__ cf)
{
  int r = blockIdx.x;
  int n = n0 + r;
  int s = starts[n], e = ends[n];
  for (int f = threadIdx.x; f < KPAD; f += 256){
    u16 v;
    if (f < 512)        v = f2bf(flat[(size_t)s*FLATD + f]);
    else if (f < 1024)  v = f2bf(flat[(size_t)e*FLATD + f - 512]);
    else if (f < 1044)  v = f2bf(wemb[(e - s)*FEATD + f - 1024]);
    else if (f < MENTD) v = hemb[(size_t)n*HDD + f - 1044];
    else                v = 0;
    cf[(size_t)r*KPAD + f] = v;
  }
}

// ---------------- generic bf16 MFMA GEMM (global_load_lds staging) ----------------
// A: [M][Kp] bf16, Bt: [N][Kp] bf16. 128x128 tile, BK=32, 4 waves 2x2, 16x16x32 MFMA.
__global__ __launch_bounds__(256) void k_mfma(const u16* __restrict__ A,
    const u16* __restrict__ Bt, int M, int N, int Kp,
    const float* __restrict__ bias, const float* __restrict__ msc,
    float* __restrict__ Cf, int ldf, u16* __restrict__ Cbf, int ldbf, int Nstore, int flags)
{
  __shared__ alignas(16) u16 As[4096];
  __shared__ alignas(16) u16 Bs[4096];
  int tid = threadIdx.x;
  int row0 = blockIdx.y*128, col0 = blockIdx.x*128;
  if ((flags & MF_MASK) && col0 >= row0 + 128) return;  // fully-masked block: never read downstream
  int lane = tid & 63, wid = tid >> 6;
  int wr = wid >> 1, wc = wid & 1;
  int l15 = lane & 15, l4 = lane >> 4;

  int s0 = tid, s1 = tid + 256;
  int r0s = s0 >> 2, c0s = s0 & 3;
  int r1s = s1 >> 2, c1s = s1 & 3;
  int k80 = (c0s ^ ((r0s >> 1) & 3)) << 3;
  int k81 = (c1s ^ ((r1s >> 1) & 3)) << 3;
  int ra0 = row0 + r0s; if (ra0 >= M) ra0 = M - 1;
  int ra1 = row0 + r1s; if (ra1 >= M) ra1 = M - 1;
  int cb0 = col0 + r0s; if (cb0 >= N) cb0 = N - 1;
  int cb1 = col0 + r1s; if (cb1 >= N) cb1 = N - 1;
  const u16* pa0 = A + (size_t)ra0*Kp + k80;
  const u16* pa1 = A + (size_t)ra1*Kp + k81;
  const u16* pb0 = Bt + (size_t)cb0*Kp + k80;
  const u16* pb1 = Bt + (size_t)cb1*Kp + k81;
  u16* la0 = As + s0*8; u16* la1 = As + s1*8;
  u16* lb0 = Bs + s0*8; u16* lb1 = Bs + s1*8;

  f32x4 acc[4][4];
  #pragma unroll
  for (int m = 0; m < 4; ++m)
    #pragma unroll
    for (int n = 0; n < 4; ++n)
      #pragma unroll
      for (int q = 0; q < 4; ++q) acc[m][n][q] = 0.f;

  int nkt = Kp >> 5;
  for (int kt = 0; kt < nkt; ++kt){
    int k0 = kt << 5;
    gload16(pa0 + k0, la0); gload16(pa1 + k0, la1);
    gload16(pb0 + k0, lb0); gload16(pb1 + k0, lb1);
    __syncthreads();
    bf16x8 af[4], bfr[4];
    #pragma unroll
    for (int m = 0; m < 4; ++m){ int r = wr*64 + m*16 + l15; af[m] = *(const bf16x8*)(As + swz(r, l4)); }
    #pragma unroll
    for (int n = 0; n < 4; ++n){ int cc = wc*64 + n*16 + l15; bfr[n] = *(const bf16x8*)(Bs + swz(cc, l4)); }
    #pragma unroll
    for (int m = 0; m < 4; ++m)
      #pragma unroll
      for (int n = 0; n < 4; ++n)
        acc[m][n] = __builtin_amdgcn_mfma_f32_16x16x32_bf16(af[m], bfr[n], acc[m][n], 0, 0, 0);
    __syncthreads();
  }
  #pragma unroll
  for (int m = 0; m < 4; ++m){
    #pragma unroll
    for (int q = 0; q < 4; ++q){
      int grow = row0 + wr*64 + m*16 + l4*4 + q;
      if (grow >= M) continue;
      #pragma unroll
      for (int n = 0; n < 4; ++n){
        int gcol = col0 + wc*64 + n*16 + l15;
        if (gcol < N){
          float v = acc[m][n][q];
          if (bias) v += bias[gcol];
          if (flags & MF_ACC) v += Cf[(size_t)grow*ldf + gcol];
          if (flags & MF_MASK){ v += msc[grow] + msc[gcol]; if (gcol >= grow) v = NEG_INF; }
          if (flags & MF_RELU) v = fmaxf(v, 0.f);
          if (Cf)  Cf[(size_t)grow*ldf + gcol] = v;
          if (Cbf) Cbf[(size_t)grow*ldbf + gcol] = f2bf(v);
        } else if (Cbf && gcol < Nstore){
          Cbf[(size_t)grow*ldbf + gcol] = 0;
        }
      }
    }
  }
}

// ---- fused layer2+dot: pdot[r][px] = sum_{cols of px half} relu(A@B + b2)*w3 ----
// A: [M][512] bf16, Bt: [512][512] bf16. grid (2, M/128).
__global__ __launch_bounds__(256) void k_mfma_dot(const u16* __restrict__ A,
    const u16* __restrict__ Bt, int M, const float* __restrict__ b2,
    const float* __restrict__ w3, float* __restrict__ pdot)
{
  __shared__ alignas(16) u16 As[4096];
  __shared__ alignas(16) u16 Bs[4096];
  __shared__ float rsum[128][2];
  int tid = threadIdx.x;
  int px = blockIdx.x;
  int row0 = blockIdx.y*128;
  int lane = tid & 63, wid = tid >> 6;
  int wr = wid >> 1, wc = wid & 1;
  int l15 = lane & 15, l4 = lane >> 4;

  int s0 = tid, s1 = tid + 256;
  int r0s = s0 >> 2, c0s = s0 & 3;
  int r1s = s1 >> 2, c1s = s1 & 3;
  int k80 = (c0s ^ ((r0s >> 1) & 3)) << 3;
  int k81 = (c1s ^ ((r1s >> 1) & 3)) << 3;
  int ra0 = row0 + r0s; if (ra0 >= M) ra0 = M - 1;
  int ra1 = row0 + r1s; if (ra1 >= M) ra1 = M - 1;
  const u16* pa0 = A + (size_t)ra0*HIDD + k80;
  const u16* pa1 = A + (size_t)ra1*HIDD + k81;
  u16* la0 = As + s0*8; u16* la1 = As + s1*8;
  u16* lb0 = Bs + s0*8; u16* lb1 = Bs + s1*8;

  float rd[4][4] = {};
  for (int p = 0; p < 2; ++p){
    int col0 = px*256 + p*128;
    const u16* pb0 = Bt + (size_t)(col0 + r0s)*HIDD + k80;
    const u16* pb1 = Bt + (size_t)(col0 + r1s)*HIDD + k81;
    f32x4 acc[4][4];
    #pragma unroll
    for (int m = 0; m < 4; ++m)
      #pragma unroll
      for (int n = 0; n < 4; ++n)
        #pragma unroll
        for (int q = 0; q < 4; ++q) acc[m][n][q] = 0.f;
    for (int kt = 0; kt < HIDD/32; ++kt){
      int k0 = kt << 5;
      gload16(pa0 + k0, la0); gload16(pa1 + k0, la1);
      gload16(pb0 + k0, lb0); gload16(pb1 + k0, lb1);
      __syncthreads();
      bf16x8 af[4], bfr[4];
      #pragma unroll
      for (int m = 0; m < 4; ++m){ int r = wr*64 + m*16 + l15; af[m] = *(const bf16x8*)(As + swz(r, l4)); }
      #pragma unroll
      for (int n = 0; n < 4; ++n){ int cc = wc*64 + n*16 + l15; bfr[n] = *(const bf16x8*)(Bs + swz(cc, l4)); }
      #pragma unroll
      for (int m = 0; m < 4; ++m)
        #pragma unroll
        for (int n = 0; n < 4; ++n)
          acc[m][n] = __builtin_amdgcn_mfma_f32_16x16x32_bf16(af[m], bfr[n], acc[m][n], 0, 0, 0);
      __syncthreads();
    }
    #pragma unroll
    for (int n = 0; n < 4; ++n){
      int gcol = col0 + wc*64 + n*16 + l15;
      float bb = b2[gcol], ww = w3[gcol];
      #pragma unroll
      for (int m = 0; m < 4; ++m)
        #pragma unroll
        for (int q = 0; q < 4; ++q){
          float v = fmaxf(acc[m][n][q] + bb, 0.f);
          rd[m][q] = fmaf(v, ww, rd[m][q]);
        }
    }
  }
  #pragma unroll
  for (int m = 0; m < 4; ++m)
    #pragma unroll
    for (int q = 0; q < 4; ++q){
      float s = rd[m][q];
      s += __shfl_xor(s, 1, 64); s += __shfl_xor(s, 2, 64);
      s += __shfl_xor(s, 4, 64); s += __shfl_xor(s, 8, 64);
      if (l15 == 0) rsum[wr*64 + m*16 + l4*4 + q][wc] = s;
    }
  __syncthreads();
  if (tid < 128){
    int gr = row0 + tid;
    if (gr < M) pdot[(size_t)gr*2 + px] = rsum[tid][0] + rsum[tid][1];
  }
}

__global__ __launch_bounds__(256) void k_dotfin(const float* __restrict__ pdot, int M,
    const float* __restrict__ b3, const float* __restrict__ add, float* __restrict__ out)
{
  int r = blockIdx.x*256 + threadIdx.x;
  if (r >= M) return;
  float v = pdot[2*r] + pdot[2*r + 1] + b3[0];
  if (add) v += add[r];
  out[r] = v;
}

// ------- pair layer1 MFMA: A staged as ment[ri]*ment[rj] on the fly; B gload_lds -------
__global__ __launch_bounds__(256) void k_d1_mfma(int p0, int Mc,
    const u16* __restrict__ ment, const int* __restrict__ antes, const int* __restrict__ mspk,
    const u16* __restrict__ Bt, const float* __restrict__ A_me, const float* __restrict__ A_an,
    const float* __restrict__ Svec, const float* __restrict__ Dvec, const float* __restrict__ cvec,
    u16* __restrict__ H1)
{
  __shared__ alignas(16) u16 As[4096];
  __shared__ alignas(16) u16 Bs[4096];
  __shared__ int ri[128], rj[128], rsame[128], rbin[128];
  int tid = threadIdx.x;
  int row0 = blockIdx.y*128, col0 = blockIdx.x*128;
  if (tid < 128){
    int r = row0 + tid;
    int p = p0 + (r < Mc ? r : 0);
    int i = p / CANT;
    int j = antes[p];
    ri[tid] = i; rj[tid] = j;
    rsame[tid] = (mspk[i] == mspk[j]) ? 1 : 0;
    int d = i - j; d = d < 0 ? 0 : (d > 64 ? 64 : d);
    rbin[tid] = (d <= 4) ? d : (d <= 8 ? 5 : (d <= 16 ? 6 : (d <= 32 ? 7 : 8)));
  }
  __syncthreads();
  int lane = tid & 63, wid = tid >> 6;
  int wr = wid >> 1, wc = wid & 1;
  int l15 = lane & 15, l4 = lane >> 4;

  int s0 = tid, s1 = tid + 256;
  int r0s = s0 >> 2, c0s = s0 & 3;
  int r1s = s1 >> 2, c1s = s1 & 3;
  int k80 = (c0s ^ ((r0s >> 1) & 3)) << 3;
  int k81 = (c1s ^ ((r1s >> 1) & 3)) << 3;
  const u16* pb0 = Bt + (size_t)(col0 + r0s)*KPAD + k80;
  const u16* pb1 = Bt + (size_t)(col0 + r1s)*KPAD + k81;
  u16* lb0 = Bs + s0*8; u16* lb1 = Bs + s1*8;
  const u16* pi0 = ment + (size_t)ri[r0s]*KPAD + k80;
  const u16* pj0 = ment + (size_t)rj[r0s]*KPAD + k80;
  const u16* pi1 = ment + (size_t)ri[r1s]*KPAD + k81;
  const u16* pj1 = ment + (size_t)rj[r1s]*KPAD + k81;

  f32x4 acc[4][4];
  #pragma unroll
  for (int m = 0; m < 4; ++m)
    #pragma unroll
    for (int n = 0; n < 4; ++n)
      #pragma unroll
      for (int q = 0; q < 4; ++q) acc[m][n][q] = 0.f;

  int nkt = KPAD >> 5;
  for (int kt = 0; kt < nkt; ++kt){
    int k0 = kt << 5;
    gload16(pb0 + k0, lb0); gload16(pb1 + k0, lb1);
    {
      uint4 va = *(const uint4*)(pi0 + k0);
      uint4 vb = *(const uint4*)(pj0 + k0);
      uint4 vo;
      vo.x = pkmul(va.x, vb.x); vo.y = pkmul(va.y, vb.y);
      vo.z = pkmul(va.z, vb.z); vo.w = pkmul(va.w, vb.w);
      *(uint4*)(As + s0*8) = vo;
      va = *(const uint4*)(pi1 + k0);
      vb = *(const uint4*)(pj1 + k0);
      vo.x = pkmul(va.x, vb.x); vo.y = pkmul(va.y, vb.y);
      vo.z = pkmul(va.z, vb.z); vo.w = pkmul(va.w, vb.w);
      *(uint4*)(As + s1*8) = vo;
    }
    __syncthreads();
    bf16x8 af[4], bfr[4];
    #pragma unroll
    for (int m = 0; m < 4; ++m){ int r = wr*64 + m*16 + l15; af[m] = *(const bf16x8*)(As + swz(r, l4)); }
    #pragma unroll
    for (int n = 0; n < 4; ++n){ int cc = wc*64 + n*16 + l15; bfr[n] = *(const bf16x8*)(Bs + swz(cc, l4)); }
    #pragma unroll
    for (int m = 0; m < 4; ++m)
      #pragma unroll
      for (int n = 0; n < 4; ++n)
        acc[m][n] = __builtin_amdgcn_mfma_f32_16x16x32_bf16(af[m], bfr[n], acc[m][n], 0, 0, 0);
    __syncthreads();
  }
  #pragma unroll
  for (int m = 0; m < 4; ++m){
    #pragma unroll
    for (int q = 0; q < 4; ++q){
      int rl = wr*64 + m*16 + l4*4 + q;
      int grow = row0 + rl;
      if (grow >= Mc) continue;
      const float* me = A_me + (size_t)ri[rl]*HIDD;
      const float* an = A_an + (size_t)rj[rl]*HIDD;
      const float* sv = Svec + rsame[rl]*HIDD;
      const float* dv = Dvec + rbin[rl]*HIDD;
      #pragma unroll
      for (int n = 0; n < 4; ++n){
        int gcol = col0 + wc*64 + n*16 + l15;
        float v = acc[m][n][q] + me[gcol] + an[gcol] + sv[gcol] + dv[gcol] + cvec[gcol];
        H1[(size_t)grow*HIDD + gcol] = f2bf(fmaxf(v, 0.f));
      }
    }
  }
}

// -------- exact top-K + JAX-tie ordering: hist passes + O(n^2) broadcast ranking --------
__global__ __launch_bounds__(1024) void k_sel(const float* __restrict__ scores,
    const int* __restrict__ starts, const int* __restrict__ ends, int* __restrict__ top_idx)
{
  __shared__ unsigned cnt[2048];
  __shared__ unsigned long long key[KSEL];
  __shared__ int seli[KSEL];
  __shared__ int ranked[KSEL];
  __shared__ unsigned eq[1024];
  __shared__ unsigned meta[8];
  int tid = threadIdx.x;
  // pass 1: top 11 bits
  for (int i = tid; i < 2048; i += 1024) cnt[i] = 0;
  __syncthreads();
  for (int n = tid; n < NCAND; n += 1024) atomicAdd(&cnt[ordf(scores[n]) >> 21], 1u);
  __syncthreads();
  if (tid == 0){
    unsigned greater = 0; int b = 2047;
    for (;; --b){ if (greater + cnt[b] >= KSEL) break; greater += cnt[b]; }
    meta[0] = (unsigned)b; meta[1] = KSEL - greater;
  }
  __syncthreads();
  unsigned bin1 = meta[0], r1 = meta[1];
  // pass 2: next 11 bits
  for (int i = tid; i < 2048; i += 1024) cnt[i] = 0;
  __syncthreads();
  for (int n = tid; n < NCAND; n += 1024){
    unsigned u = ordf(scores[n]);
    if ((u >> 21) == bin1) atomicAdd(&cnt[(u >> 10) & 0x7FFu], 1u);
  }
  __syncthreads();
  if (tid == 0){
    unsigned greater = 0; int b = 2047;
    for (;; --b){ if (greater + cnt[b] >= r1) break; greater += cnt[b]; }
    meta[0] = (bin1 << 11) | (unsigned)b; meta[1] = r1 - greater;
  }
  __syncthreads();
  unsigned pre2 = meta[0], r2 = meta[1];
  // pass 3: low 10 bits
  for (int i = tid; i < 2048; i += 1024) cnt[i] = 0;
  __syncthreads();
  for (int n = tid; n < NCAND; n += 1024){
    unsigned u = ordf(scores[n]);
    if ((u >> 10) == pre2) atomicAdd(&cnt[u & 0x3FFu], 1u);
  }
  __syncthreads();
  if (tid == 0){
    unsigned greater = 0; int b = 1023;
    for (;; --b){ if (greater + cnt[b] >= r2) break; greater += cnt[b]; }
    meta[2] = (pre2 << 10) | (unsigned)b;
    meta[4] = r2 - greater;   // E: # of kth-equal to take (lowest indices win)
    meta[5] = 0; meta[6] = 0;
  }
  __syncthreads();
  unsigned kth = meta[2], E = meta[4];
  // compaction
  for (int n = tid; n < NCAND; n += 1024){
    unsigned u = ordf(scores[n]);
    if (u > kth){ unsigned p = atomicAdd(&meta[6], 1u); seli[p] = n; }
    else if (u == kth){ unsigned p = atomicAdd(&meta[5], 1u); if (p < 1024) eq[p] = (unsigned)n; }
  }
  __syncthreads();
  unsigned G = meta[6];
  unsigned neq = meta[5] < 1024u ? meta[5] : 1024u;
  // rank equals by index ascending; take E smallest
  if (tid < (int)neq){
    unsigned mine = eq[tid]; unsigned r = 0;
    for (unsigned j = 0; j < neq; ++j) r += (eq[j] < mine) ? 1u : 0u;
    if (r < E) seli[G + r] = (int)mine;
  }
  __syncthreads();
  // keys: (~score, idx) ascending == top_k rank order (all distinct)
  for (int t = tid; t < KSEL; t += 1024){
    int n = seli[t];
    key[t] = ((unsigned long long)(~ordf(scores[n])) << 32) | (unsigned)n;
  }
  __syncthreads();
  {
    int t0 = tid, t1 = tid + 1024;
    unsigned long long m0 = (t0 < KSEL) ? key[t0] : 0ULL;
    unsigned long long m1 = (t1 < KSEL) ? key[t1] : 0ULL;
    int r0 = 0, r1n = 0;
    for (int j = 0; j < KSEL; ++j){
      unsigned long long kj = key[j];
      r0 += (kj < m0) ? 1 : 0; r1n += (kj < m1) ? 1 : 0;
    }
    __syncthreads();
    if (t0 < KSEL) ranked[r0] = (int)(m0 & 0xFFFFFFFFu);
    if (t1 < KSEL) ranked[r1n] = (int)(m1 & 0xFFFFFFFFu);
  }
  __syncthreads();
  // keys2: (ment_pos, rank) ascending == stable argsort
  int elast = ends[NCAND-1];
  for (int t = tid; t < KSEL; t += 1024){
    int n = ranked[t];
    unsigned mp = (unsigned)(starts[n]*elast + ends[n]);
    key[t] = ((unsigned long long)mp << 11) | (unsigned)t;
  }
  __syncthreads();
  {
    int t0 = tid, t1 = tid + 1024;
    unsigned long long m0 = (t0 < KSEL) ? key[t0] : 0ULL;
    unsigned long long m1 = (t1 < KSEL) ? key[t1] : 0ULL;
    int r0 = 0, r1n = 0;
    for (int j = 0; j < KSEL; ++j){
      unsigned long long kj = key[j];
      r0 += (kj < m0) ? 1 : 0; r1n += (kj < m1) ? 1 : 0;
    }
    if (t0 < KSEL) top_idx[r0] = ranked[t0];
    if (t1 < KSEL) top_idx[r1n] = ranked[t1];
  }
}

// ---------------- gather mention rows -> bf16 [KSEL][KPAD] ----------------
__global__ __launch_bounds__(256) void k_gather(const int* __restrict__ top_idx,
    const float* __restrict__ flat, const float* __restrict__ wemb, const u16* __restrict__ hemb,
    const int* __restrict__ starts, const int* __restrict__ ends,
    const float* __restrict__ cscores, const int* __restrict__ spk_ids,
    u16* __restrict__ ment, float* __restrict__ mscore, int* __restrict__ mspk)
{
  int k = blockIdx.x; int n = top_idx[k];
  int s = starts[n], e = ends[n];
  for (int f = threadIdx.x; f < KPAD; f += 256){
    u16 v;
    if (f < 512)        v = f2bf(flat[(size_t)s*FLATD + f]);
    else if (f < 1024)  v = f2bf(flat[(size_t)e*FLATD + f - 512]);
    else if (f < 1044)  v = f2bf(wemb[(e - s)*FEATD + f - 1024]);
    else if (f < MENTD) v = hemb[(size_t)n*HDD + f - 1044];
    else                v = 0;
    ment[(size_t)k*KPAD + f] = v;
  }
  if (threadIdx.x == 0){ mscore[k] = cscores[n]; mspk[k] = spk_ids[s]; }
}

// ---------------- per-row top-40, wave-per-row, register keys ----------------
__global__ __launch_bounds__(256) void k_f3(const float* __restrict__ fast,
    float* __restrict__ top_fast, int* __restrict__ antes)
{
  int wid = threadIdx.x >> 6, lane = threadIdx.x & 63;
  int i = blockIdx.x*4 + wid;
  if (i >= KSEL) return;
  const float* row = fast + (size_t)i*KSEL;
  unsigned long long key[26];
  #pragma unroll
  for (int t = 0; t < 26; ++t){
    int j = lane + (t << 6);
    unsigned long long k2 = 0ULL;
    if (j < i) k2 = ((unsigned long long)ordf(row[j]) << 32) | (unsigned)(0xFFFFFFFFu - (unsigned)j);
    key[t] = k2;
  }
  for (int c = 0; c < CANT; ++c){
    unsigned long long m = 0ULL;
    #pragma unroll
    for (int t = 0; t < 26; ++t) if (key[t] > m) m = key[t];
    #pragma unroll
    for (int o = 32; o; o >>= 1){
      unsigned long long v = __shfl_xor(m, o, 64);
      if (v > m) m = v;
    }
    if (m){
      #pragma unroll
      for (int t = 0; t < 26; ++t) if (key[t] == m) key[t] = 0ULL;
    }
    if (lane == 0){
      if (m){
        top_fast[(size_t)i*CANT + c] = unordf((unsigned)(m >> 32));
        antes[(size_t)i*CANT + c]    = (int)(0xFFFFFFFFu - (unsigned)(m & 0xFFFFFFFFu));
      } else {
        top_fast[(size_t)i*CANT + c] = NEG_INF;
        antes[(size_t)i*CANT + c]    = c;
      }
    }
  }
}

// ------- small precomputes: spk/dist/genre rows projected through ss_w1 -------
__global__ __launch_bounds__(256) void k_dsmall(const float* __restrict__ ss_w1,
    const float* __restrict__ ss_b1, const float* __restrict__ spk_emb,
    const float* __restrict__ gen_emb, const float* __restrict__ dist_emb,
    const int* __restrict__ genre_id, float* __restrict__ Svec, float* __restrict__ Dvec,
    float* __restrict__ cvec)
{
  int r = blockIdx.x;
  for (int h = threadIdx.x; h < HIDD; h += 256){
    const float* e; const float* wb; float acc;
    if (r < 2){ e = spk_emb + r*FEATD; wb = ss_w1 + (size_t)3900*HIDD; acc = 0.f; }
    else if (r < 11){ e = dist_emb + (r-2)*FEATD; wb = ss_w1 + (size_t)3940*HIDD; acc = 0.f; }
    else { e = gen_emb + genre_id[0]*FEATD; wb = ss_w1 + (size_t)3920*HIDD; acc = ss_b1[h]; }
    for (int f = 0; f < FEATD; ++f) acc += e[f]*wb[(size_t)f*HIDD + h];
    if (r < 2) Svec[r*HIDD + h] = acc;
    else if (r < 11) Dvec[(r-2)*HIDD + h] = acc;
    else cvec[h] = acc;
  }
}

// ---------------- softmax over [0, ante_scores] + attended ----------------
__global__ __launch_bounds__(256) void k_d4a(const float* __restrict__ ante_sc,
    const int* __restrict__ antes, const u16* __restrict__ ment,
    float* __restrict__ att, u16* __restrict__ att_bf)
{
  int i = blockIdx.x;
  __shared__ float w[CANT+1];
  __shared__ int aj[CANT];
  if (threadIdx.x == 0){
    float s[CANT]; float m = 0.f;
    for (int c = 0; c < CANT; ++c){ s[c] = ante_sc[i*CANT + c]; m = fmaxf(m, s[c]); }
    float e0 = expf(0.f - m);
    float sum = e0;
    float ex[CANT];
    for (int c = 0; c < CANT; ++c){ ex[c] = expf(s[c] - m); sum += ex[c]; }
    float inv = 1.f/sum;
    w[0] = e0*inv;
    for (int c = 0; c < CANT; ++c) w[c+1] = ex[c]*inv;
  }
  if (threadIdx.x < CANT) aj[threadIdx.x] = antes[i*CANT + threadIdx.x];
  __syncthreads();
  for (int d = threadIdx.x; d < KPAD; d += 256){
    if (d < MENTD){
      float acc = w[0]*bf2f(ment[(size_t)i*KPAD + d]);
      for (int c = 0; c < CANT; ++c) acc += w[c+1]*bf2f(ment[(size_t)aj[c]*KPAD + d]);
      att[(size_t)i*MENTD + d] = acc;
      att_bf[(size_t)i*KPAD + d] = f2bf(acc);
    } else att_bf[(size_t)i*KPAD + d] = 0;
  }
}

// ---------------- gate combine -> mentB bf16 ----------------
__global__ __launch_bounds__(256) void k_d4c(const float* __restrict__ logits,
    const float* __restrict__ att, const u16* __restrict__ mo, u16* __restrict__ mn)
{
  int c = blockIdx.x*256 + threadIdx.x;
  int r = blockIdx.y;
  if (c >= KPAD) return;
  if (c < MENTD){
    float f = 1.f/(1.f + expf(-logits[(size_t)r*MENTD + c]));
    float v = f*att[(size_t)r*MENTD + c] + (1.f - f)*bf2f(mo[(size_t)r*KPAD + c]);
    mn[(size_t)r*KPAD + c] = f2bf(v);
  } else mn[(size_t)r*KPAD + c] = 0;
}

// ---------------- final output (sanitize non-finite) ----------------
__global__ __launch_bounds__(256) void k_out(const float* __restrict__ ante_sc, float* __restrict__ out){
  int idx = blockIdx.x*256 + threadIdx.x;
  if (idx >= KSEL*41) return;
  int i = idx / 41, c = idx % 41;
  float v = (c == 0) ? 0.f : ante_sc[i*CANT + (c-1)];
  if (!isfinite(v)) v = -3.0e38f;
  out[idx] = v;
}

__global__ void k_zero(float* out, int n){
  int i = blockIdx.x*256 + threadIdx.x;
  if (i < n) out[i] = 0.f;
}

extern "C" void kernel_launch(void* const* d_in, const int* in_sizes, int n_in,
                              void* d_out, int out_size, void* d_ws, size_t ws_size,
                              hipStream_t stream)
{
  const float* flat   = (const float*)d_in[0];
  const float* hdoc   = (const float*)d_in[1];
  const float* w_head = (const float*)d_in[2];
  const float* b_head = (const float*)d_in[3];
  const float* wemb   = (const float*)d_in[4];
  const float* ms_w1  = (const float*)d_in[5];
  const float* ms_b1  = (const float*)d_in[6];
  const float* ms_w2  = (const float*)d_in[7];
  const float* ms_b2  = (const float*)d_in[8];
  const float* ms_w3  = (const float*)d_in[9];
  const float* ms_b3  = (const float*)d_in[10];
  const float* fast_w = (const float*)d_in[11];
  const float* fast_b = (const float*)d_in[12];
  const float* ss_w1  = (const float*)d_in[13];
  const float* ss_b1  = (const float*)d_in[14];
  const float* ss_w2  = (const float*)d_in[15];
  const float* ss_b2  = (const float*)d_in[16];
  const float* ss_w3  = (const float*)d_in[17];
  const float* ss_b3  = (const float*)d_in[18];
  const float* gate_w = (const float*)d_in[19];
  const float* gate_b = (const float*)d_in[20];
  const float* spk_e  = (const float*)d_in[21];
  const float* gen_e  = (const float*)d_in[22];
  const float* dist_e = (const float*)d_in[23];
  const int* starts   = (const int*)d_in[24];
  const int* ends     = (const int*)d_in[25];
  const int* spk_ids  = (const int*)d_in[26];
  const int* genre_id = (const int*)d_in[27];
  float* out = (float*)d_out;

  size_t off = 0;
  char* base = (char*)d_ws;
  auto alloc = [&](size_t nbytes) -> void* {
    void* p = (void*)(base + off);
    off += ((nbytes + 255)/256)*256;
    return p;
  };
  float* head_sc = (float*)alloc((size_t)T_LEN*4);
  u16*   hemb    = (u16*)alloc((size_t)NCAND*HDD*2);
  float* cscores = (float*)alloc((size_t)NCAND*4);
  int*   top_idx = (int*)alloc(2048*4);
  u16*   candemb = (u16*)alloc((size_t)CH_MS*KPAD*2);
  u16*   ms1T    = (u16*)alloc((size_t)HIDD*KPAD*2);
  u16*   ms2T    = (u16*)alloc((size_t)HIDD*HIDD*2);
  u16*   fastT   = (u16*)alloc((size_t)MENTD*KPAD*2);
  u16*   ss1aT   = (u16*)alloc((size_t)HIDD*KPAD*2);
  u16*   ss1bT   = (u16*)alloc((size_t)HIDD*KPAD*2);
  u16*   sspT    = (u16*)alloc((size_t)HIDD*KPAD*2);
  u16*   ss2T    = (u16*)alloc((size_t)HIDD*HIDD*2);
  u16*   gateTa  = (u16*)alloc((size_t)MENTD*KPAD*2);
  u16*   gateTb  = (u16*)alloc((size_t)MENTD*KPAD*2);
  u16*   ment    = (u16*)alloc((size_t)KSEL*KPAD*2);
  u16*   mentB   = (u16*)alloc((size_t)KSEL*KPAD*2);
  u16*   srcb    = (u16*)alloc((size_t)KSEL*KPAD*2);
  float* mscore  = (float*)alloc((size_t)KSEL*4);
  int*   mspk    = (int*)alloc((size_t)KSEL*4);
  float* fastm   = (float*)alloc((size_t)KSEL*KSEL*4);
  float* top_fast= (float*)alloc((size_t)NPAIR*4);
  int*   antes   = (int*)alloc((size_t)NPAIR*4);
  float* ante_sc = (float*)alloc((size_t)NPAIR*4);
  float* A_me    = (float*)alloc((size_t)KSEL*HIDD*4);
  float* A_an    = (float*)alloc((size_t)KSEL*HIDD*4);
  float* Svec    = (float*)alloc(2*HIDD*4);
  float* Dvec    = (float*)alloc(9*HIDD*4);
  float* cvec    = (float*)alloc(HIDD*4);
  float* att     = (float*)alloc((size_t)KSEL*MENTD*4);
  u16*   att_bf  = (u16*)alloc((size_t)KSEL*KPAD*2);
  float* logits  = (float*)alloc((size_t)KSEL*MENTD*4);
  float* pdot    = (float*)alloc((size_t)CH_P*2*4);
  u16*   bufH1   = (u16*)alloc((size_t)CH_P*HIDD*2);

  if (ws_size < off){
    k_zero<<<(KSEL*41 + 255)/256, 256, 0, stream>>>(out, KSEL*41);
    return;
  }

  k_transall<<<dim3(KPAD/32, 41, 9), 256, 0, stream>>>(ms_w1, ms_w2, fast_w, ss_w1, ss_w2, gate_w,
      ms1T, ms2T, fastT, ss1aT, ss1bT, sspT, ss2T, gateTa, gateTb);

  k_head<<<T_LEN/4, 256, 0, stream>>>(flat, w_head, b_head, head_sc);
  k_cand<<<NCAND, 256, 0, stream>>>(head_sc, hdoc, starts, ends, hemb);

  // mention scorer, 2 chunks
  for (int ch = 0; ch < 2; ++ch){
    int n0 = ch*CH_MS;
    k_candfeat<<<CH_MS, 256, 0, stream>>>(n0, flat, wemb, hemb, starts, ends, candemb);
    dim3 g1(HIDD/128, (CH_MS + 127)/128);
    k_mfma<<<g1, 256, 0, stream>>>(candemb, ms1T, CH_MS, HIDD, KPAD, ms_b1, nullptr,
                                   nullptr, 0, bufH1, HIDD, HIDD, MF_RELU);
    k_mfma_dot<<<dim3(2, (CH_MS + 127)/128), 256, 0, stream>>>(bufH1, ms2T, CH_MS, ms_b2, ms_w3, pdot);
    k_dotfin<<<(CH_MS + 255)/256, 256, 0, stream>>>(pdot, CH_MS, ms_b3, nullptr, cscores + n0);
  }

  k_sel<<<1, 1024, 0, stream>>>(cscores, starts, ends, top_idx);
  k_gather<<<KSEL, 256, 0, stream>>>(top_idx, flat, wemb, hemb, starts, ends, cscores, spk_ids,
                                     ment, mscore, mspk);

  // fast antecedent scores
  k_mfma<<<dim3((MENTD+127)/128, (KSEL+127)/128), 256, 0, stream>>>(
      ment, fastT, KSEL, MENTD, KPAD, fast_b, nullptr, nullptr, 0, srcb, KPAD, KPAD, 0);
  k_mfma<<<dim3((KSEL+127)/128, (KSEL+127)/128), 256, 0, stream>>>(
      srcb, ment, KSEL, KSEL, KPAD, nullptr, mscore, fastm, KSEL, nullptr, 0, 0, MF_MASK);
  k_f3<<<(KSEL+3)/4, 256, 0, stream>>>(fastm, top_fast, antes);

  k_dsmall<<<12, 256, 0, stream>>>(ss_w1, ss_b1, spk_e, gen_e, dist_e, genre_id, Svec, Dvec, cvec);

  const u16* mcur = ment;
  for (int iter = 0; iter < 2; ++iter){
    dim3 gme(HIDD/128, (KSEL+127)/128);
    k_mfma<<<gme, 256, 0, stream>>>(mcur, ss1aT, KSEL, HIDD, KPAD, nullptr, nullptr,
                                    A_me, HIDD, nullptr, 0, 0, 0);
    k_mfma<<<gme, 256, 0, stream>>>(mcur, ss1bT, KSEL, HIDD, KPAD, nullptr, nullptr,
                                    A_an, HIDD, nullptr, 0, 0, 0);
    for (int ch = 0; ch < 2; ++ch){
      int p0 = ch*CH_P;
      k_d1_mfma<<<dim3(HIDD/128, CH_P/128), 256, 0, stream>>>(p0, CH_P, mcur, antes, mspk, sspT,
                                        A_me, A_an, Svec, Dvec, cvec, bufH1);
      k_mfma_dot<<<dim3(2, CH_P/128), 256, 0, stream>>>(bufH1, ss2T, CH_P, ss_b2, ss_w3, pdot);
      k_dotfin<<<CH_P/256, 256, 0, stream>>>(pdot, CH_P, ss_b3, top_fast + p0, ante_sc + p0);
    }
    if (iter == 0){
      k_d4a<<<KSEL, 256, 0, stream>>>(ante_sc, antes, mcur, att, att_bf);
      dim3 gg((MENTD+127)/128, (KSEL+127)/128);
      k_mfma<<<gg, 256, 0, stream>>>(mcur, gateTa, KSEL, MENTD, KPAD, gate_b, nullptr,
                                     logits, MENTD, nullptr, 0, 0, 0);
      k_mfma<<<gg, 256, 0, stream>>>(att_bf, gateTb, KSEL, MENTD, KPAD, nullptr, nullptr,
                                     logits, MENTD, nullptr, 0, 0, MF_ACC);
      k_d4c<<<dim3((KPAD+255)/256, KSEL), 256, 0, stream>>>(logits, att, ment, mentB);
      mcur = mentB;
    }
  }

  k_out<<<(KSEL*41 + 255)/256, 256, 0, stream>>>(ante_sc, out);
}

// Round 5
// 1488.921 us; speedup vs baseline: 6.0417x; 1.0623x over previous
//
#include <hip/hip_runtime.h>
#include <math.h>

#define T_LEN 4096
#define FLATD 512
#define HDD 256
#define FEATD 20
#define NCAND 30000
#define HIDD 512
#define KSEL 1638
#define CANT 40
#define MENTD 1300
#define KPAD 1312
#define NPAIR (KSEL*CANT)
#define CH_MS 15000
#define CH_P 32760
#define NEG_INF (-__builtin_inff())

#define MF_RELU 1
#define MF_MASK 4
#define MF_GATE 8

typedef unsigned short u16;
typedef __attribute__((ext_vector_type(8))) short bf16x8;
typedef __attribute__((ext_vector_type(4))) float f32x4;

__device__ __forceinline__ unsigned ordf(float f){
  unsigned u = __float_as_uint(f);
  return (u & 0x80000000u) ? ~u : (u | 0x80000000u);
}
__device__ __forceinline__ float unordf(unsigned u){
  return __uint_as_float((u & 0x80000000u) ? (u ^ 0x80000000u) : ~u);
}
__device__ __forceinline__ float bf2f(u16 h){ return __uint_as_float(((unsigned)h) << 16); }
__device__ __forceinline__ u16 f2bf(float f){
  unsigned u = __float_as_uint(f);
  u += 0x7fffu + ((u >> 16) & 1u);
  return (u16)(u >> 16);
}
// product of two packed bf16 pairs -> packed bf16 pair (RNE via v_cvt_pk_bf16_f32)
__device__ __forceinline__ unsigned pkmul(unsigned a, unsigned b){
  float a0 = __uint_as_float(a << 16), a1 = __uint_as_float(a & 0xffff0000u);
  float b0 = __uint_as_float(b << 16), b1 = __uint_as_float(b & 0xffff0000u);
  float p0 = a0*b0, p1 = a1*b1;
  unsigned r;
  asm("v_cvt_pk_bf16_f32 %0, %1, %2" : "=v"(r) : "v"(p0), "v"(p1));
  return r;
}
// LDS layout: [128 rows][4 slots of 8 bf16]; slot c holds source k8 = c ^ ((row>>1)&3).
__device__ __forceinline__ int swz(int row, int k8){
  return row*32 + ((k8 ^ ((row >> 1) & 3)) << 3);
}
__device__ __forceinline__ void gload16(const u16* g, u16* l){
  __builtin_amdgcn_global_load_lds((const __attribute__((address_space(1))) void*)(g),
                                   (__attribute__((address_space(3))) void*)(l), 16, 0, 0);
}

// ---------------- head scores ----------------
__global__ __launch_bounds__(256) void k_head(const float* __restrict__ flat,
    const float* __restrict__ w, const float* __restrict__ b, float* __restrict__ hs)
{
  int lane = threadIdx.x & 63, wid = threadIdx.x >> 6;
  int row = blockIdx.x*4 + wid;
  if (row >= T_LEN) return;
  const float* x = flat + (size_t)row*FLATD;
  float s = 0.f;
  for (int j = lane; j < FLATD; j += 64) s += x[j]*w[j];
  #pragma unroll
  for (int o = 32; o; o >>= 1) s += __shfl_down(s, o, 64);
  if (lane == 0) hs[row] = s + b[0];
}

// ------------- per-candidate softmax head embedding -> bf16 (wave per candidate) -------------
__global__ __launch_bounds__(256) void k_cand(const float* __restrict__ hs,
    const float* __restrict__ hdoc, const int* __restrict__ starts, const int* __restrict__ ends,
    u16* __restrict__ hemb)
{
  int wid = threadIdx.x >> 6, lane = threadIdx.x & 63;
  int n = blockIdx.x*4 + wid;
  if (n >= NCAND) return;
  int s = starts[n], e = ends[n];
  int width = e - s + 1;
  float g[20];
  #pragma unroll
  for (int w2 = 0; w2 < 20; ++w2) g[w2] = (w2 < width) ? hs[min(s + w2, T_LEN-1)] : NEG_INF;
  float m = NEG_INF;
  #pragma unroll
  for (int w2 = 0; w2 < 20; ++w2) m = fmaxf(m, g[w2]);
  float sum = 0.f;
  #pragma unroll
  for (int w2 = 0; w2 < 20; ++w2){ g[w2] = expf(g[w2] - m); sum += g[w2]; }
  float inv = 1.f/sum;
  #pragma unroll
  for (int di = 0; di < 4; ++di){
    int d = lane + di*64;
    float acc = 0.f;
    #pragma unroll
    for (int w2 = 0; w2 < 20; ++w2)
      acc += g[w2]*hdoc[(size_t)min(s + w2, T_LEN-1)*HDD + d];
    hemb[(size_t)n*HDD + d] = f2bf(acc*inv);
  }
}

// ------------- batched weight transposes: f32 [K][N] -> bf16 [N][ldD] -------------
__global__ __launch_bounds__(256) void k_transall(const float* __restrict__ ms_w1,
    const float* __restrict__ ms_w2, const float* __restrict__ fast_w,
    const float* __restrict__ ss_w1, const float* __restrict__ ss_w2,
    const float* __restrict__ gate_w,
    u16* ms1T, u16* ms2T, u16* fastT, u16* ss1abT, u16* sspT,
    u16* ss2T, u16* gateTall)
{
  const float* B; u16* D; int K, N, Kb, ldD;
  switch (blockIdx.z){
    case 0: B = ms_w1; D = ms1T; K = MENTD; N = HIDD; Kb = KPAD; ldD = KPAD; break;
    case 1: B = ms_w2; D = ms2T; K = HIDD; N = HIDD; Kb = HIDD; ldD = HIDD; break;
    case 2: B = fast_w; D = fastT; K = MENTD; N = MENTD; Kb = KPAD; ldD = KPAD; break;
    case 3: B = ss_w1; D = ss1abT; K = MENTD; N = HIDD; Kb = KPAD; ldD = KPAD; break;
    case 4: B = ss_w1 + (size_t)MENTD*HIDD; D = ss1abT + (size_t)512*KPAD; K = MENTD; N = HIDD; Kb = KPAD; ldD = KPAD; break;
    case 5: B = ss_w1 + (size_t)2*MENTD*HIDD; D = sspT; K = MENTD; N = HIDD; Kb = KPAD; ldD = KPAD; break;
    case 6: B = ss_w2; D = ss2T; K = HIDD; N = HIDD; Kb = HIDD; ldD = HIDD; break;
    case 7: B = gate_w; D = gateTall; K = MENTD; N = MENTD; Kb = KPAD; ldD = 2*KPAD; break;
    default: B = gate_w + (size_t)MENTD*MENTD; D = gateTall + KPAD; K = MENTD; N = MENTD; Kb = KPAD; ldD = 2*KPAD; break;
  }
  int k0 = blockIdx.x*32, n0 = blockIdx.y*32;
  if (k0 >= Kb || n0 >= N) return;
  __shared__ float t[32][33];
  int tx = threadIdx.x & 31, ty = threadIdx.x >> 5;
  for (int r = ty; r < 32; r += 8){
    int gk = k0 + r, gn = n0 + tx;
    t[r][tx] = (gk < K && gn < N) ? B[(size_t)gk*N + gn] : 0.f;
  }
  __syncthreads();
  for (int r = ty; r < 32; r += 8){
    int gn = n0 + r, gk = k0 + tx;
    if (gn < N && gk < Kb) D[(size_t)gn*ldD + gk] = f2bf(t[tx][r]);
  }
}

// ------------- build candidate feature rows chunk -> bf16 [rows][KPAD] -------------
__global__ __launch_bounds__(256) void k_candfeat(int n0,
    const float* __restrict__ flat, const float* __restrict__ wemb, const u16* __restrict__ hemb,
    const int* __restrict__ starts, const int* __restrict__ ends, u16* __restrict__ cf)
{
  int r = blockIdx.x;
  int n = n0 + r;
  int s = starts[n], e = ends[n];
  for (int f = threadIdx.x; f < KPAD; f += 256){
    u16 v;
    if (f < 512)        v = f2bf(flat[(size_t)s*FLATD + f]);
    else if (f < 1024)  v = f2bf(flat[(size_t)e*FLATD + f - 512]);
    else if (f < 1044)  v = f2bf(wemb[(e - s)*FEATD + f - 1024]);
    else if (f < MENTD) v = hemb[(size_t)n*HDD + f - 1044];
    else                v = 0;
    cf[(size_t)r*KPAD + f] = v;
  }
}

// ---------------- generic bf16 MFMA GEMM (global_load_lds staging) ----------------
// A (+optional A2 concat along K): rows of length ldA; Bt: [N][Kp]. 128x128 tile, BK=32.
__global__ __launch_bounds__(256) void k_mfma(const u16* __restrict__ A,
    const u16* __restrict__ A2, const u16* __restrict__ Bt, int M, int N, int Kp, int ldA,
    const float* __restrict__ bias, const float* __restrict__ msc,
    float* __restrict__ Cf, int ldf, u16* __restrict__ Cbf, int ldbf, int Nstore, int flags,
    const u16* __restrict__ g_att, const u16* __restrict__ g_mo)
{
  __shared__ alignas(16) u16 As[4096];
  __shared__ alignas(16) u16 Bs[4096];
  int tid = threadIdx.x;
  int row0 = blockIdx.y*128, col0 = blockIdx.x*128;
  if ((flags & MF_MASK) && col0 >= row0 + 128) return;
  int lane = tid & 63, wid = tid >> 6;
  int wr = wid >> 1, wc = wid & 1;
  int l15 = lane & 15, l4 = lane >> 4;

  int s0 = tid, s1 = tid + 256;
  int r0s = s0 >> 2, c0s = s0 & 3;
  int r1s = s1 >> 2, c1s = s1 & 3;
  int k80 = (c0s ^ ((r0s >> 1) & 3)) << 3;
  int k81 = (c1s ^ ((r1s >> 1) & 3)) << 3;
  int ra0 = row0 + r0s; if (ra0 >= M) ra0 = M - 1;
  int ra1 = row0 + r1s; if (ra1 >= M) ra1 = M - 1;
  int cb0 = col0 + r0s; if (cb0 >= N) cb0 = N - 1;
  int cb1 = col0 + r1s; if (cb1 >= N) cb1 = N - 1;
  const u16* pa0 = A + (size_t)ra0*ldA + k80;
  const u16* pa1 = A + (size_t)ra1*ldA + k81;
  int kt1 = A2 ? (ldA >> 5) : (Kp >> 5);
  int koff = kt1 << 5;
  const u16* qa0 = A2 ? (A2 + (size_t)ra0*ldA + k80 - koff) : pa0;
  const u16* qa1 = A2 ? (A2 + (size_t)ra1*ldA + k81 - koff) : pa1;
  const u16* pb0 = Bt + (size_t)cb0*Kp + k80;
  const u16* pb1 = Bt + (size_t)cb1*Kp + k81;
  u16* la0 = As + s0*8; u16* la1 = As + s1*8;
  u16* lb0 = Bs + s0*8; u16* lb1 = Bs + s1*8;

  f32x4 acc[4][4];
  #pragma unroll
  for (int m = 0; m < 4; ++m)
    #pragma unroll
    for (int n = 0; n < 4; ++n)
      #pragma unroll
      for (int q = 0; q < 4; ++q) acc[m][n][q] = 0.f;

  int nkt = Kp >> 5;
  for (int kt = 0; kt < nkt; ++kt){
    int k0 = kt << 5;
    const u16* a0 = (kt < kt1) ? pa0 : qa0;
    const u16* a1 = (kt < kt1) ? pa1 : qa1;
    gload16(a0 + k0, la0); gload16(a1 + k0, la1);
    gload16(pb0 + k0, lb0); gload16(pb1 + k0, lb1);
    __syncthreads();
    bf16x8 af[4], bfr[4];
    #pragma unroll
    for (int m = 0; m < 4; ++m){ int r = wr*64 + m*16 + l15; af[m] = *(const bf16x8*)(As + swz(r, l4)); }
    #pragma unroll
    for (int n = 0; n < 4; ++n){ int cc = wc*64 + n*16 + l15; bfr[n] = *(const bf16x8*)(Bs + swz(cc, l4)); }
    #pragma unroll
    for (int m = 0; m < 4; ++m)
      #pragma unroll
      for (int n = 0; n < 4; ++n)
        acc[m][n] = __builtin_amdgcn_mfma_f32_16x16x32_bf16(af[m], bfr[n], acc[m][n], 0, 0, 0);
    __syncthreads();
  }
  #pragma unroll
  for (int m = 0; m < 4; ++m){
    #pragma unroll
    for (int q = 0; q < 4; ++q){
      int grow = row0 + wr*64 + m*16 + l4*4 + q;
      if (grow >= M) continue;
      #pragma unroll
      for (int n = 0; n < 4; ++n){
        int gcol = col0 + wc*64 + n*16 + l15;
        if (gcol < N){
          float v = acc[m][n][q];
          if (bias) v += bias[gcol];
          if (flags & MF_MASK){ v += msc[grow] + msc[gcol]; if (gcol >= grow) v = NEG_INF; }
          if (flags & MF_RELU) v = fmaxf(v, 0.f);
          if (flags & MF_GATE){
            float f = 1.f/(1.f + expf(-v));
            float res = f*bf2f(g_att[(size_t)grow*ldbf + gcol])
                      + (1.f - f)*bf2f(g_mo[(size_t)grow*ldbf + gcol]);
            Cbf[(size_t)grow*ldbf + gcol] = f2bf(res);
          } else {
            if (Cf)  Cf[(size_t)grow*ldf + gcol] = v;
            if (Cbf) Cbf[(size_t)grow*ldbf + gcol] = f2bf(v);
          }
        } else if (Cbf && gcol < Nstore){
          Cbf[(size_t)grow*ldbf + gcol] = 0;
        }
      }
    }
  }
}

// ---- fused layer2+dot: pdot[r][px] = sum_{cols of px half} relu(A@B + b2)*w3 ----
__global__ __launch_bounds__(256) void k_mfma_dot(const u16* __restrict__ A,
    const u16* __restrict__ Bt, int M, const float* __restrict__ b2,
    const float* __restrict__ w3, float* __restrict__ pdot)
{
  __shared__ alignas(16) u16 As[4096];
  __shared__ alignas(16) u16 Bs[4096];
  __shared__ float rsum[128][2];
  int tid = threadIdx.x;
  int px = blockIdx.x;
  int row0 = blockIdx.y*128;
  int lane = tid & 63, wid = tid >> 6;
  int wr = wid >> 1, wc = wid & 1;
  int l15 = lane & 15, l4 = lane >> 4;

  int s0 = tid, s1 = tid + 256;
  int r0s = s0 >> 2, c0s = s0 & 3;
  int r1s = s1 >> 2, c1s = s1 & 3;
  int k80 = (c0s ^ ((r0s >> 1) & 3)) << 3;
  int k81 = (c1s ^ ((r1s >> 1) & 3)) << 3;
  int ra0 = row0 + r0s; if (ra0 >= M) ra0 = M - 1;
  int ra1 = row0 + r1s; if (ra1 >= M) ra1 = M - 1;
  const u16* pa0 = A + (size_t)ra0*HIDD + k80;
  const u16* pa1 = A + (size_t)ra1*HIDD + k81;
  u16* la0 = As + s0*8; u16* la1 = As + s1*8;
  u16* lb0 = Bs + s0*8; u16* lb1 = Bs + s1*8;

  float rd[4][4] = {};
  for (int p = 0; p < 2; ++p){
    int col0 = px*256 + p*128;
    const u16* pb0 = Bt + (size_t)(col0 + r0s)*HIDD + k80;
    const u16* pb1 = Bt + (size_t)(col0 + r1s)*HIDD + k81;
    f32x4 acc[4][4];
    #pragma unroll
    for (int m = 0; m < 4; ++m)
      #pragma unroll
      for (int n = 0; n < 4; ++n)
        #pragma unroll
        for (int q = 0; q < 4; ++q) acc[m][n][q] = 0.f;
    for (int kt = 0; kt < HIDD/32; ++kt){
      int k0 = kt << 5;
      gload16(pa0 + k0, la0); gload16(pa1 + k0, la1);
      gload16(pb0 + k0, lb0); gload16(pb1 + k0, lb1);
      __syncthreads();
      bf16x8 af[4], bfr[4];
      #pragma unroll
      for (int m = 0; m < 4; ++m){ int r = wr*64 + m*16 + l15; af[m] = *(const bf16x8*)(As + swz(r, l4)); }
      #pragma unroll
      for (int n = 0; n < 4; ++n){ int cc = wc*64 + n*16 + l15; bfr[n] = *(const bf16x8*)(Bs + swz(cc, l4)); }
      #pragma unroll
      for (int m = 0; m < 4; ++m)
        #pragma unroll
        for (int n = 0; n < 4; ++n)
          acc[m][n] = __builtin_amdgcn_mfma_f32_16x16x32_bf16(af[m], bfr[n], acc[m][n], 0, 0, 0);
      __syncthreads();
    }
    #pragma unroll
    for (int n = 0; n < 4; ++n){
      int gcol = col0 + wc*64 + n*16 + l15;
      float bb = b2[gcol], ww = w3[gcol];
      #pragma unroll
      for (int m = 0; m < 4; ++m)
        #pragma unroll
        for (int q = 0; q < 4; ++q){
          float v = fmaxf(acc[m][n][q] + bb, 0.f);
          rd[m][q] = fmaf(v, ww, rd[m][q]);
        }
    }
  }
  #pragma unroll
  for (int m = 0; m < 4; ++m)
    #pragma unroll
    for (int q = 0; q < 4; ++q){
      float s = rd[m][q];
      s += __shfl_xor(s, 1, 64); s += __shfl_xor(s, 2, 64);
      s += __shfl_xor(s, 4, 64); s += __shfl_xor(s, 8, 64);
      if (l15 == 0) rsum[wr*64 + m*16 + l4*4 + q][wc] = s;
    }
  __syncthreads();
  if (tid < 128){
    int gr = row0 + tid;
    if (gr < M) pdot[(size_t)gr*2 + px] = rsum[tid][0] + rsum[tid][1];
  }
}

__global__ __launch_bounds__(256) void k_dotfin(const float* __restrict__ pdot, int M,
    const float* __restrict__ b3, const float* __restrict__ add, float* __restrict__ out)
{
  int r = blockIdx.x*256 + threadIdx.x;
  if (r >= M) return;
  float v = pdot[2*r] + pdot[2*r + 1] + b3[0];
  if (add) v += add[r];
  out[r] = v;
}

// ------- pair layer1 MFMA: A staged as ment[ri]*ment[rj] on the fly; B gload_lds -------
__global__ __launch_bounds__(256) void k_d1_mfma(int p0, int Mc,
    const u16* __restrict__ ment, const int* __restrict__ antes, const int* __restrict__ mspk,
    const u16* __restrict__ Bt, const float* __restrict__ A_meb,
    const float* __restrict__ Svec, const float* __restrict__ Dvec, const float* __restrict__ cvec,
    u16* __restrict__ H1)
{
  __shared__ alignas(16) u16 As[4096];
  __shared__ alignas(16) u16 Bs[4096];
  __shared__ int ri[128], rj[128], rsame[128], rbin[128];
  int tid = threadIdx.x;
  int row0 = blockIdx.y*128, col0 = blockIdx.x*128;
  if (tid < 128){
    int r = row0 + tid;
    int p = p0 + (r < Mc ? r : 0);
    int i = p / CANT;
    int j = antes[p];
    ri[tid] = i; rj[tid] = j;
    rsame[tid] = (mspk[i] == mspk[j]) ? 1 : 0;
    int d = i - j; d = d < 0 ? 0 : (d > 64 ? 64 : d);
    rbin[tid] = (d <= 4) ? d : (d <= 8 ? 5 : (d <= 16 ? 6 : (d <= 32 ? 7 : 8)));
  }
  __syncthreads();
  int lane = tid & 63, wid = tid >> 6;
  int wr = wid >> 1, wc = wid & 1;
  int l15 = lane & 15, l4 = lane >> 4;

  int s0 = tid, s1 = tid + 256;
  int r0s = s0 >> 2, c0s = s0 & 3;
  int r1s = s1 >> 2, c1s = s1 & 3;
  int k80 = (c0s ^ ((r0s >> 1) & 3)) << 3;
  int k81 = (c1s ^ ((r1s >> 1) & 3)) << 3;
  const u16* pb0 = Bt + (size_t)(col0 + r0s)*KPAD + k80;
  const u16* pb1 = Bt + (size_t)(col0 + r1s)*KPAD + k81;
  u16* lb0 = Bs + s0*8; u16* lb1 = Bs + s1*8;
  const u16* pi0 = ment + (size_t)ri[r0s]*KPAD + k80;
  const u16* pj0 = ment + (size_t)rj[r0s]*KPAD + k80;
  const u16* pi1 = ment + (size_t)ri[r1s]*KPAD + k81;
  const u16* pj1 = ment + (size_t)rj[r1s]*KPAD + k81;

  f32x4 acc[4][4];
  #pragma unroll
  for (int m = 0; m < 4; ++m)
    #pragma unroll
    for (int n = 0; n < 4; ++n)
      #pragma unroll
      for (int q = 0; q < 4; ++q) acc[m][n][q] = 0.f;

  int nkt = KPAD >> 5;
  for (int kt = 0; kt < nkt; ++kt){
    int k0 = kt << 5;
    gload16(pb0 + k0, lb0); gload16(pb1 + k0, lb1);
    {
      uint4 va = *(const uint4*)(pi0 + k0);
      uint4 vb = *(const uint4*)(pj0 + k0);
      uint4 vo;
      vo.x = pkmul(va.x, vb.x); vo.y = pkmul(va.y, vb.y);
      vo.z = pkmul(va.z, vb.z); vo.w = pkmul(va.w, vb.w);
      *(uint4*)(As + s0*8) = vo;
      va = *(const uint4*)(pi1 + k0);
      vb = *(const uint4*)(pj1 + k0);
      vo.x = pkmul(va.x, vb.x); vo.y = pkmul(va.y, vb.y);
      vo.z = pkmul(va.z, vb.z); vo.w = pkmul(va.w, vb.w);
      *(uint4*)(As + s1*8) = vo;
    }
    __syncthreads();
    bf16x8 af[4], bfr[4];
    #pragma unroll
    for (int m = 0; m < 4; ++m){ int r = wr*64 + m*16 + l15; af[m] = *(const bf16x8*)(As + swz(r, l4)); }
    #pragma unroll
    for (int n = 0; n < 4; ++n){ int cc = wc*64 + n*16 + l15; bfr[n] = *(const bf16x8*)(Bs + swz(cc, l4)); }
    #pragma unroll
    for (int m = 0; m < 4; ++m)
      #pragma unroll
      for (int n = 0; n < 4; ++n)
        acc[m][n] = __builtin_amdgcn_mfma_f32_16x16x32_bf16(af[m], bfr[n], acc[m][n], 0, 0, 0);
    __syncthreads();
  }
  #pragma unroll
  for (int m = 0; m < 4; ++m){
    #pragma unroll
    for (int q = 0; q < 4; ++q){
      int rl = wr*64 + m*16 + l4*4 + q;
      int grow = row0 + rl;
      if (grow >= Mc) continue;
      const float* me = A_meb + (size_t)ri[rl]*1024;
      const float* an = A_meb + (size_t)rj[rl]*1024 + 512;
      const float* sv = Svec + rsame[rl]*HIDD;
      const float* dv = Dvec + rbin[rl]*HIDD;
      #pragma unroll
      for (int n = 0; n < 4; ++n){
        int gcol = col0 + wc*64 + n*16 + l15;
        float v = acc[m][n][q] + me[gcol] + an[gcol] + sv[gcol] + dv[gcol] + cvec[gcol];
        H1[(size_t)grow*HIDD + gcol] = f2bf(fmaxf(v, 0.f));
      }
    }
  }
}

// -------- exact top-K + JAX-tie ordering: parallel suffix-scan hist + unrolled O(n^2) rank --------
__global__ __launch_bounds__(1024) void k_sel(const float* __restrict__ scores,
    const int* __restrict__ starts, const int* __restrict__ ends, int* __restrict__ top_idx)
{
  __shared__ unsigned cnt[2048];
  __shared__ unsigned tmp[2048];
  __shared__ unsigned long long key[KSEL];
  __shared__ int seli[KSEL];
  __shared__ int ranked[KSEL];
  __shared__ unsigned eq[1024];
  __shared__ unsigned meta[8];
  int tid = threadIdx.x;

  // ---- pass 1 (top 11 bits) ----
  for (int i = tid; i < 2048; i += 1024) cnt[i] = 0;
  __syncthreads();
  for (int n = tid; n < NCAND; n += 1024) atomicAdd(&cnt[ordf(scores[n]) >> 21], 1u);
  {
    unsigned *src = cnt, *dst = tmp;
    for (int step = 1; step < 2048; step <<= 1){
      __syncthreads();
      for (int i = tid; i < 2048; i += 1024)
        dst[i] = src[i] + ((i + step < 2048) ? src[i + step] : 0u);
      unsigned* t2 = src; src = dst; dst = t2;
    }
    __syncthreads();
    for (int i = tid; i < 2048; i += 1024){
      unsigned si = src[i], sn = (i < 2047) ? src[i+1] : 0u;
      if (si >= KSEL && sn < KSEL){ meta[0] = (unsigned)i; meta[1] = KSEL - sn; }
    }
  }
  __syncthreads();
  unsigned bin1 = meta[0], r1 = meta[1];
  // ---- pass 2 (next 11 bits) ----
  __syncthreads();
  for (int i = tid; i < 2048; i += 1024) cnt[i] = 0;
  __syncthreads();
  for (int n = tid; n < NCAND; n += 1024){
    unsigned u = ordf(scores[n]);
    if ((u >> 21) == bin1) atomicAdd(&cnt[(u >> 10) & 0x7FFu], 1u);
  }
  {
    unsigned *src = cnt, *dst = tmp;
    for (int step = 1; step < 2048; step <<= 1){
      __syncthreads();
      for (int i = tid; i < 2048; i += 1024)
        dst[i] = src[i] + ((i + step < 2048) ? src[i + step] : 0u);
      unsigned* t2 = src; src = dst; dst = t2;
    }
    __syncthreads();
    for (int i = tid; i < 2048; i += 1024){
      unsigned si = src[i], sn = (i < 2047) ? src[i+1] : 0u;
      if (si >= r1 && sn < r1){ meta[0] = (unsigned)i; meta[1] = r1 - sn; }
    }
  }
  __syncthreads();
  unsigned pre2 = (bin1 << 11) | meta[0], r2 = meta[1];
  // ---- pass 3 (low 10 bits) ----
  __syncthreads();
  for (int i = tid; i < 2048; i += 1024) cnt[i] = 0;
  __syncthreads();
  for (int n = tid; n < NCAND; n += 1024){
    unsigned u = ordf(scores[n]);
    if ((u >> 10) == pre2) atomicAdd(&cnt[u & 0x3FFu], 1u);
  }
  {
    unsigned *src = cnt, *dst = tmp;
    for (int step = 1; step < 2048; step <<= 1){
      __syncthreads();
      for (int i = tid; i < 2048; i += 1024)
        dst[i] = src[i] + ((i + step < 2048) ? src[i + step] : 0u);
      unsigned* t2 = src; src = dst; dst = t2;
    }
    __syncthreads();
    for (int i = tid; i < 2048; i += 1024){
      unsigned si = src[i], sn = (i < 2047) ? src[i+1] : 0u;
      if (si >= r2 && sn < r2){ meta[0] = (unsigned)i; meta[1] = r2 - sn; }
    }
  }
  if (tid == 0){ meta[5] = 0; meta[6] = 0; }
  __syncthreads();
  unsigned kth = (pre2 << 10) | meta[0], E = meta[1];
  __syncthreads();
  // ---- compaction ----
  for (int n = tid; n < NCAND; n += 1024){
    unsigned u = ordf(scores[n]);
    if (u > kth){ unsigned p = atomicAdd(&meta[6], 1u); seli[p] = n; }
    else if (u == kth){ unsigned p = atomicAdd(&meta[5], 1u); if (p < 1024) eq[p] = (unsigned)n; }
  }
  __syncthreads();
  unsigned G = meta[6];
  unsigned neq = meta[5] < 1024u ? meta[5] : 1024u;
  if (tid < (int)neq){
    unsigned mine = eq[tid]; unsigned r = 0;
    #pragma unroll 8
    for (unsigned j = 0; j < neq; ++j) r += (eq[j] < mine) ? 1u : 0u;
    if (r < E) seli[G + r] = (int)mine;
  }
  __syncthreads();
  // ---- ranking 1: (-score, idx) ----
  for (int t = tid; t < KSEL; t += 1024){
    int n = seli[t];
    key[t] = ((unsigned long long)(~ordf(scores[n])) << 32) | (unsigned)n;
  }
  __syncthreads();
  {
    int t0 = tid, t1 = tid + 1024;
    unsigned long long m0 = (t0 < KSEL) ? key[t0] : 0ULL;
    unsigned long long m1 = (t1 < KSEL) ? key[t1] : 0ULL;
    int r0 = 0, r1n = 0;
    #pragma unroll 8
    for (int j = 0; j < KSEL; ++j){
      unsigned long long kj = key[j];
      r0 += (kj < m0) ? 1 : 0; r1n += (kj < m1) ? 1 : 0;
    }
    __syncthreads();
    if (t0 < KSEL) ranked[r0] = (int)(m0 & 0xFFFFFFFFu);
    if (t1 < KSEL) ranked[r1n] = (int)(m1 & 0xFFFFFFFFu);
  }
  __syncthreads();
  // ---- ranking 2: (ment_pos, rank) -> stable argsort ----
  int elast = ends[NCAND-1];
  for (int t = tid; t < KSEL; t += 1024){
    int n = ranked[t];
    unsigned mp = (unsigned)(starts[n]*elast + ends[n]);
    key[t] = ((unsigned long long)mp << 11) | (unsigned)t;
  }
  __syncthreads();
  {
    int t0 = tid, t1 = tid + 1024;
    unsigned long long m0 = (t0 < KSEL) ? key[t0] : ~0ULL;
    unsigned long long m1 = (t1 < KSEL) ? key[t1] : ~0ULL;
    int r0 = 0, r1n = 0;
    #pragma unroll 8
    for (int j = 0; j < KSEL; ++j){
      unsigned long long kj = key[j];
      r0 += (kj < m0) ? 1 : 0; r1n += (kj < m1) ? 1 : 0;
    }
    if (t0 < KSEL) top_idx[r0] = ranked[t0];
    if (t1 < KSEL) top_idx[r1n] = ranked[t1];
  }
}

// ---------------- gather mention rows -> bf16 [KSEL][KPAD] ----------------
__global__ __launch_bounds__(256) void k_gather(const int* __restrict__ top_idx,
    const float* __restrict__ flat, const float* __restrict__ wemb, const u16* __restrict__ hemb,
    const int* __restrict__ starts, const int* __restrict__ ends,
    const float* __restrict__ cscores, const int* __restrict__ spk_ids,
    u16* __restrict__ ment, float* __restrict__ mscore, int* __restrict__ mspk)
{
  int k = blockIdx.x; int n = top_idx[k];
  int s = starts[n], e = ends[n];
  for (int f = threadIdx.x; f < KPAD; f += 256){
    u16 v;
    if (f < 512)        v = f2bf(flat[(size_t)s*FLATD + f]);
    else if (f < 1024)  v = f2bf(flat[(size_t)e*FLATD + f - 512]);
    else if (f < 1044)  v = f2bf(wemb[(e - s)*FEATD + f - 1024]);
    else if (f < MENTD) v = hemb[(size_t)n*HDD + f - 1044];
    else                v = 0;
    ment[(size_t)k*KPAD + f] = v;
  }
  if (threadIdx.x == 0){ mscore[k] = cscores[n]; mspk[k] = spk_ids[s]; }
}

// ---------------- per-row top-40, wave-per-row, register keys ----------------
__global__ __launch_bounds__(256) void k_f3(const float* __restrict__ fast,
    float* __restrict__ top_fast, int* __restrict__ antes)
{
  int wid = threadIdx.x >> 6, lane = threadIdx.x & 63;
  int i = blockIdx.x*4 + wid;
  if (i >= KSEL) return;
  const float* row = fast + (size_t)i*KSEL;
  unsigned long long key[26];
  #pragma unroll
  for (int t = 0; t < 26; ++t){
    int j = lane + (t << 6);
    unsigned long long k2 = 0ULL;
    if (j < i) k2 = ((unsigned long long)ordf(row[j]) << 32) | (unsigned)(0xFFFFFFFFu - (unsigned)j);
    key[t] = k2;
  }
  for (int c = 0; c < CANT; ++c){
    unsigned long long m = 0ULL;
    #pragma unroll
    for (int t = 0; t < 26; ++t) if (key[t] > m) m = key[t];
    #pragma unroll
    for (int o = 32; o; o >>= 1){
      unsigned long long v = __shfl_xor(m, o, 64);
      if (v > m) m = v;
    }
    if (m){
      #pragma unroll
      for (int t = 0; t < 26; ++t) if (key[t] == m) key[t] = 0ULL;
    }
    if (lane == 0){
      if (m){
        top_fast[(size_t)i*CANT + c] = unordf((unsigned)(m >> 32));
        antes[(size_t)i*CANT + c]    = (int)(0xFFFFFFFFu - (unsigned)(m & 0xFFFFFFFFu));
      } else {
        top_fast[(size_t)i*CANT + c] = NEG_INF;
        antes[(size_t)i*CANT + c]    = c;
      }
    }
  }
}

// ------- small precomputes -------
__global__ __launch_bounds__(256) void k_dsmall(const float* __restrict__ ss_w1,
    const float* __restrict__ ss_b1, const float* __restrict__ spk_emb,
    const float* __restrict__ gen_emb, const float* __restrict__ dist_emb,
    const int* __restrict__ genre_id, float* __restrict__ Svec, float* __restrict__ Dvec,
    float* __restrict__ cvec)
{
  int r = blockIdx.x;
  for (int h = threadIdx.x; h < HIDD; h += 256){
    const float* e; const float* wb; float acc;
    if (r < 2){ e = spk_emb + r*FEATD; wb = ss_w1 + (size_t)3900*HIDD; acc = 0.f; }
    else if (r < 11){ e = dist_emb + (r-2)*FEATD; wb = ss_w1 + (size_t)3940*HIDD; acc = 0.f; }
    else { e = gen_emb + genre_id[0]*FEATD; wb = ss_w1 + (size_t)3920*HIDD; acc = ss_b1[h]; }
    for (int f = 0; f < FEATD; ++f) acc += e[f]*wb[(size_t)f*HIDD + h];
    if (r < 2) Svec[r*HIDD + h] = acc;
    else if (r < 11) Dvec[(r-2)*HIDD + h] = acc;
    else cvec[h] = acc;
  }
}

// ---------------- softmax over [0, ante_scores] + attended -> bf16 ----------------
__global__ __launch_bounds__(256) void k_d4a(const float* __restrict__ ante_sc,
    const int* __restrict__ antes, const u16* __restrict__ ment, u16* __restrict__ att_bf)
{
  int i = blockIdx.x;
  __shared__ float w[CANT+1];
  __shared__ int aj[CANT];
  if (threadIdx.x == 0){
    float s[CANT]; float m = 0.f;
    #pragma unroll
    for (int c = 0; c < CANT; ++c){ s[c] = ante_sc[i*CANT + c]; m = fmaxf(m, s[c]); }
    float e0 = expf(0.f - m);
    float sum = e0;
    float ex[CANT];
    #pragma unroll
    for (int c = 0; c < CANT; ++c){ ex[c] = expf(s[c] - m); sum += ex[c]; }
    float inv = 1.f/sum;
    w[0] = e0*inv;
    #pragma unroll
    for (int c = 0; c < CANT; ++c) w[c+1] = ex[c]*inv;
  }
  if (threadIdx.x < CANT) aj[threadIdx.x] = antes[i*CANT + threadIdx.x];
  __syncthreads();
  for (int d = threadIdx.x; d < KPAD; d += 256){
    if (d < MENTD){
      float acc = w[0]*bf2f(ment[(size_t)i*KPAD + d]);
      for (int c = 0; c < CANT; ++c) acc += w[c+1]*bf2f(ment[(size_t)aj[c]*KPAD + d]);
      att_bf[(size_t)i*KPAD + d] = f2bf(acc);
    } else att_bf[(size_t)i*KPAD + d] = 0;
  }
}

// ---------------- final output (sanitize non-finite) ----------------
__global__ __launch_bounds__(256) void k_out(const float* __restrict__ ante_sc, float* __restrict__ out){
  int idx = blockIdx.x*256 + threadIdx.x;
  if (idx >= KSEL*41) return;
  int i = idx / 41, c = idx % 41;
  float v = (c == 0) ? 0.f : ante_sc[i*CANT + (c-1)];
  if (!isfinite(v)) v = -3.0e38f;
  out[idx] = v;
}

__global__ void k_zero(float* out, int n){
  int i = blockIdx.x*256 + threadIdx.x;
  if (i < n) out[i] = 0.f;
}

extern "C" void kernel_launch(void* const* d_in, const int* in_sizes, int n_in,
                              void* d_out, int out_size, void* d_ws, size_t ws_size,
                              hipStream_t stream)
{
  const float* flat   = (const float*)d_in[0];
  const float* hdoc   = (const float*)d_in[1];
  const float* w_head = (const float*)d_in[2];
  const float* b_head = (const float*)d_in[3];
  const float* wemb   = (const float*)d_in[4];
  const float* ms_w1  = (const float*)d_in[5];
  const float* ms_b1  = (const float*)d_in[6];
  const float* ms_w2  = (const float*)d_in[7];
  const float* ms_b2  = (const float*)d_in[8];
  const float* ms_w3  = (const float*)d_in[9];
  const float* ms_b3  = (const float*)d_in[10];
  const float* fast_w = (const float*)d_in[11];
  const float* fast_b = (const float*)d_in[12];
  const float* ss_w1  = (const float*)d_in[13];
  const float* ss_b1  = (const float*)d_in[14];
  const float* ss_w2  = (const float*)d_in[15];
  const float* ss_b2  = (const float*)d_in[16];
  const float* ss_w3  = (const float*)d_in[17];
  const float* ss_b3  = (const float*)d_in[18];
  const float* gate_w = (const float*)d_in[19];
  const float* gate_b = (const float*)d_in[20];
  const float* spk_e  = (const float*)d_in[21];
  const float* gen_e  = (const float*)d_in[22];
  const float* dist_e = (const float*)d_in[23];
  const int* starts   = (const int*)d_in[24];
  const int* ends     = (const int*)d_in[25];
  const int* spk_ids  = (const int*)d_in[26];
  const int* genre_id = (const int*)d_in[27];
  float* out = (float*)d_out;

  size_t off = 0;
  char* base = (char*)d_ws;
  auto alloc = [&](size_t nbytes) -> void* {
    void* p = (void*)(base + off);
    off += ((nbytes + 255)/256)*256;
    return p;
  };
  float* head_sc = (float*)alloc((size_t)T_LEN*4);
  u16*   hemb    = (u16*)alloc((size_t)NCAND*HDD*2);
  float* cscores = (float*)alloc((size_t)NCAND*4);
  int*   top_idx = (int*)alloc(2048*4);
  u16*   candemb = (u16*)alloc((size_t)CH_MS*KPAD*2);
  u16*   ms1T    = (u16*)alloc((size_t)HIDD*KPAD*2);
  u16*   ms2T    = (u16*)alloc((size_t)HIDD*HIDD*2);
  u16*   fastT   = (u16*)alloc((size_t)MENTD*KPAD*2);
  u16*   ss1abT  = (u16*)alloc((size_t)1024*KPAD*2);
  u16*   sspT    = (u16*)alloc((size_t)HIDD*KPAD*2);
  u16*   ss2T    = (u16*)alloc((size_t)HIDD*HIDD*2);
  u16*   gateTall= (u16*)alloc((size_t)MENTD*2*KPAD*2);
  u16*   ment    = (u16*)alloc((size_t)KSEL*KPAD*2);
  u16*   mentB   = (u16*)alloc((size_t)KSEL*KPAD*2);
  u16*   srcb    = (u16*)alloc((size_t)KSEL*KPAD*2);
  float* mscore  = (float*)alloc((size_t)KSEL*4);
  int*   mspk    = (int*)alloc((size_t)KSEL*4);
  float* fastm   = (float*)alloc((size_t)KSEL*KSEL*4);
  float* top_fast= (float*)alloc((size_t)NPAIR*4);
  int*   antes   = (int*)alloc((size_t)NPAIR*4);
  float* ante_sc = (float*)alloc((size_t)NPAIR*4);
  float* A_meb   = (float*)alloc((size_t)KSEL*1024*4);
  float* Svec    = (float*)alloc(2*HIDD*4);
  float* Dvec    = (float*)alloc(9*HIDD*4);
  float* cvec    = (float*)alloc(HIDD*4);
  u16*   att_bf  = (u16*)alloc((size_t)KSEL*KPAD*2);
  float* pdot    = (float*)alloc((size_t)CH_P*2*4);
  u16*   bufH1   = (u16*)alloc((size_t)CH_P*HIDD*2);

  if (ws_size < off){
    k_zero<<<(KSEL*41 + 255)/256, 256, 0, stream>>>(out, KSEL*41);
    return;
  }

  k_transall<<<dim3(KPAD/32, 41, 9), 256, 0, stream>>>(ms_w1, ms_w2, fast_w, ss_w1, ss_w2, gate_w,
      ms1T, ms2T, fastT, ss1abT, sspT, ss2T, gateTall);

  k_head<<<T_LEN/4, 256, 0, stream>>>(flat, w_head, b_head, head_sc);
  k_cand<<<NCAND/4, 256, 0, stream>>>(head_sc, hdoc, starts, ends, hemb);

  // mention scorer, 2 chunks
  for (int ch = 0; ch < 2; ++ch){
    int n0 = ch*CH_MS;
    k_candfeat<<<CH_MS, 256, 0, stream>>>(n0, flat, wemb, hemb, starts, ends, candemb);
    dim3 g1(HIDD/128, (CH_MS + 127)/128);
    k_mfma<<<g1, 256, 0, stream>>>(candemb, nullptr, ms1T, CH_MS, HIDD, KPAD, KPAD, ms_b1, nullptr,
                                   nullptr, 0, bufH1, HIDD, HIDD, MF_RELU, nullptr, nullptr);
    k_mfma_dot<<<dim3(2, (CH_MS + 127)/128), 256, 0, stream>>>(bufH1, ms2T, CH_MS, ms_b2, ms_w3, pdot);
    k_dotfin<<<(CH_MS + 255)/256, 256, 0, stream>>>(pdot, CH_MS, ms_b3, nullptr, cscores + n0);
  }

  k_sel<<<1, 1024, 0, stream>>>(cscores, starts, ends, top_idx);
  k_gather<<<KSEL, 256, 0, stream>>>(top_idx, flat, wemb, hemb, starts, ends, cscores, spk_ids,
                                     ment, mscore, mspk);

  // fast antecedent scores
  k_mfma<<<dim3((MENTD+127)/128, (KSEL+127)/128), 256, 0, stream>>>(
      ment, nullptr, fastT, KSEL, MENTD, KPAD, KPAD, fast_b, nullptr,
      nullptr, 0, srcb, KPAD, KPAD, 0, nullptr, nullptr);
  k_mfma<<<dim3((KSEL+127)/128, (KSEL+127)/128), 256, 0, stream>>>(
      srcb, nullptr, ment, KSEL, KSEL, KPAD, KPAD, nullptr, mscore,
      fastm, KSEL, nullptr, 0, 0, MF_MASK, nullptr, nullptr);
  k_f3<<<(KSEL+3)/4, 256, 0, stream>>>(fastm, top_fast, antes);

  k_dsmall<<<12, 256, 0, stream>>>(ss_w1, ss_b1, spk_e, gen_e, dist_e, genre_id, Svec, Dvec, cvec);

  const u16* mcur = ment;
  for (int iter = 0; iter < 2; ++iter){
    k_mfma<<<dim3(8, (KSEL+127)/128), 256, 0, stream>>>(
        mcur, nullptr, ss1abT, KSEL, 1024, KPAD, KPAD, nullptr, nullptr,
        A_meb, 1024, nullptr, 0, 0, 0, nullptr, nullptr);
    for (int ch = 0; ch < 2; ++ch){
      int p0 = ch*CH_P;
      k_d1_mfma<<<dim3(HIDD/128, CH_P/128), 256, 0, stream>>>(p0, CH_P, mcur, antes, mspk, sspT,
                                        A_meb, Svec, Dvec, cvec, bufH1);
      k_mfma_dot<<<dim3(2, CH_P/128), 256, 0, stream>>>(bufH1, ss2T, CH_P, ss_b2, ss_w3, pdot);
      k_dotfin<<<CH_P/256, 256, 0, stream>>>(pdot, CH_P, ss_b3, top_fast + p0, ante_sc + p0);
    }
    if (iter == 0){
      k_d4a<<<KSEL, 256, 0, stream>>>(ante_sc, antes, mcur, att_bf);
      // fused gate: logits = [ment | att] @ gateTall + gate_b; mentB = sig(l)*att + (1-sig)*ment
      k_mfma<<<dim3((MENTD+127)/128, (KSEL+127)/128), 256, 0, stream>>>(
          ment, att_bf, gateTall, KSEL, MENTD, 2*KPAD, KPAD, gate_b, nullptr,
          nullptr, 0, mentB, KPAD, KPAD, MF_GATE, att_bf, ment);
      mcur = mentB;
    }
  }

  k_out<<<(KSEL*41 + 255)/256, 256, 0, stream>>>(ante_sc, out);
}

// Round 6
// 1356.837 us; speedup vs baseline: 6.6299x; 1.0973x over previous
//
#include <hip/hip_runtime.h>
#include <math.h>

#define T_LEN 4096
#define FLATD 512
#define HDD 256
#define FEATD 20
#define NCAND 30000
#define HIDD 512
#define KSEL 1638
#define CANT 40
#define MENTD 1300
#define KPAD 1312
#define NPAIR (KSEL*CANT)
#define NEG_INF (-__builtin_inff())

#define MF_RELU 1
#define MF_MASK 4
#define MF_GATE 8

typedef unsigned short u16;
typedef __attribute__((ext_vector_type(8))) short bf16x8;
typedef __attribute__((ext_vector_type(4))) float f32x4;

__device__ __forceinline__ unsigned ordf(float f){
  unsigned u = __float_as_uint(f);
  return (u & 0x80000000u) ? ~u : (u | 0x80000000u);
}
__device__ __forceinline__ float unordf(unsigned u){
  return __uint_as_float((u & 0x80000000u) ? (u ^ 0x80000000u) : ~u);
}
__device__ __forceinline__ float bf2f(u16 h){ return __uint_as_float(((unsigned)h) << 16); }
__device__ __forceinline__ u16 f2bf(float f){
  unsigned u = __float_as_uint(f);
  u += 0x7fffu + ((u >> 16) & 1u);
  return (u16)(u >> 16);
}
__device__ __forceinline__ unsigned pkmul(unsigned a, unsigned b){
  float a0 = __uint_as_float(a << 16), a1 = __uint_as_float(a & 0xffff0000u);
  float b0 = __uint_as_float(b << 16), b1 = __uint_as_float(b & 0xffff0000u);
  float p0 = a0*b0, p1 = a1*b1;
  unsigned r;
  asm("v_cvt_pk_bf16_f32 %0, %1, %2" : "=v"(r) : "v"(p0), "v"(p1));
  return r;
}
// permuted feature layout [start512|end512|hemb256|wemb20|pad12] -> original source row
__device__ __forceinline__ int featsrc(int k){
  if (k < 1024) return k;
  if (k < 1280) return k + 20;   // hemb: orig rows 1044..1299
  if (k < 1300) return k - 256;  // wemb: orig rows 1024..1043
  return -1;
}
// LDS layout: [128 rows][4 slots of 8 bf16]; slot c holds source k8 = c ^ ((row>>1)&3).
__device__ __forceinline__ int swz(int row, int k8){
  return row*32 + ((k8 ^ ((row >> 1) & 3)) << 3);
}
__device__ __forceinline__ void gload16(const u16* g, u16* l){
  __builtin_amdgcn_global_load_lds((const __attribute__((address_space(1))) void*)(g),
                                   (__attribute__((address_space(3))) void*)(l), 16, 0, 0);
}

// ---------------- prep: flat->bf16, padded wemb, permuted biases ----------------
__global__ __launch_bounds__(256) void k_prep(const float* __restrict__ flat,
    const float* __restrict__ wemb, const float* __restrict__ fast_b, const float* __restrict__ gate_b,
    u16* __restrict__ flatbf, u16* __restrict__ wembP, float* __restrict__ fbP, float* __restrict__ gbP)
{
  int i = blockIdx.x*256 + threadIdx.x;
  if (i < T_LEN*FLATD) flatbf[i] = f2bf(flat[i]);
  if (i < 20*32) wembP[i] = ((i & 31) < 20) ? f2bf(wemb[(i >> 5)*FEATD + (i & 31)]) : (u16)0;
  if (i < KPAD){
    int s = featsrc(i);
    fbP[i] = (s >= 0) ? fast_b[s] : 0.f;
    gbP[i] = (s >= 0) ? gate_b[s] : 0.f;
  }
}

// ---------------- head scores ----------------
__global__ __launch_bounds__(256) void k_head(const float* __restrict__ flat,
    const float* __restrict__ w, const float* __restrict__ b, float* __restrict__ hs)
{
  int lane = threadIdx.x & 63, wid = threadIdx.x >> 6;
  int row = blockIdx.x*4 + wid;
  if (row >= T_LEN) return;
  const float* x = flat + (size_t)row*FLATD;
  float s = 0.f;
  for (int j = lane; j < FLATD; j += 64) s += x[j]*w[j];
  #pragma unroll
  for (int o = 32; o; o >>= 1) s += __shfl_down(s, o, 64);
  if (lane == 0) hs[row] = s + b[0];
}

// ------------- per-candidate softmax head embedding -> bf16 (wave per candidate) -------------
__global__ __launch_bounds__(256) void k_cand(const float* __restrict__ hs,
    const float* __restrict__ hdoc, const int* __restrict__ starts, const int* __restrict__ ends,
    u16* __restrict__ hemb)
{
  int wid = threadIdx.x >> 6, lane = threadIdx.x & 63;
  int n = blockIdx.x*4 + wid;
  if (n >= NCAND) return;
  int s = starts[n], e = ends[n];
  int width = e - s + 1;
  float g[20];
  #pragma unroll
  for (int w2 = 0; w2 < 20; ++w2) g[w2] = (w2 < width) ? hs[min(s + w2, T_LEN-1)] : NEG_INF;
  float m = NEG_INF;
  #pragma unroll
  for (int w2 = 0; w2 < 20; ++w2) m = fmaxf(m, g[w2]);
  float sum = 0.f;
  #pragma unroll
  for (int w2 = 0; w2 < 20; ++w2){ g[w2] = expf(g[w2] - m); sum += g[w2]; }
  float inv = 1.f/sum;
  #pragma unroll
  for (int di = 0; di < 4; ++di){
    int d = lane + di*64;
    float acc = 0.f;
    #pragma unroll
    for (int w2 = 0; w2 < 20; ++w2)
      acc += g[w2]*hdoc[(size_t)min(s + w2, T_LEN-1)*HDD + d];
    hemb[(size_t)n*HDD + d] = f2bf(acc*inv);
  }
}

// ------------- batched weight transposes with feature permutation -------------
__global__ __launch_bounds__(256) void k_transall(const float* __restrict__ ms_w1,
    const float* __restrict__ ms_w2, const float* __restrict__ fast_w,
    const float* __restrict__ ss_w1, const float* __restrict__ ss_w2,
    const float* __restrict__ gate_w,
    u16* ms1T, u16* ms2T, u16* fastT, u16* ss1abT, u16* sspT,
    u16* ss2T, u16* gateTall)
{
  const float* B; u16* D; int Kb, N, srcN, ldD, kperm, nperm;
  switch (blockIdx.z){
    case 0: B = ms_w1; D = ms1T; Kb = KPAD; N = HIDD; srcN = HIDD; ldD = KPAD; kperm = 1; nperm = 0; break;
    case 1: B = ms_w2; D = ms2T; Kb = HIDD; N = HIDD; srcN = HIDD; ldD = HIDD; kperm = 0; nperm = 0; break;
    case 2: B = fast_w; D = fastT; Kb = KPAD; N = MENTD; srcN = MENTD; ldD = KPAD; kperm = 1; nperm = 1; break;
    case 3: B = ss_w1; D = ss1abT; Kb = KPAD; N = HIDD; srcN = HIDD; ldD = KPAD; kperm = 1; nperm = 0; break;
    case 4: B = ss_w1 + (size_t)MENTD*HIDD; D = ss1abT + (size_t)512*KPAD; Kb = KPAD; N = HIDD; srcN = HIDD; ldD = KPAD; kperm = 1; nperm = 0; break;
    case 5: B = ss_w1 + (size_t)2*MENTD*HIDD; D = sspT; Kb = KPAD; N = HIDD; srcN = HIDD; ldD = KPAD; kperm = 1; nperm = 0; break;
    case 6: B = ss_w2; D = ss2T; Kb = HIDD; N = HIDD; srcN = HIDD; ldD = HIDD; kperm = 0; nperm = 0; break;
    case 7: B = gate_w; D = gateTall; Kb = KPAD; N = MENTD; srcN = MENTD; ldD = 2*KPAD; kperm = 1; nperm = 1; break;
    default: B = gate_w + (size_t)MENTD*MENTD; D = gateTall + KPAD; Kb = KPAD; N = MENTD; srcN = MENTD; ldD = 2*KPAD; kperm = 1; nperm = 1; break;
  }
  int k0 = blockIdx.x*32, n0 = blockIdx.y*32;
  if (k0 >= Kb || n0 >= N) return;
  __shared__ float t[32][33];
  int tx = threadIdx.x & 31, ty = threadIdx.x >> 5;
  for (int r = ty; r < 32; r += 8){
    int gk = k0 + r, gn = n0 + tx;
    int sk = kperm ? featsrc(gk) : ((gk < Kb) ? gk : -1);
    int sn = nperm ? ((gn < N) ? featsrc(gn) : -1) : ((gn < N) ? gn : -1);
    t[r][tx] = (sk >= 0 && sn >= 0) ? B[(size_t)sk*srcN + sn] : 0.f;
  }
  __syncthreads();
  for (int r = ty; r < 32; r += 8){
    int gn = n0 + r, gk = k0 + tx;
    if (gn < N && gk < Kb) D[(size_t)gn*ldD + gk] = f2bf(t[tx][r]);
  }
}

// ------- mention-scorer layer1: A rows built on the fly (all-bf16 regions, gload_lds) -------
__global__ __launch_bounds__(256) void k_mfma_cand(
    const u16* __restrict__ flatbf, const u16* __restrict__ hemb, const u16* __restrict__ wembP,
    const int* __restrict__ starts, const int* __restrict__ ends,
    const u16* __restrict__ Bt, int M, const float* __restrict__ bias, u16* __restrict__ Cbf)
{
  __shared__ alignas(16) u16 As[4096];
  __shared__ alignas(16) u16 Bs[4096];
  int tid = threadIdx.x;
  int row0 = blockIdx.y*128, col0 = blockIdx.x*128;
  int lane = tid & 63, wid = tid >> 6;
  int wr = wid >> 1, wc = wid & 1;
  int l15 = lane & 15, l4 = lane >> 4;

  int s0 = tid, s1 = tid + 256;
  int r0s = s0 >> 2, c0s = s0 & 3;
  int r1s = s1 >> 2, c1s = s1 & 3;
  int k80 = (c0s ^ ((r0s >> 1) & 3)) << 3;
  int k81 = (c1s ^ ((r1s >> 1) & 3)) << 3;
  int n0r = row0 + r0s; if (n0r >= M) n0r = M - 1;
  int n1r = row0 + r1s; if (n1r >= M) n1r = M - 1;
  int sA0 = starts[n0r], eA0 = ends[n0r];
  int sA1 = starts[n1r], eA1 = ends[n1r];
  const u16* bS0 = flatbf + (size_t)sA0*FLATD;
  const u16* bE0 = flatbf + (size_t)eA0*FLATD;
  const u16* bH0 = hemb + (size_t)n0r*HDD;
  const u16* bW0 = wembP + (eA0 - sA0)*32;
  const u16* bS1 = flatbf + (size_t)sA1*FLATD;
  const u16* bE1 = flatbf + (size_t)eA1*FLATD;
  const u16* bH1p = hemb + (size_t)n1r*HDD;
  const u16* bW1 = wembP + (eA1 - sA1)*32;
  const u16* pb0 = Bt + (size_t)(col0 + r0s)*KPAD + k80;
  const u16* pb1 = Bt + (size_t)(col0 + r1s)*KPAD + k81;
  u16* la0 = As + s0*8; u16* la1 = As + s1*8;
  u16* lb0 = Bs + s0*8; u16* lb1 = Bs + s1*8;

  f32x4 acc[4][4];
  #pragma unroll
  for (int m = 0; m < 4; ++m)
    #pragma unroll
    for (int n = 0; n < 4; ++n)
      #pragma unroll
      for (int q = 0; q < 4; ++q) acc[m][n][q] = 0.f;

  for (int kt = 0; kt < KPAD/32; ++kt){
    int k0 = kt << 5;
    int f0 = k0 + k80, f1 = k0 + k81;
    const u16* src0 = (f0 < 512) ? bS0 + f0 : (f0 < 1024) ? bE0 + (f0 - 512)
                    : (f0 < 1280) ? bH0 + (f0 - 1024) : bW0 + (f0 - 1280);
    const u16* src1 = (f1 < 512) ? bS1 + f1 : (f1 < 1024) ? bE1 + (f1 - 512)
                    : (f1 < 1280) ? bH1p + (f1 - 1024) : bW1 + (f1 - 1280);
    gload16(src0, la0); gload16(src1, la1);
    gload16(pb0 + k0, lb0); gload16(pb1 + k0, lb1);
    __syncthreads();
    bf16x8 af[4], bfr[4];
    #pragma unroll
    for (int m = 0; m < 4; ++m){ int r = wr*64 + m*16 + l15; af[m] = *(const bf16x8*)(As + swz(r, l4)); }
    #pragma unroll
    for (int n = 0; n < 4; ++n){ int cc = wc*64 + n*16 + l15; bfr[n] = *(const bf16x8*)(Bs + swz(cc, l4)); }
    #pragma unroll
    for (int m = 0; m < 4; ++m)
      #pragma unroll
      for (int n = 0; n < 4; ++n)
        acc[m][n] = __builtin_amdgcn_mfma_f32_16x16x32_bf16(af[m], bfr[n], acc[m][n], 0, 0, 0);
    __syncthreads();
  }
  #pragma unroll
  for (int m = 0; m < 4; ++m){
    #pragma unroll
    for (int q = 0; q < 4; ++q){
      int grow = row0 + wr*64 + m*16 + l4*4 + q;
      if (grow >= M) continue;
      #pragma unroll
      for (int n = 0; n < 4; ++n){
        int gcol = col0 + wc*64 + n*16 + l15;
        float v = fmaxf(acc[m][n][q] + bias[gcol], 0.f);
        Cbf[(size_t)grow*HIDD + gcol] = f2bf(v);
      }
    }
  }
}

// ---------------- generic bf16 MFMA GEMM (global_load_lds staging) ----------------
__global__ __launch_bounds__(256) void k_mfma(const u16* __restrict__ A,
    const u16* __restrict__ A2, const u16* __restrict__ Bt, int M, int N, int Kp, int ldA,
    const float* __restrict__ bias, const float* __restrict__ msc,
    float* __restrict__ Cf, int ldf, u16* __restrict__ Cbf, int ldbf, int Nstore, int flags,
    const u16* __restrict__ g_att, const u16* __restrict__ g_mo)
{
  __shared__ alignas(16) u16 As[4096];
  __shared__ alignas(16) u16 Bs[4096];
  int tid = threadIdx.x;
  int row0 = blockIdx.y*128, col0 = blockIdx.x*128;
  if ((flags & MF_MASK) && col0 >= row0 + 128) return;
  int lane = tid & 63, wid = tid >> 6;
  int wr = wid >> 1, wc = wid & 1;
  int l15 = lane & 15, l4 = lane >> 4;

  int s0 = tid, s1 = tid + 256;
  int r0s = s0 >> 2, c0s = s0 & 3;
  int r1s = s1 >> 2, c1s = s1 & 3;
  int k80 = (c0s ^ ((r0s >> 1) & 3)) << 3;
  int k81 = (c1s ^ ((r1s >> 1) & 3)) << 3;
  int ra0 = row0 + r0s; if (ra0 >= M) ra0 = M - 1;
  int ra1 = row0 + r1s; if (ra1 >= M) ra1 = M - 1;
  int cb0 = col0 + r0s; if (cb0 >= N) cb0 = N - 1;
  int cb1 = col0 + r1s; if (cb1 >= N) cb1 = N - 1;
  const u16* pa0 = A + (size_t)ra0*ldA + k80;
  const u16* pa1 = A + (size_t)ra1*ldA + k81;
  int kt1 = A2 ? (ldA >> 5) : (Kp >> 5);
  int koff = kt1 << 5;
  const u16* qa0 = A2 ? (A2 + (size_t)ra0*ldA + k80 - koff) : pa0;
  const u16* qa1 = A2 ? (A2 + (size_t)ra1*ldA + k81 - koff) : pa1;
  const u16* pb0 = Bt + (size_t)cb0*Kp + k80;
  const u16* pb1 = Bt + (size_t)cb1*Kp + k81;
  u16* la0 = As + s0*8; u16* la1 = As + s1*8;
  u16* lb0 = Bs + s0*8; u16* lb1 = Bs + s1*8;

  f32x4 acc[4][4];
  #pragma unroll
  for (int m = 0; m < 4; ++m)
    #pragma unroll
    for (int n = 0; n < 4; ++n)
      #pragma unroll
      for (int q = 0; q < 4; ++q) acc[m][n][q] = 0.f;

  int nkt = Kp >> 5;
  for (int kt = 0; kt < nkt; ++kt){
    int k0 = kt << 5;
    const u16* a0 = (kt < kt1) ? pa0 : qa0;
    const u16* a1 = (kt < kt1) ? pa1 : qa1;
    gload16(a0 + k0, la0); gload16(a1 + k0, la1);
    gload16(pb0 + k0, lb0); gload16(pb1 + k0, lb1);
    __syncthreads();
    bf16x8 af[4], bfr[4];
    #pragma unroll
    for (int m = 0; m < 4; ++m){ int r = wr*64 + m*16 + l15; af[m] = *(const bf16x8*)(As + swz(r, l4)); }
    #pragma unroll
    for (int n = 0; n < 4; ++n){ int cc = wc*64 + n*16 + l15; bfr[n] = *(const bf16x8*)(Bs + swz(cc, l4)); }
    #pragma unroll
    for (int m = 0; m < 4; ++m)
      #pragma unroll
      for (int n = 0; n < 4; ++n)
        acc[m][n] = __builtin_amdgcn_mfma_f32_16x16x32_bf16(af[m], bfr[n], acc[m][n], 0, 0, 0);
    __syncthreads();
  }
  #pragma unroll
  for (int m = 0; m < 4; ++m){
    #pragma unroll
    for (int q = 0; q < 4; ++q){
      int grow = row0 + wr*64 + m*16 + l4*4 + q;
      if (grow >= M) continue;
      #pragma unroll
      for (int n = 0; n < 4; ++n){
        int gcol = col0 + wc*64 + n*16 + l15;
        if (gcol < N){
          float v = acc[m][n][q];
          if (bias) v += bias[gcol];
          if (flags & MF_MASK){ v += msc[grow] + msc[gcol]; if (gcol >= grow) v = NEG_INF; }
          if (flags & MF_RELU) v = fmaxf(v, 0.f);
          if (flags & MF_GATE){
            float f = 1.f/(1.f + expf(-v));
            float res = f*bf2f(g_att[(size_t)grow*ldbf + gcol])
                      + (1.f - f)*bf2f(g_mo[(size_t)grow*ldbf + gcol]);
            Cbf[(size_t)grow*ldbf + gcol] = f2bf(res);
          } else {
            if (Cf)  Cf[(size_t)grow*ldf + gcol] = v;
            if (Cbf) Cbf[(size_t)grow*ldbf + gcol] = f2bf(v);
          }
        } else if (Cbf && gcol < Nstore){
          Cbf[(size_t)grow*ldbf + gcol] = 0;
        }
      }
    }
  }
}

// ---- fused layer2 + w3 dot, full row per block: out[r] = sum relu(A@B + b2)*w3 + b3 (+add) ----
__global__ __launch_bounds__(256) void k_mfma_rowdot(const u16* __restrict__ A,
    const u16* __restrict__ Bt, int M, const float* __restrict__ b2,
    const float* __restrict__ w3, const float* __restrict__ b3,
    const float* __restrict__ add, float* __restrict__ out)
{
  __shared__ alignas(16) u16 As[4096];
  __shared__ alignas(16) u16 Bs[4096];
  __shared__ float rsum[128][2];
  int tid = threadIdx.x;
  int row0 = blockIdx.x*128;
  int lane = tid & 63, wid = tid >> 6;
  int wr = wid >> 1, wc = wid & 1;
  int l15 = lane & 15, l4 = lane >> 4;

  int s0 = tid, s1 = tid + 256;
  int r0s = s0 >> 2, c0s = s0 & 3;
  int r1s = s1 >> 2, c1s = s1 & 3;
  int k80 = (c0s ^ ((r0s >> 1) & 3)) << 3;
  int k81 = (c1s ^ ((r1s >> 1) & 3)) << 3;
  int ra0 = row0 + r0s; if (ra0 >= M) ra0 = M - 1;
  int ra1 = row0 + r1s; if (ra1 >= M) ra1 = M - 1;
  const u16* pa0 = A + (size_t)ra0*HIDD + k80;
  const u16* pa1 = A + (size_t)ra1*HIDD + k81;
  u16* la0 = As + s0*8; u16* la1 = As + s1*8;
  u16* lb0 = Bs + s0*8; u16* lb1 = Bs + s1*8;

  float rd[4][4] = {};
  for (int p = 0; p < 4; ++p){
    int col0 = p*128;
    const u16* pb0 = Bt + (size_t)(col0 + r0s)*HIDD + k80;
    const u16* pb1 = Bt + (size_t)(col0 + r1s)*HIDD + k81;
    f32x4 acc[4][4];
    #pragma unroll
    for (int m = 0; m < 4; ++m)
      #pragma unroll
      for (int n = 0; n < 4; ++n)
        #pragma unroll
        for (int q = 0; q < 4; ++q) acc[m][n][q] = 0.f;
    for (int kt = 0; kt < HIDD/32; ++kt){
      int k0 = kt << 5;
      gload16(pa0 + k0, la0); gload16(pa1 + k0, la1);
      gload16(pb0 + k0, lb0); gload16(pb1 + k0, lb1);
      __syncthreads();
      bf16x8 af[4], bfr[4];
      #pragma unroll
      for (int m = 0; m < 4; ++m){ int r = wr*64 + m*16 + l15; af[m] = *(const bf16x8*)(As + swz(r, l4)); }
      #pragma unroll
      for (int n = 0; n < 4; ++n){ int cc = wc*64 + n*16 + l15; bfr[n] = *(const bf16x8*)(Bs + swz(cc, l4)); }
      #pragma unroll
      for (int m = 0; m < 4; ++m)
        #pragma unroll
        for (int n = 0; n < 4; ++n)
          acc[m][n] = __builtin_amdgcn_mfma_f32_16x16x32_bf16(af[m], bfr[n], acc[m][n], 0, 0, 0);
      __syncthreads();
    }
    #pragma unroll
    for (int n = 0; n < 4; ++n){
      int gcol = col0 + wc*64 + n*16 + l15;
      float bb = b2[gcol], ww = w3[gcol];
      #pragma unroll
      for (int m = 0; m < 4; ++m)
        #pragma unroll
        for (int q = 0; q < 4; ++q){
          float v = fmaxf(acc[m][n][q] + bb, 0.f);
          rd[m][q] = fmaf(v, ww, rd[m][q]);
        }
    }
  }
  #pragma unroll
  for (int m = 0; m < 4; ++m)
    #pragma unroll
    for (int q = 0; q < 4; ++q){
      float s = rd[m][q];
      s += __shfl_xor(s, 1, 64); s += __shfl_xor(s, 2, 64);
      s += __shfl_xor(s, 4, 64); s += __shfl_xor(s, 8, 64);
      if (l15 == 0) rsum[wr*64 + m*16 + l4*4 + q][wc] = s;
    }
  __syncthreads();
  if (tid < 128){
    int gr = row0 + tid;
    if (gr < M){
      float v = rsum[tid][0] + rsum[tid][1] + b3[0];
      if (add) v += add[gr];
      out[gr] = v;
    }
  }
}

// ------- pair layer1 MFMA: A staged as ment[ri]*ment[rj] on the fly; B gload_lds -------
__global__ __launch_bounds__(256) void k_d1_mfma(int Mc,
    const u16* __restrict__ ment, const int* __restrict__ antes, const int* __restrict__ mspk,
    const u16* __restrict__ Bt, const float* __restrict__ A_meb,
    const float* __restrict__ Svec, const float* __restrict__ Dvec, const float* __restrict__ cvec,
    u16* __restrict__ H1)
{
  __shared__ alignas(16) u16 As[4096];
  __shared__ alignas(16) u16 Bs[4096];
  __shared__ int ri[128], rj[128], rsame[128], rbin[128];
  int tid = threadIdx.x;
  int row0 = blockIdx.y*128, col0 = blockIdx.x*128;
  if (tid < 128){
    int r = row0 + tid;
    int p = (r < Mc ? r : 0);
    int i = p / CANT;
    int j = antes[p];
    ri[tid] = i; rj[tid] = j;
    rsame[tid] = (mspk[i] == mspk[j]) ? 1 : 0;
    int d = i - j; d = d < 0 ? 0 : (d > 64 ? 64 : d);
    rbin[tid] = (d <= 4) ? d : (d <= 8 ? 5 : (d <= 16 ? 6 : (d <= 32 ? 7 : 8)));
  }
  __syncthreads();
  int lane = tid & 63, wid = tid >> 6;
  int wr = wid >> 1, wc = wid & 1;
  int l15 = lane & 15, l4 = lane >> 4;

  int s0 = tid, s1 = tid + 256;
  int r0s = s0 >> 2, c0s = s0 & 3;
  int r1s = s1 >> 2, c1s = s1 & 3;
  int k80 = (c0s ^ ((r0s >> 1) & 3)) << 3;
  int k81 = (c1s ^ ((r1s >> 1) & 3)) << 3;
  const u16* pb0 = Bt + (size_t)(col0 + r0s)*KPAD + k80;
  const u16* pb1 = Bt + (size_t)(col0 + r1s)*KPAD + k81;
  u16* lb0 = Bs + s0*8; u16* lb1 = Bs + s1*8;
  const u16* pi0 = ment + (size_t)ri[r0s]*KPAD + k80;
  const u16* pj0 = ment + (size_t)rj[r0s]*KPAD + k80;
  const u16* pi1 = ment + (size_t)ri[r1s]*KPAD + k81;
  const u16* pj1 = ment + (size_t)rj[r1s]*KPAD + k81;

  f32x4 acc[4][4];
  #pragma unroll
  for (int m = 0; m < 4; ++m)
    #pragma unroll
    for (int n = 0; n < 4; ++n)
      #pragma unroll
      for (int q = 0; q < 4; ++q) acc[m][n][q] = 0.f;

  int nkt = KPAD >> 5;
  for (int kt = 0; kt < nkt; ++kt){
    int k0 = kt << 5;
    gload16(pb0 + k0, lb0); gload16(pb1 + k0, lb1);
    {
      uint4 va = *(const uint4*)(pi0 + k0);
      uint4 vb = *(const uint4*)(pj0 + k0);
      uint4 vo;
      vo.x = pkmul(va.x, vb.x); vo.y = pkmul(va.y, vb.y);
      vo.z = pkmul(va.z, vb.z); vo.w = pkmul(va.w, vb.w);
      *(uint4*)(As + s0*8) = vo;
      va = *(const uint4*)(pi1 + k0);
      vb = *(const uint4*)(pj1 + k0);
      vo.x = pkmul(va.x, vb.x); vo.y = pkmul(va.y, vb.y);
      vo.z = pkmul(va.z, vb.z); vo.w = pkmul(va.w, vb.w);
      *(uint4*)(As + s1*8) = vo;
    }
    __syncthreads();
    bf16x8 af[4], bfr[4];
    #pragma unroll
    for (int m = 0; m < 4; ++m){ int r = wr*64 + m*16 + l15; af[m] = *(const bf16x8*)(As + swz(r, l4)); }
    #pragma unroll
    for (int n = 0; n < 4; ++n){ int cc = wc*64 + n*16 + l15; bfr[n] = *(const bf16x8*)(Bs + swz(cc, l4)); }
    #pragma unroll
    for (int m = 0; m < 4; ++m)
      #pragma unroll
      for (int n = 0; n < 4; ++n)
        acc[m][n] = __builtin_amdgcn_mfma_f32_16x16x32_bf16(af[m], bfr[n], acc[m][n], 0, 0, 0);
    __syncthreads();
  }
  #pragma unroll
  for (int m = 0; m < 4; ++m){
    #pragma unroll
    for (int q = 0; q < 4; ++q){
      int rl = wr*64 + m*16 + l4*4 + q;
      int grow = row0 + rl;
      if (grow >= Mc) continue;
      const float* me = A_meb + (size_t)ri[rl]*1024;
      const float* an = A_meb + (size_t)rj[rl]*1024 + 512;
      const float* sv = Svec + rsame[rl]*HIDD;
      const float* dv = Dvec + rbin[rl]*HIDD;
      #pragma unroll
      for (int n = 0; n < 4; ++n){
        int gcol = col0 + wc*64 + n*16 + l15;
        float v = acc[m][n][q] + me[gcol] + an[gcol] + sv[gcol] + dv[gcol] + cvec[gcol];
        H1[(size_t)grow*HIDD + gcol] = f2bf(fmaxf(v, 0.f));
      }
    }
  }
}

// ================= top-K selection pipeline (multi-kernel, multi-CU) =================
// selws int layout: [0..2047] binA | [2048..4095] binB | [4096..6143] binC | [6144..6151] meta | [6152..6155] cnt
__global__ __launch_bounds__(256) void k_selzero(unsigned* selws){
  int i = blockIdx.x*256 + threadIdx.x;
  if (i < 6156) selws[i] = 0;
}
__global__ __launch_bounds__(256) void k_hist(const float* __restrict__ scores,
    unsigned* __restrict__ selws, int pass)
{
  int n = blockIdx.x*256 + threadIdx.x;
  if (n >= NCAND) return;
  unsigned u = ordf(scores[n]);
  const unsigned* meta = selws + 6144;
  if (pass == 0) atomicAdd(&selws[u >> 21], 1u);
  else if (pass == 1){ if ((u >> 21) == meta[0]) atomicAdd(&selws[2048 + ((u >> 10) & 0x7FFu)], 1u); }
  else { if ((u >> 10) == meta[2]) atomicAdd(&selws[4096 + (u & 0x3FFu)], 1u); }
}
__global__ __launch_bounds__(1024) void k_thresh(unsigned* __restrict__ selws, int mode){
  __shared__ unsigned a[2048], b[2048];
  int tid = threadIdx.x;
  unsigned* meta = selws + 6144;
  const unsigned* gbin = selws + (mode == 0 ? 0 : (mode == 1 ? 2048 : 4096));
  unsigned target = (mode == 0) ? (unsigned)KSEL : meta[mode == 1 ? 1 : 3];
  a[tid] = gbin[tid]; a[tid + 1024] = gbin[tid + 1024];
  unsigned *src = a, *dst = b;
  for (int step = 1; step < 2048; step <<= 1){
    __syncthreads();
    for (int i = tid; i < 2048; i += 1024)
      dst[i] = src[i] + ((i + step < 2048) ? src[i + step] : 0u);
    unsigned* t2 = src; src = dst; dst = t2;
  }
  __syncthreads();
  for (int i = tid; i < 2048; i += 1024){
    unsigned si = src[i], sn = (i < 2047) ? src[i+1] : 0u;
    if (si >= target && sn < target){
      if (mode == 0){ meta[0] = (unsigned)i; meta[1] = target - sn; }
      else if (mode == 1){ meta[2] = (meta[0] << 11) | (unsigned)i; meta[3] = target - sn; }
      else { meta[4] = (meta[2] << 10) | (unsigned)i; meta[5] = target - sn; }
    }
  }
}
__global__ __launch_bounds__(256) void k_compact(const float* __restrict__ scores,
    unsigned* __restrict__ selws, int* __restrict__ g_sel, unsigned* __restrict__ g_eq)
{
  int n = blockIdx.x*256 + threadIdx.x;
  if (n >= NCAND) return;
  unsigned kth = selws[6144 + 4];
  unsigned* cnt = selws + 6152;
  unsigned u = ordf(scores[n]);
  if (u > kth){ unsigned p = atomicAdd(&cnt[0], 1u); g_sel[p] = n; }
  else if (u == kth){ unsigned p = atomicAdd(&cnt[1], 1u); if (p < 1024) g_eq[p] = (unsigned)n; }
}
__global__ __launch_bounds__(1024) void k_eqrank(unsigned* __restrict__ selws,
    const unsigned* __restrict__ g_eq, int* __restrict__ g_sel)
{
  __shared__ unsigned eq[1024];
  int tid = threadIdx.x;
  unsigned neq = selws[6152 + 1]; if (neq > 1024u) neq = 1024u;
  unsigned E = selws[6144 + 5];
  unsigned G = selws[6152 + 0];
  eq[tid] = (tid < (int)neq) ? g_eq[tid] : 0xFFFFFFFFu;
  __syncthreads();
  if (tid < (int)neq){
    unsigned mine = eq[tid]; unsigned r = 0;
    for (unsigned j = 0; j < neq; ++j) r += (eq[j] < mine) ? 1u : 0u;
    if (r < E) g_sel[G + r] = (int)mine;
  }
}
// rank selected by (-score, idx): ranked[r] = n  (7 blocks x 256)
__global__ __launch_bounds__(256) void k_rank1(const float* __restrict__ scores,
    const int* __restrict__ g_sel, int* __restrict__ ranked)
{
  __shared__ unsigned long long key[KSEL];
  int tid = threadIdx.x;
  for (int t = tid; t < KSEL; t += 256){
    int n = g_sel[t];
    key[t] = ((unsigned long long)(~ordf(scores[n])) << 32) | (unsigned)n;
  }
  __syncthreads();
  int t = blockIdx.x*256 + tid;
  if (t >= KSEL) return;
  unsigned long long mine = key[t];
  int r = 0;
  #pragma unroll 16
  for (int j = 0; j < KSEL; ++j) r += (key[j] < mine) ? 1 : 0;
  ranked[r] = (int)(mine & 0xFFFFFFFFu);
}
// rank by (ment_pos, prev-rank): top_idx[r] = ranked[t]
__global__ __launch_bounds__(256) void k_rank2(const int* __restrict__ ranked,
    const int* __restrict__ starts, const int* __restrict__ ends, int* __restrict__ top_idx)
{
  __shared__ unsigned long long key[KSEL];
  int tid = threadIdx.x;
  int elast = ends[NCAND-1];
  for (int t = tid; t < KSEL; t += 256){
    int n = ranked[t];
    unsigned mp = (unsigned)(starts[n]*elast + ends[n]);
    key[t] = ((unsigned long long)mp << 11) | (unsigned)t;
  }
  __syncthreads();
  int t = blockIdx.x*256 + tid;
  if (t >= KSEL) return;
  unsigned long long mine = key[t];
  int r = 0;
  #pragma unroll 16
  for (int j = 0; j < KSEL; ++j) r += (key[j] < mine) ? 1 : 0;
  top_idx[r] = ranked[t];
}

// ---------------- gather mention rows -> bf16 [KSEL][KPAD], permuted layout ----------------
__global__ __launch_bounds__(256) void k_gather(const int* __restrict__ top_idx,
    const u16* __restrict__ flatbf, const u16* __restrict__ hemb, const u16* __restrict__ wembP,
    const int* __restrict__ starts, const int* __restrict__ ends,
    const float* __restrict__ cscores, const int* __restrict__ spk_ids,
    u16* __restrict__ ment, float* __restrict__ mscore, int* __restrict__ mspk)
{
  int k = blockIdx.x; int n = top_idx[k];
  int s = starts[n], e = ends[n];
  int v = threadIdx.x;
  if (v < KPAD/8){
    int f0 = v*8;
    const u16* src = (f0 < 512) ? flatbf + (size_t)s*FLATD + f0
                   : (f0 < 1024) ? flatbf + (size_t)e*FLATD + (f0 - 512)
                   : (f0 < 1280) ? hemb + (size_t)n*HDD + (f0 - 1024)
                   : wembP + (e - s)*32 + (f0 - 1280);
    *(uint4*)(ment + (size_t)k*KPAD + f0) = *(const uint4*)src;
  }
  if (threadIdx.x == 0){ mscore[k] = cscores[n]; mspk[k] = spk_ids[s]; }
}

// ---------------- per-row top-40, wave-per-row, register keys ----------------
__global__ __launch_bounds__(256) void k_f3(const float* __restrict__ fast,
    float* __restrict__ top_fast, int* __restrict__ antes)
{
  int wid = threadIdx.x >> 6, lane = threadIdx.x & 63;
  int i = blockIdx.x*4 + wid;
  if (i >= KSEL) return;
  const float* row = fast + (size_t)i*KSEL;
  unsigned long long key[26];
  #pragma unroll
  for (int t = 0; t < 26; ++t){
    int j = lane + (t << 6);
    unsigned long long k2 = 0ULL;
    if (j < i) k2 = ((unsigned long long)ordf(row[j]) << 32) | (unsigned)(0xFFFFFFFFu - (unsigned)j);
    key[t] = k2;
  }
  for (int c = 0; c < CANT; ++c){
    unsigned long long m = 0ULL;
    #pragma unroll
    for (int t = 0; t < 26; ++t) if (key[t] > m) m = key[t];
    #pragma unroll
    for (int o = 32; o; o >>= 1){
      unsigned long long v = __shfl_xor(m, o, 64);
      if (v > m) m = v;
    }
    if (m){
      #pragma unroll
      for (int t = 0; t < 26; ++t) if (key[t] == m) key[t] = 0ULL;
    }
    if (lane == 0){
      if (m){
        top_fast[(size_t)i*CANT + c] = unordf((unsigned)(m >> 32));
        antes[(size_t)i*CANT + c]    = (int)(0xFFFFFFFFu - (unsigned)(m & 0xFFFFFFFFu));
      } else {
        top_fast[(size_t)i*CANT + c] = NEG_INF;
        antes[(size_t)i*CANT + c]    = c;
      }
    }
  }
}

// ------- small precomputes -------
__global__ __launch_bounds__(256) void k_dsmall(const float* __restrict__ ss_w1,
    const float* __restrict__ ss_b1, const float* __restrict__ spk_emb,
    const float* __restrict__ gen_emb, const float* __restrict__ dist_emb,
    const int* __restrict__ genre_id, float* __restrict__ Svec, float* __restrict__ Dvec,
    float* __restrict__ cvec)
{
  int r = blockIdx.x;
  for (int h = threadIdx.x; h < HIDD; h += 256){
    const float* e; const float* wb; float acc;
    if (r < 2){ e = spk_emb + r*FEATD; wb = ss_w1 + (size_t)3900*HIDD; acc = 0.f; }
    else if (r < 11){ e = dist_emb + (r-2)*FEATD; wb = ss_w1 + (size_t)3940*HIDD; acc = 0.f; }
    else { e = gen_emb + genre_id[0]*FEATD; wb = ss_w1 + (size_t)3920*HIDD; acc = ss_b1[h]; }
    for (int f = 0; f < FEATD; ++f) acc += e[f]*wb[(size_t)f*HIDD + h];
    if (r < 2) Svec[r*HIDD + h] = acc;
    else if (r < 11) Dvec[(r-2)*HIDD + h] = acc;
    else cvec[h] = acc;
  }
}

// ---------------- softmax over [0, ante_scores] + attended -> bf16 ----------------
__global__ __launch_bounds__(256) void k_d4a(const float* __restrict__ ante_sc,
    const int* __restrict__ antes, const u16* __restrict__ ment, u16* __restrict__ att_bf)
{
  int i = blockIdx.x;
  __shared__ float w[CANT+1];
  __shared__ int aj[CANT];
  if (threadIdx.x == 0){
    float s[CANT]; float m = 0.f;
    #pragma unroll
    for (int c = 0; c < CANT; ++c){ s[c] = ante_sc[i*CANT + c]; m = fmaxf(m, s[c]); }
    float e0 = expf(0.f - m);
    float sum = e0;
    float ex[CANT];
    #pragma unroll
    for (int c = 0; c < CANT; ++c){ ex[c] = expf(s[c] - m); sum += ex[c]; }
    float inv = 1.f/sum;
    w[0] = e0*inv;
    #pragma unroll
    for (int c = 0; c < CANT; ++c) w[c+1] = ex[c]*inv;
  }
  if (threadIdx.x < CANT) aj[threadIdx.x] = antes[i*CANT + threadIdx.x];
  __syncthreads();
  for (int d = threadIdx.x; d < KPAD; d += 256){
    if (d < MENTD){
      float acc = w[0]*bf2f(ment[(size_t)i*KPAD + d]);
      for (int c = 0; c < CANT; ++c) acc += w[c+1]*bf2f(ment[(size_t)aj[c]*KPAD + d]);
      att_bf[(size_t)i*KPAD + d] = f2bf(acc);
    } else att_bf[(size_t)i*KPAD + d] = 0;
  }
}

// ---------------- final output (sanitize non-finite) ----------------
__global__ __launch_bounds__(256) void k_out(const float* __restrict__ ante_sc, float* __restrict__ out){
  int idx = blockIdx.x*256 + threadIdx.x;
  if (idx >= KSEL*41) return;
  int i = idx / 41, c = idx % 41;
  float v = (c == 0) ? 0.f : ante_sc[i*CANT + (c-1)];
  if (!isfinite(v)) v = -3.0e38f;
  out[idx] = v;
}

__global__ void k_zero(float* out, int n){
  int i = blockIdx.x*256 + threadIdx.x;
  if (i < n) out[i] = 0.f;
}

extern "C" void kernel_launch(void* const* d_in, const int* in_sizes, int n_in,
                              void* d_out, int out_size, void* d_ws, size_t ws_size,
                              hipStream_t stream)
{
  const float* flat   = (const float*)d_in[0];
  const float* hdoc   = (const float*)d_in[1];
  const float* w_head = (const float*)d_in[2];
  const float* b_head = (const float*)d_in[3];
  const float* wemb   = (const float*)d_in[4];
  const float* ms_w1  = (const float*)d_in[5];
  const float* ms_b1  = (const float*)d_in[6];
  const float* ms_w2  = (const float*)d_in[7];
  const float* ms_b2  = (const float*)d_in[8];
  const float* ms_w3  = (const float*)d_in[9];
  const float* ms_b3  = (const float*)d_in[10];
  const float* fast_w = (const float*)d_in[11];
  const float* fast_b = (const float*)d_in[12];
  const float* ss_w1  = (const float*)d_in[13];
  const float* ss_b1  = (const float*)d_in[14];
  const float* ss_w2  = (const float*)d_in[15];
  const float* ss_b2  = (const float*)d_in[16];
  const float* ss_w3  = (const float*)d_in[17];
  const float* ss_b3  = (const float*)d_in[18];
  const float* gate_w = (const float*)d_in[19];
  const float* gate_b = (const float*)d_in[20];
  const float* spk_e  = (const float*)d_in[21];
  const float* gen_e  = (const float*)d_in[22];
  const float* dist_e = (const float*)d_in[23];
  const int* starts   = (const int*)d_in[24];
  const int* ends     = (const int*)d_in[25];
  const int* spk_ids  = (const int*)d_in[26];
  const int* genre_id = (const int*)d_in[27];
  float* out = (float*)d_out;

  size_t off = 0;
  char* base = (char*)d_ws;
  auto alloc = [&](size_t nbytes) -> void* {
    void* p = (void*)(base + off);
    off += ((nbytes + 255)/256)*256;
    return p;
  };
  float* head_sc = (float*)alloc((size_t)T_LEN*4);
  u16*   flatbf  = (u16*)alloc((size_t)T_LEN*FLATD*2);
  u16*   wembP   = (u16*)alloc((size_t)20*32*2);
  float* fbP     = (float*)alloc((size_t)KPAD*4);
  float* gbP     = (float*)alloc((size_t)KPAD*4);
  u16*   hemb    = (u16*)alloc((size_t)NCAND*HDD*2);
  float* cscores = (float*)alloc((size_t)NCAND*4);
  int*   top_idx = (int*)alloc(2048*4);
  unsigned* selws= (unsigned*)alloc(6160*4);
  int*   g_sel   = (int*)alloc((size_t)KSEL*4);
  unsigned* g_eq = (unsigned*)alloc(1024*4);
  int*   g_rank  = (int*)alloc((size_t)KSEL*4);
  u16*   ms1T    = (u16*)alloc((size_t)HIDD*KPAD*2);
  u16*   ms2T    = (u16*)alloc((size_t)HIDD*HIDD*2);
  u16*   fastT   = (u16*)alloc((size_t)MENTD*KPAD*2);
  u16*   ss1abT  = (u16*)alloc((size_t)1024*KPAD*2);
  u16*   sspT    = (u16*)alloc((size_t)HIDD*KPAD*2);
  u16*   ss2T    = (u16*)alloc((size_t)HIDD*HIDD*2);
  u16*   gateTall= (u16*)alloc((size_t)MENTD*2*KPAD*2);
  u16*   ment    = (u16*)alloc((size_t)KSEL*KPAD*2);
  u16*   mentB   = (u16*)alloc((size_t)KSEL*KPAD*2);
  u16*   srcb    = (u16*)alloc((size_t)KSEL*KPAD*2);
  float* mscore  = (float*)alloc((size_t)KSEL*4);
  int*   mspk    = (int*)alloc((size_t)KSEL*4);
  float* fastm   = (float*)alloc((size_t)KSEL*KSEL*4);
  float* top_fast= (float*)alloc((size_t)NPAIR*4);
  int*   antes   = (int*)alloc((size_t)NPAIR*4);
  float* ante_sc = (float*)alloc((size_t)NPAIR*4);
  float* A_meb   = (float*)alloc((size_t)KSEL*1024*4);
  float* Svec    = (float*)alloc(2*HIDD*4);
  float* Dvec    = (float*)alloc(9*HIDD*4);
  float* cvec    = (float*)alloc(HIDD*4);
  u16*   att_bf  = (u16*)alloc((size_t)KSEL*KPAD*2);
  u16*   bufH1   = (u16*)alloc((size_t)NPAIR*HIDD*2);

  if (ws_size < off){
    k_zero<<<(KSEL*41 + 255)/256, 256, 0, stream>>>(out, KSEL*41);
    return;
  }

  k_prep<<<(T_LEN*FLATD + 255)/256, 256, 0, stream>>>(flat, wemb, fast_b, gate_b,
                                                      flatbf, wembP, fbP, gbP);
  k_transall<<<dim3(KPAD/32, 41, 9), 256, 0, stream>>>(ms_w1, ms_w2, fast_w, ss_w1, ss_w2, gate_w,
      ms1T, ms2T, fastT, ss1abT, sspT, ss2T, gateTall);

  k_head<<<T_LEN/4, 256, 0, stream>>>(flat, w_head, b_head, head_sc);
  k_cand<<<NCAND/4, 256, 0, stream>>>(head_sc, hdoc, starts, ends, hemb);

  // mention scorer (single pass over 30000 rows)
  k_mfma_cand<<<dim3(HIDD/128, (NCAND + 127)/128), 256, 0, stream>>>(
      flatbf, hemb, wembP, starts, ends, ms1T, NCAND, ms_b1, bufH1);
  k_mfma_rowdot<<<(NCAND + 127)/128, 256, 0, stream>>>(bufH1, ms2T, NCAND, ms_b2, ms_w3, ms_b3,
                                                       nullptr, cscores);

  // top-K selection pipeline
  k_selzero<<<25, 256, 0, stream>>>(selws);
  k_hist<<<(NCAND + 255)/256, 256, 0, stream>>>(cscores, selws, 0);
  k_thresh<<<1, 1024, 0, stream>>>(selws, 0);
  k_hist<<<(NCAND + 255)/256, 256, 0, stream>>>(cscores, selws, 1);
  k_thresh<<<1, 1024, 0, stream>>>(selws, 1);
  k_hist<<<(NCAND + 255)/256, 256, 0, stream>>>(cscores, selws, 2);
  k_thresh<<<1, 1024, 0, stream>>>(selws, 2);
  k_compact<<<(NCAND + 255)/256, 256, 0, stream>>>(cscores, selws, g_sel, g_eq);
  k_eqrank<<<1, 1024, 0, stream>>>(selws, g_eq, g_sel);
  k_rank1<<<(KSEL + 255)/256, 256, 0, stream>>>(cscores, g_sel, g_rank);
  k_rank2<<<(KSEL + 255)/256, 256, 0, stream>>>(g_rank, starts, ends, top_idx);

  k_gather<<<KSEL, 256, 0, stream>>>(top_idx, flatbf, hemb, wembP, starts, ends, cscores, spk_ids,
                                     ment, mscore, mspk);

  // fast antecedent scores
  k_mfma<<<dim3((MENTD+127)/128, (KSEL+127)/128), 256, 0, stream>>>(
      ment, nullptr, fastT, KSEL, MENTD, KPAD, KPAD, fbP, nullptr,
      nullptr, 0, srcb, KPAD, KPAD, 0, nullptr, nullptr);
  k_mfma<<<dim3((KSEL+127)/128, (KSEL+127)/128), 256, 0, stream>>>(
      srcb, nullptr, ment, KSEL, KSEL, KPAD, KPAD, nullptr, mscore,
      fastm, KSEL, nullptr, 0, 0, MF_MASK, nullptr, nullptr);
  k_f3<<<(KSEL+3)/4, 256, 0, stream>>>(fastm, top_fast, antes);

  k_dsmall<<<12, 256, 0, stream>>>(ss_w1, ss_b1, spk_e, gen_e, dist_e, genre_id, Svec, Dvec, cvec);

  const u16* mcur = ment;
  for (int iter = 0; iter < 2; ++iter){
    k_mfma<<<dim3(8, (KSEL+127)/128), 256, 0, stream>>>(
        mcur, nullptr, ss1abT, KSEL, 1024, KPAD, KPAD, nullptr, nullptr,
        A_meb, 1024, nullptr, 0, 0, 0, nullptr, nullptr);
    k_d1_mfma<<<dim3(HIDD/128, (NPAIR + 127)/128), 256, 0, stream>>>(
        NPAIR, mcur, antes, mspk, sspT, A_meb, Svec, Dvec, cvec, bufH1);
    k_mfma_rowdot<<<(NPAIR + 127)/128, 256, 0, stream>>>(bufH1, ss2T, NPAIR, ss_b2, ss_w3, ss_b3,
                                                         top_fast, ante_sc);
    if (iter == 0){
      k_d4a<<<KSEL, 256, 0, stream>>>(ante_sc, antes, mcur, att_bf);
      k_mfma<<<dim3((MENTD+127)/128, (KSEL+127)/128), 256, 0, stream>>>(
          ment, att_bf, gateTall, KSEL, MENTD, 2*KPAD, KPAD, gbP, nullptr,
          nullptr, 0, mentB, KPAD, KPAD, MF_GATE, att_bf, ment);
      mcur = mentB;
    }
  }

  k_out<<<(KSEL*41 + 255)/256, 256, 0, stream>>>(ante_sc, out);
}

// Round 7
// 1261.731 us; speedup vs baseline: 7.1296x; 1.0754x over previous
//
#include <hip/hip_runtime.h>
#include <math.h>

#define T_LEN 4096
#define FLATD 512
#define HDD 256
#define FEATD 20
#define NCAND 30000
#define HIDD 512
#define KSEL 1638
#define CANT 40
#define MENTD 1300
#define KPAD 1312
#define NPAIR (KSEL*CANT)
#define NEG_INF (-__builtin_inff())

#define MF_RELU 1
#define MF_MASK 4
#define MF_GATE 8

typedef unsigned short u16;
typedef __attribute__((ext_vector_type(8))) short bf16x8;
typedef __attribute__((ext_vector_type(4))) float f32x4;

__device__ __forceinline__ unsigned ordf(float f){
  unsigned u = __float_as_uint(f);
  return (u & 0x80000000u) ? ~u : (u | 0x80000000u);
}
__device__ __forceinline__ float unordf(unsigned u){
  return __uint_as_float((u & 0x80000000u) ? (u ^ 0x80000000u) : ~u);
}
__device__ __forceinline__ float bf2f(u16 h){ return __uint_as_float(((unsigned)h) << 16); }
__device__ __forceinline__ u16 f2bf(float f){
  unsigned u = __float_as_uint(f);
  u += 0x7fffu + ((u >> 16) & 1u);
  return (u16)(u >> 16);
}
__device__ __forceinline__ unsigned pkmul(unsigned a, unsigned b){
  float a0 = __uint_as_float(a << 16), a1 = __uint_as_float(a & 0xffff0000u);
  float b0 = __uint_as_float(b << 16), b1 = __uint_as_float(b & 0xffff0000u);
  float p0 = a0*b0, p1 = a1*b1;
  unsigned r;
  asm("v_cvt_pk_bf16_f32 %0, %1, %2" : "=v"(r) : "v"(p0), "v"(p1));
  return r;
}
// permuted feature layout [start512|end512|hemb256|wemb20|pad12] -> original source row
__device__ __forceinline__ int featsrc(int k){
  if (k < 1024) return k;
  if (k < 1280) return k + 20;
  if (k < 1300) return k - 256;
  return -1;
}
// LDS layout: [rows][4 slots of 8 bf16]; slot c holds source k8 = c ^ ((row>>1)&3).
__device__ __forceinline__ int swz(int row, int k8){
  return row*32 + ((k8 ^ ((row >> 1) & 3)) << 3);
}
__device__ __forceinline__ void gload16(const u16* g, u16* l){
  __builtin_amdgcn_global_load_lds((const __attribute__((address_space(1))) void*)(g),
                                   (__attribute__((address_space(3))) void*)(l), 16, 0, 0);
}

// ---------------- prep: flat->bf16, padded wemb, permuted biases, selws zero ----------------
__global__ __launch_bounds__(256) void k_prep(const float* __restrict__ flat,
    const float* __restrict__ wemb, const float* __restrict__ fast_b, const float* __restrict__ gate_b,
    u16* __restrict__ flatbf, u16* __restrict__ wembP, float* __restrict__ fbP, float* __restrict__ gbP,
    unsigned* __restrict__ selws)
{
  int i = blockIdx.x*256 + threadIdx.x;
  if (i < T_LEN*FLATD) flatbf[i] = f2bf(flat[i]);
  if (i < 20*32) wembP[i] = ((i & 31) < 20) ? f2bf(wemb[(i >> 5)*FEATD + (i & 31)]) : (u16)0;
  if (i < KPAD){
    int s = featsrc(i);
    fbP[i] = (s >= 0) ? fast_b[s] : 0.f;
    gbP[i] = (s >= 0) ? gate_b[s] : 0.f;
  }
  if (i < 6156) selws[i] = 0;
}

// ---------------- head scores ----------------
__global__ __launch_bounds__(256) void k_head(const float* __restrict__ flat,
    const float* __restrict__ w, const float* __restrict__ b, float* __restrict__ hs)
{
  int lane = threadIdx.x & 63, wid = threadIdx.x >> 6;
  int row = blockIdx.x*4 + wid;
  if (row >= T_LEN) return;
  const float* x = flat + (size_t)row*FLATD;
  float s = 0.f;
  for (int j = lane; j < FLATD; j += 64) s += x[j]*w[j];
  #pragma unroll
  for (int o = 32; o; o >>= 1) s += __shfl_down(s, o, 64);
  if (lane == 0) hs[row] = s + b[0];
}

// ------------- per-candidate softmax head embedding -> bf16 (wave per candidate) -------------
__global__ __launch_bounds__(256) void k_cand(const float* __restrict__ hs,
    const float* __restrict__ hdoc, const int* __restrict__ starts, const int* __restrict__ ends,
    u16* __restrict__ hemb)
{
  int wid = threadIdx.x >> 6, lane = threadIdx.x & 63;
  int n = blockIdx.x*4 + wid;
  if (n >= NCAND) return;
  int s = starts[n], e = ends[n];
  int width = e - s + 1;
  float g[20];
  #pragma unroll
  for (int w2 = 0; w2 < 20; ++w2) g[w2] = (w2 < width) ? hs[min(s + w2, T_LEN-1)] : NEG_INF;
  float m = NEG_INF;
  #pragma unroll
  for (int w2 = 0; w2 < 20; ++w2) m = fmaxf(m, g[w2]);
  float sum = 0.f;
  #pragma unroll
  for (int w2 = 0; w2 < 20; ++w2){ g[w2] = expf(g[w2] - m); sum += g[w2]; }
  float inv = 1.f/sum;
  #pragma unroll
  for (int di = 0; di < 4; ++di){
    int d = lane + di*64;
    float acc = 0.f;
    #pragma unroll
    for (int w2 = 0; w2 < 20; ++w2)
      acc += g[w2]*hdoc[(size_t)min(s + w2, T_LEN-1)*HDD + d];
    hemb[(size_t)n*HDD + d] = f2bf(acc*inv);
  }
}

// ------------- batched weight transposes with feature permutation -------------
__global__ __launch_bounds__(256) void k_transall(const float* __restrict__ ms_w1,
    const float* __restrict__ ms_w2, const float* __restrict__ fast_w,
    const float* __restrict__ ss_w1, const float* __restrict__ ss_w2,
    const float* __restrict__ gate_w,
    u16* ms1T, u16* ms2T, u16* fastT, u16* ss1abT, u16* sspT,
    u16* ss2T, u16* gateTall)
{
  const float* B; u16* D; int Kb, N, srcN, ldD, kperm, nperm;
  switch (blockIdx.z){
    case 0: B = ms_w1; D = ms1T; Kb = KPAD; N = HIDD; srcN = HIDD; ldD = KPAD; kperm = 1; nperm = 0; break;
    case 1: B = ms_w2; D = ms2T; Kb = HIDD; N = HIDD; srcN = HIDD; ldD = HIDD; kperm = 0; nperm = 0; break;
    case 2: B = fast_w; D = fastT; Kb = KPAD; N = MENTD; srcN = MENTD; ldD = KPAD; kperm = 1; nperm = 1; break;
    case 3: B = ss_w1; D = ss1abT; Kb = KPAD; N = HIDD; srcN = HIDD; ldD = KPAD; kperm = 1; nperm = 0; break;
    case 4: B = ss_w1 + (size_t)MENTD*HIDD; D = ss1abT + (size_t)512*KPAD; Kb = KPAD; N = HIDD; srcN = HIDD; ldD = KPAD; kperm = 1; nperm = 0; break;
    case 5: B = ss_w1 + (size_t)2*MENTD*HIDD; D = sspT; Kb = KPAD; N = HIDD; srcN = HIDD; ldD = KPAD; kperm = 1; nperm = 0; break;
    case 6: B = ss_w2; D = ss2T; Kb = HIDD; N = HIDD; srcN = HIDD; ldD = HIDD; kperm = 0; nperm = 0; break;
    case 7: B = gate_w; D = gateTall; Kb = KPAD; N = MENTD; srcN = MENTD; ldD = 2*KPAD; kperm = 1; nperm = 1; break;
    default: B = gate_w + (size_t)MENTD*MENTD; D = gateTall + KPAD; Kb = KPAD; N = MENTD; srcN = MENTD; ldD = 2*KPAD; kperm = 1; nperm = 1; break;
  }
  int k0 = blockIdx.x*32, n0 = blockIdx.y*32;
  if (k0 >= Kb || n0 >= N) return;
  __shared__ float t[32][33];
  int tx = threadIdx.x & 31, ty = threadIdx.x >> 5;
  for (int r = ty; r < 32; r += 8){
    int gk = k0 + r, gn = n0 + tx;
    int sk = kperm ? featsrc(gk) : ((gk < Kb) ? gk : -1);
    int sn = nperm ? ((gn < N) ? featsrc(gn) : -1) : ((gn < N) ? gn : -1);
    t[r][tx] = (sk >= 0 && sn >= 0) ? B[(size_t)sk*srcN + sn] : 0.f;
  }
  __syncthreads();
  for (int r = ty; r < 32; r += 8){
    int gn = n0 + r, gk = k0 + tx;
    if (gn < N && gk < Kb) D[(size_t)gn*ldD + gk] = f2bf(t[tx][r]);
  }
}

// ------- mention-scorer layer1: A rows built on the fly (all-bf16 regions, gload_lds) -------
__global__ __launch_bounds__(256) void k_mfma_cand(
    const u16* __restrict__ flatbf, const u16* __restrict__ hemb, const u16* __restrict__ wembP,
    const int* __restrict__ starts, const int* __restrict__ ends,
    const u16* __restrict__ Bt, int M, const float* __restrict__ bias, u16* __restrict__ Cbf)
{
  __shared__ alignas(16) u16 As[4096];
  __shared__ alignas(16) u16 Bs[4096];
  int tid = threadIdx.x;
  int row0 = blockIdx.y*128, col0 = blockIdx.x*128;
  int lane = tid & 63, wid = tid >> 6;
  int wr = wid >> 1, wc = wid & 1;
  int l15 = lane & 15, l4 = lane >> 4;

  int s0 = tid, s1 = tid + 256;
  int r0s = s0 >> 2, c0s = s0 & 3;
  int r1s = s1 >> 2, c1s = s1 & 3;
  int k80 = (c0s ^ ((r0s >> 1) & 3)) << 3;
  int k81 = (c1s ^ ((r1s >> 1) & 3)) << 3;
  int n0r = row0 + r0s; if (n0r >= M) n0r = M - 1;
  int n1r = row0 + r1s; if (n1r >= M) n1r = M - 1;
  int sA0 = starts[n0r], eA0 = ends[n0r];
  int sA1 = starts[n1r], eA1 = ends[n1r];
  const u16* bS0 = flatbf + (size_t)sA0*FLATD;
  const u16* bE0 = flatbf + (size_t)eA0*FLATD;
  const u16* bH0 = hemb + (size_t)n0r*HDD;
  const u16* bW0 = wembP + (eA0 - sA0)*32;
  const u16* bS1 = flatbf + (size_t)sA1*FLATD;
  const u16* bE1 = flatbf + (size_t)eA1*FLATD;
  const u16* bH1p = hemb + (size_t)n1r*HDD;
  const u16* bW1 = wembP + (eA1 - sA1)*32;
  const u16* pb0 = Bt + (size_t)(col0 + r0s)*KPAD + k80;
  const u16* pb1 = Bt + (size_t)(col0 + r1s)*KPAD + k81;
  u16* la0 = As + s0*8; u16* la1 = As + s1*8;
  u16* lb0 = Bs + s0*8; u16* lb1 = Bs + s1*8;

  f32x4 acc[4][4];
  #pragma unroll
  for (int m = 0; m < 4; ++m)
    #pragma unroll
    for (int n = 0; n < 4; ++n)
      #pragma unroll
      for (int q = 0; q < 4; ++q) acc[m][n][q] = 0.f;

  for (int kt = 0; kt < KPAD/32; ++kt){
    int k0 = kt << 5;
    int f0 = k0 + k80, f1 = k0 + k81;
    const u16* src0 = (f0 < 512) ? bS0 + f0 : (f0 < 1024) ? bE0 + (f0 - 512)
                    : (f0 < 1280) ? bH0 + (f0 - 1024) : bW0 + (f0 - 1280);
    const u16* src1 = (f1 < 512) ? bS1 + f1 : (f1 < 1024) ? bE1 + (f1 - 512)
                    : (f1 < 1280) ? bH1p + (f1 - 1024) : bW1 + (f1 - 1280);
    gload16(src0, la0); gload16(src1, la1);
    gload16(pb0 + k0, lb0); gload16(pb1 + k0, lb1);
    __syncthreads();
    bf16x8 af[4], bfr[4];
    #pragma unroll
    for (int m = 0; m < 4; ++m){ int r = wr*64 + m*16 + l15; af[m] = *(const bf16x8*)(As + swz(r, l4)); }
    #pragma unroll
    for (int n = 0; n < 4; ++n){ int cc = wc*64 + n*16 + l15; bfr[n] = *(const bf16x8*)(Bs + swz(cc, l4)); }
    #pragma unroll
    for (int m = 0; m < 4; ++m)
      #pragma unroll
      for (int n = 0; n < 4; ++n)
        acc[m][n] = __builtin_amdgcn_mfma_f32_16x16x32_bf16(af[m], bfr[n], acc[m][n], 0, 0, 0);
    __syncthreads();
  }
  #pragma unroll
  for (int m = 0; m < 4; ++m){
    #pragma unroll
    for (int q = 0; q < 4; ++q){
      int grow = row0 + wr*64 + m*16 + l4*4 + q;
      if (grow >= M) continue;
      #pragma unroll
      for (int n = 0; n < 4; ++n){
        int gcol = col0 + wc*64 + n*16 + l15;
        float v = fmaxf(acc[m][n][q] + bias[gcol], 0.f);
        Cbf[(size_t)grow*HIDD + gcol] = f2bf(v);
      }
    }
  }
}

// ---------------- generic bf16 MFMA GEMM (global_load_lds staging) ----------------
__global__ __launch_bounds__(256) void k_mfma(const u16* __restrict__ A,
    const u16* __restrict__ A2, const u16* __restrict__ Bt, int M, int N, int Kp, int ldA,
    const float* __restrict__ bias, const float* __restrict__ msc,
    float* __restrict__ Cf, int ldf, u16* __restrict__ Cbf, int ldbf, int Nstore, int flags,
    const u16* __restrict__ g_att, const u16* __restrict__ g_mo)
{
  __shared__ alignas(16) u16 As[4096];
  __shared__ alignas(16) u16 Bs[4096];
  int tid = threadIdx.x;
  int row0 = blockIdx.y*128, col0 = blockIdx.x*128;
  if ((flags & MF_MASK) && col0 >= row0 + 128) return;
  int lane = tid & 63, wid = tid >> 6;
  int wr = wid >> 1, wc = wid & 1;
  int l15 = lane & 15, l4 = lane >> 4;

  int s0 = tid, s1 = tid + 256;
  int r0s = s0 >> 2, c0s = s0 & 3;
  int r1s = s1 >> 2, c1s = s1 & 3;
  int k80 = (c0s ^ ((r0s >> 1) & 3)) << 3;
  int k81 = (c1s ^ ((r1s >> 1) & 3)) << 3;
  int ra0 = row0 + r0s; if (ra0 >= M) ra0 = M - 1;
  int ra1 = row0 + r1s; if (ra1 >= M) ra1 = M - 1;
  int cb0 = col0 + r0s; if (cb0 >= N) cb0 = N - 1;
  int cb1 = col0 + r1s; if (cb1 >= N) cb1 = N - 1;
  const u16* pa0 = A + (size_t)ra0*ldA + k80;
  const u16* pa1 = A + (size_t)ra1*ldA + k81;
  int kt1 = A2 ? (ldA >> 5) : (Kp >> 5);
  int koff = kt1 << 5;
  const u16* qa0 = A2 ? (A2 + (size_t)ra0*ldA + k80 - koff) : pa0;
  const u16* qa1 = A2 ? (A2 + (size_t)ra1*ldA + k81 - koff) : pa1;
  const u16* pb0 = Bt + (size_t)cb0*Kp + k80;
  const u16* pb1 = Bt + (size_t)cb1*Kp + k81;
  u16* la0 = As + s0*8; u16* la1 = As + s1*8;
  u16* lb0 = Bs + s0*8; u16* lb1 = Bs + s1*8;

  f32x4 acc[4][4];
  #pragma unroll
  for (int m = 0; m < 4; ++m)
    #pragma unroll
    for (int n = 0; n < 4; ++n)
      #pragma unroll
      for (int q = 0; q < 4; ++q) acc[m][n][q] = 0.f;

  int nkt = Kp >> 5;
  for (int kt = 0; kt < nkt; ++kt){
    int k0 = kt << 5;
    const u16* a0 = (kt < kt1) ? pa0 : qa0;
    const u16* a1 = (kt < kt1) ? pa1 : qa1;
    gload16(a0 + k0, la0); gload16(a1 + k0, la1);
    gload16(pb0 + k0, lb0); gload16(pb1 + k0, lb1);
    __syncthreads();
    bf16x8 af[4], bfr[4];
    #pragma unroll
    for (int m = 0; m < 4; ++m){ int r = wr*64 + m*16 + l15; af[m] = *(const bf16x8*)(As + swz(r, l4)); }
    #pragma unroll
    for (int n = 0; n < 4; ++n){ int cc = wc*64 + n*16 + l15; bfr[n] = *(const bf16x8*)(Bs + swz(cc, l4)); }
    #pragma unroll
    for (int m = 0; m < 4; ++m)
      #pragma unroll
      for (int n = 0; n < 4; ++n)
        acc[m][n] = __builtin_amdgcn_mfma_f32_16x16x32_bf16(af[m], bfr[n], acc[m][n], 0, 0, 0);
    __syncthreads();
  }
  #pragma unroll
  for (int m = 0; m < 4; ++m){
    #pragma unroll
    for (int q = 0; q < 4; ++q){
      int grow = row0 + wr*64 + m*16 + l4*4 + q;
      if (grow >= M) continue;
      #pragma unroll
      for (int n = 0; n < 4; ++n){
        int gcol = col0 + wc*64 + n*16 + l15;
        if (gcol < N){
          float v = acc[m][n][q];
          if (bias) v += bias[gcol];
          if (flags & MF_MASK){ v += msc[grow] + msc[gcol]; if (gcol >= grow) v = NEG_INF; }
          if (flags & MF_RELU) v = fmaxf(v, 0.f);
          if (flags & MF_GATE){
            float f = 1.f/(1.f + expf(-v));
            float res = f*bf2f(g_att[(size_t)grow*ldbf + gcol])
                      + (1.f - f)*bf2f(g_mo[(size_t)grow*ldbf + gcol]);
            Cbf[(size_t)grow*ldbf + gcol] = f2bf(res);
          } else {
            if (Cf)  Cf[(size_t)grow*ldf + gcol] = v;
            if (Cbf) Cbf[(size_t)grow*ldbf + gcol] = f2bf(v);
          }
        } else if (Cbf && gcol < Nstore){
          Cbf[(size_t)grow*ldbf + gcol] = 0;
        }
      }
    }
  }
}

// ---- fused layer2 + w3 dot, full row per block ----
__global__ __launch_bounds__(256) void k_mfma_rowdot(const u16* __restrict__ A,
    const u16* __restrict__ Bt, int M, const float* __restrict__ b2,
    const float* __restrict__ w3, const float* __restrict__ b3,
    const float* __restrict__ add, float* __restrict__ out)
{
  __shared__ alignas(16) u16 As[4096];
  __shared__ alignas(16) u16 Bs[4096];
  __shared__ float rsum[128][2];
  int tid = threadIdx.x;
  int row0 = blockIdx.x*128;
  int lane = tid & 63, wid = tid >> 6;
  int wr = wid >> 1, wc = wid & 1;
  int l15 = lane & 15, l4 = lane >> 4;

  int s0 = tid, s1 = tid + 256;
  int r0s = s0 >> 2, c0s = s0 & 3;
  int r1s = s1 >> 2, c1s = s1 & 3;
  int k80 = (c0s ^ ((r0s >> 1) & 3)) << 3;
  int k81 = (c1s ^ ((r1s >> 1) & 3)) << 3;
  int ra0 = row0 + r0s; if (ra0 >= M) ra0 = M - 1;
  int ra1 = row0 + r1s; if (ra1 >= M) ra1 = M - 1;
  const u16* pa0 = A + (size_t)ra0*HIDD + k80;
  const u16* pa1 = A + (size_t)ra1*HIDD + k81;
  u16* la0 = As + s0*8; u16* la1 = As + s1*8;
  u16* lb0 = Bs + s0*8; u16* lb1 = Bs + s1*8;

  float rd[4][4] = {};
  for (int p = 0; p < 4; ++p){
    int col0 = p*128;
    const u16* pb0 = Bt + (size_t)(col0 + r0s)*HIDD + k80;
    const u16* pb1 = Bt + (size_t)(col0 + r1s)*HIDD + k81;
    f32x4 acc[4][4];
    #pragma unroll
    for (int m = 0; m < 4; ++m)
      #pragma unroll
      for (int n = 0; n < 4; ++n)
        #pragma unroll
        for (int q = 0; q < 4; ++q) acc[m][n][q] = 0.f;
    for (int kt = 0; kt < HIDD/32; ++kt){
      int k0 = kt << 5;
      gload16(pa0 + k0, la0); gload16(pa1 + k0, la1);
      gload16(pb0 + k0, lb0); gload16(pb1 + k0, lb1);
      __syncthreads();
      bf16x8 af[4], bfr[4];
      #pragma unroll
      for (int m = 0; m < 4; ++m){ int r = wr*64 + m*16 + l15; af[m] = *(const bf16x8*)(As + swz(r, l4)); }
      #pragma unroll
      for (int n = 0; n < 4; ++n){ int cc = wc*64 + n*16 + l15; bfr[n] = *(const bf16x8*)(Bs + swz(cc, l4)); }
      #pragma unroll
      for (int m = 0; m < 4; ++m)
        #pragma unroll
        for (int n = 0; n < 4; ++n)
          acc[m][n] = __builtin_amdgcn_mfma_f32_16x16x32_bf16(af[m], bfr[n], acc[m][n], 0, 0, 0);
      __syncthreads();
    }
    #pragma unroll
    for (int n = 0; n < 4; ++n){
      int gcol = col0 + wc*64 + n*16 + l15;
      float bb = b2[gcol], ww = w3[gcol];
      #pragma unroll
      for (int m = 0; m < 4; ++m)
        #pragma unroll
        for (int q = 0; q < 4; ++q){
          float v = fmaxf(acc[m][n][q] + bb, 0.f);
          rd[m][q] = fmaf(v, ww, rd[m][q]);
        }
    }
  }
  #pragma unroll
  for (int m = 0; m < 4; ++m)
    #pragma unroll
    for (int q = 0; q < 4; ++q){
      float s = rd[m][q];
      s += __shfl_xor(s, 1, 64); s += __shfl_xor(s, 2, 64);
      s += __shfl_xor(s, 4, 64); s += __shfl_xor(s, 8, 64);
      if (l15 == 0) rsum[wr*64 + m*16 + l4*4 + q][wc] = s;
    }
  __syncthreads();
  if (tid < 128){
    int gr = row0 + tid;
    if (gr < M){
      float v = rsum[tid][0] + rsum[tid][1] + b3[0];
      if (add) v += add[gr];
      out[gr] = v;
    }
  }
}

// ------- pair layer1 MFMA: 2 col-panels/block, reg-prefetched on-the-fly product A -------
__global__ __launch_bounds__(256) void k_d1_mfma(int Mc,
    const u16* __restrict__ ment, const int* __restrict__ antes, const int* __restrict__ mspk,
    const u16* __restrict__ Bt, const float* __restrict__ A_meb,
    const float* __restrict__ comb, u16* __restrict__ H1)
{
  __shared__ alignas(16) u16 As[4096];   // 128 rows x 32
  __shared__ alignas(16) u16 Bs[8192];   // 256 cols x 32
  __shared__ int ri[128], rj[128], rcomb[128];
  int tid = threadIdx.x;
  int row0 = blockIdx.y*128;
  int col0 = blockIdx.x*256;
  if (tid < 128){
    int r = row0 + tid;
    int p = (r < Mc ? r : 0);
    int i = p / CANT;
    int j = antes[p];
    ri[tid] = i; rj[tid] = j;
    int same = (mspk[i] == mspk[j]) ? 1 : 0;
    int d = i - j; d = d < 0 ? 0 : (d > 64 ? 64 : d);
    int bin = (d <= 4) ? d : (d <= 8 ? 5 : (d <= 16 ? 6 : (d <= 32 ? 7 : 8)));
    rcomb[tid] = same*9 + bin;
  }
  __syncthreads();
  int lane = tid & 63, wid = tid >> 6;
  int wr = wid >> 1, wc = wid & 1;
  int l15 = lane & 15, l4 = lane >> 4;

  // A staging: 2 slots/thread
  int s0 = tid, s1 = tid + 256;
  int r0s = s0 >> 2, c0s = s0 & 3;
  int r1s = s1 >> 2, c1s = s1 & 3;
  int k80 = (c0s ^ ((r0s >> 1) & 3)) << 3;
  int k81 = (c1s ^ ((r1s >> 1) & 3)) << 3;
  const u16* pi0 = ment + (size_t)ri[r0s]*KPAD + k80;
  const u16* pj0 = ment + (size_t)rj[r0s]*KPAD + k80;
  const u16* pi1 = ment + (size_t)ri[r1s]*KPAD + k81;
  const u16* pj1 = ment + (size_t)rj[r1s]*KPAD + k81;
  // B staging: 4 slots/thread over 256 cols
  int t0 = tid, t1 = tid + 256, t2 = tid + 512, t3 = tid + 768;
  int rB0 = t0 >> 2, rB1 = t1 >> 2, rB2 = t2 >> 2, rB3 = t3 >> 2;
  int kB0 = ((t0 & 3) ^ ((rB0 >> 1) & 3)) << 3;
  int kB1 = ((t1 & 3) ^ ((rB1 >> 1) & 3)) << 3;
  int kB2 = ((t2 & 3) ^ ((rB2 >> 1) & 3)) << 3;
  int kB3 = ((t3 & 3) ^ ((rB3 >> 1) & 3)) << 3;
  const u16* pb0 = Bt + (size_t)(col0 + rB0)*KPAD + kB0;
  const u16* pb1 = Bt + (size_t)(col0 + rB1)*KPAD + kB1;
  const u16* pb2 = Bt + (size_t)(col0 + rB2)*KPAD + kB2;
  const u16* pb3 = Bt + (size_t)(col0 + rB3)*KPAD + kB3;

  f32x4 acc[4][8];
  #pragma unroll
  for (int m = 0; m < 4; ++m)
    #pragma unroll
    for (int n = 0; n < 8; ++n)
      #pragma unroll
      for (int q = 0; q < 4; ++q) acc[m][n][q] = 0.f;

  uint4 va0 = *(const uint4*)pi0;
  uint4 vb0 = *(const uint4*)pj0;
  uint4 va1 = *(const uint4*)pi1;
  uint4 vb1 = *(const uint4*)pj1;

  int nkt = KPAD >> 5;
  for (int kt = 0; kt < nkt; ++kt){
    int k0 = kt << 5;
    {
      uint4 vo;
      vo.x = pkmul(va0.x, vb0.x); vo.y = pkmul(va0.y, vb0.y);
      vo.z = pkmul(va0.z, vb0.z); vo.w = pkmul(va0.w, vb0.w);
      *(uint4*)(As + s0*8) = vo;
      vo.x = pkmul(va1.x, vb1.x); vo.y = pkmul(va1.y, vb1.y);
      vo.z = pkmul(va1.z, vb1.z); vo.w = pkmul(va1.w, vb1.w);
      *(uint4*)(As + s1*8) = vo;
    }
    gload16(pb0 + k0, Bs + t0*8); gload16(pb1 + k0, Bs + t1*8);
    gload16(pb2 + k0, Bs + t2*8); gload16(pb3 + k0, Bs + t3*8);
    if (kt + 1 < nkt){
      int kn = (kt + 1) << 5;
      va0 = *(const uint4*)(pi0 + kn);
      vb0 = *(const uint4*)(pj0 + kn);
      va1 = *(const uint4*)(pi1 + kn);
      vb1 = *(const uint4*)(pj1 + kn);
    }
    __syncthreads();
    bf16x8 af[4];
    #pragma unroll
    for (int m = 0; m < 4; ++m){ int r = wr*64 + m*16 + l15; af[m] = *(const bf16x8*)(As + swz(r, l4)); }
    #pragma unroll
    for (int n = 0; n < 8; ++n){
      int cc = wc*128 + n*16 + l15;
      bf16x8 bfr = *(const bf16x8*)(Bs + swz(cc, l4));
      #pragma unroll
      for (int m = 0; m < 4; ++m)
        acc[m][n] = __builtin_amdgcn_mfma_f32_16x16x32_bf16(af[m], bfr, acc[m][n], 0, 0, 0);
    }
    __syncthreads();
  }
  #pragma unroll
  for (int m = 0; m < 4; ++m){
    #pragma unroll
    for (int q = 0; q < 4; ++q){
      int rl = wr*64 + m*16 + l4*4 + q;
      int grow = row0 + rl;
      if (grow >= Mc) continue;
      const float* me = A_meb + (size_t)ri[rl]*1024;
      const float* an = A_meb + (size_t)rj[rl]*1024 + 512;
      const float* cb = comb + (size_t)rcomb[rl]*HIDD;
      #pragma unroll
      for (int n = 0; n < 8; ++n){
        int gcol = col0 + wc*128 + n*16 + l15;
        float v = acc[m][n][q] + me[gcol] + an[gcol] + cb[gcol];
        H1[(size_t)grow*HIDD + gcol] = f2bf(fmaxf(v, 0.f));
      }
    }
  }
}

// ================= top-K selection pipeline (multi-kernel, multi-CU) =================
__global__ __launch_bounds__(256) void k_hist(const float* __restrict__ scores,
    unsigned* __restrict__ selws, int pass)
{
  int n = blockIdx.x*256 + threadIdx.x;
  if (n >= NCAND) return;
  unsigned u = ordf(scores[n]);
  const unsigned* meta = selws + 6144;
  if (pass == 0) atomicAdd(&selws[u >> 21], 1u);
  else if (pass == 1){ if ((u >> 21) == meta[0]) atomicAdd(&selws[2048 + ((u >> 10) & 0x7FFu)], 1u); }
  else { if ((u >> 10) == meta[2]) atomicAdd(&selws[4096 + (u & 0x3FFu)], 1u); }
}
__global__ __launch_bounds__(1024) void k_thresh(unsigned* __restrict__ selws, int mode){
  __shared__ unsigned a[2048], b[2048];
  int tid = threadIdx.x;
  unsigned* meta = selws + 6144;
  const unsigned* gbin = selws + (mode == 0 ? 0 : (mode == 1 ? 2048 : 4096));
  unsigned target = (mode == 0) ? (unsigned)KSEL : meta[mode == 1 ? 1 : 3];
  a[tid] = gbin[tid]; a[tid + 1024] = gbin[tid + 1024];
  unsigned *src = a, *dst = b;
  for (int step = 1; step < 2048; step <<= 1){
    __syncthreads();
    for (int i = tid; i < 2048; i += 1024)
      dst[i] = src[i] + ((i + step < 2048) ? src[i + step] : 0u);
    unsigned* t2 = src; src = dst; dst = t2;
  }
  __syncthreads();
  for (int i = tid; i < 2048; i += 1024){
    unsigned si = src[i], sn = (i < 2047) ? src[i+1] : 0u;
    if (si >= target && sn < target){
      if (mode == 0){ meta[0] = (unsigned)i; meta[1] = target - sn; }
      else if (mode == 1){ meta[2] = (meta[0] << 11) | (unsigned)i; meta[3] = target - sn; }
      else { meta[4] = (meta[2] << 10) | (unsigned)i; meta[5] = target - sn; }
    }
  }
}
__global__ __launch_bounds__(256) void k_compact(const float* __restrict__ scores,
    unsigned* __restrict__ selws, int* __restrict__ g_sel, unsigned* __restrict__ g_eq)
{
  int n = blockIdx.x*256 + threadIdx.x;
  if (n >= NCAND) return;
  unsigned kth = selws[6144 + 4];
  unsigned* cnt = selws + 6152;
  unsigned u = ordf(scores[n]);
  if (u > kth){ unsigned p = atomicAdd(&cnt[0], 1u); g_sel[p] = n; }
  else if (u == kth){ unsigned p = atomicAdd(&cnt[1], 1u); if (p < 1024) g_eq[p] = (unsigned)n; }
}
__global__ __launch_bounds__(1024) void k_eqrank(unsigned* __restrict__ selws,
    const unsigned* __restrict__ g_eq, int* __restrict__ g_sel)
{
  __shared__ unsigned eq[1024];
  int tid = threadIdx.x;
  unsigned neq = selws[6152 + 1]; if (neq > 1024u) neq = 1024u;
  unsigned E = selws[6144 + 5];
  unsigned G = selws[6152 + 0];
  eq[tid] = (tid < (int)neq) ? g_eq[tid] : 0xFFFFFFFFu;
  __syncthreads();
  if (tid < (int)neq){
    unsigned mine = eq[tid]; unsigned r = 0;
    for (unsigned j = 0; j < neq; ++j) r += (eq[j] < mine) ? 1u : 0u;
    if (r < E) g_sel[G + r] = (int)mine;
  }
}
__global__ __launch_bounds__(256) void k_rank1(const float* __restrict__ scores,
    const int* __restrict__ g_sel, int* __restrict__ ranked)
{
  __shared__ unsigned long long key[KSEL];
  int tid = threadIdx.x;
  for (int t = tid; t < KSEL; t += 256){
    int n = g_sel[t];
    key[t] = ((unsigned long long)(~ordf(scores[n])) << 32) | (unsigned)n;
  }
  __syncthreads();
  int t = blockIdx.x*256 + tid;
  if (t >= KSEL) return;
  unsigned long long mine = key[t];
  int r = 0;
  #pragma unroll 16
  for (int j = 0; j < KSEL; ++j) r += (key[j] < mine) ? 1 : 0;
  ranked[r] = (int)(mine & 0xFFFFFFFFu);
}
__global__ __launch_bounds__(256) void k_rank2(const int* __restrict__ ranked,
    const int* __restrict__ starts, const int* __restrict__ ends, int* __restrict__ top_idx)
{
  __shared__ unsigned long long key[KSEL];
  int tid = threadIdx.x;
  int elast = ends[NCAND-1];
  for (int t = tid; t < KSEL; t += 256){
    int n = ranked[t];
    unsigned mp = (unsigned)(starts[n]*elast + ends[n]);
    key[t] = ((unsigned long long)mp << 11) | (unsigned)t;
  }
  __syncthreads();
  int t = blockIdx.x*256 + tid;
  if (t >= KSEL) return;
  unsigned long long mine = key[t];
  int r = 0;
  #pragma unroll 16
  for (int j = 0; j < KSEL; ++j) r += (key[j] < mine) ? 1 : 0;
  top_idx[r] = ranked[t];
}

// ---------------- gather mention rows -> bf16 [KSEL][KPAD], permuted layout ----------------
__global__ __launch_bounds__(256) void k_gather(const int* __restrict__ top_idx,
    const u16* __restrict__ flatbf, const u16* __restrict__ hemb, const u16* __restrict__ wembP,
    const int* __restrict__ starts, const int* __restrict__ ends,
    const float* __restrict__ cscores, const int* __restrict__ spk_ids,
    u16* __restrict__ ment, float* __restrict__ mscore, int* __restrict__ mspk)
{
  int k = blockIdx.x; int n = top_idx[k];
  int s = starts[n], e = ends[n];
  int v = threadIdx.x;
  if (v < KPAD/8){
    int f0 = v*8;
    const u16* src = (f0 < 512) ? flatbf + (size_t)s*FLATD + f0
                   : (f0 < 1024) ? flatbf + (size_t)e*FLATD + (f0 - 512)
                   : (f0 < 1280) ? hemb + (size_t)n*HDD + (f0 - 1024)
                   : wembP + (e - s)*32 + (f0 - 1280);
    *(uint4*)(ment + (size_t)k*KPAD + f0) = *(const uint4*)src;
  }
  if (threadIdx.x == 0){ mscore[k] = cscores[n]; mspk[k] = spk_ids[s]; }
}

// ---------------- per-row top-40, wave-per-row, register keys ----------------
__global__ __launch_bounds__(256) void k_f3(const float* __restrict__ fast,
    float* __restrict__ top_fast, int* __restrict__ antes)
{
  int wid = threadIdx.x >> 6, lane = threadIdx.x & 63;
  int i = blockIdx.x*4 + wid;
  if (i >= KSEL) return;
  const float* row = fast + (size_t)i*KSEL;
  unsigned long long key[26];
  #pragma unroll
  for (int t = 0; t < 26; ++t){
    int j = lane + (t << 6);
    unsigned long long k2 = 0ULL;
    if (j < i) k2 = ((unsigned long long)ordf(row[j]) << 32) | (unsigned)(0xFFFFFFFFu - (unsigned)j);
    key[t] = k2;
  }
  for (int c = 0; c < CANT; ++c){
    unsigned long long m = 0ULL;
    #pragma unroll
    for (int t = 0; t < 26; ++t) if (key[t] > m) m = key[t];
    #pragma unroll
    for (int o = 32; o; o >>= 1){
      unsigned long long v = __shfl_xor(m, o, 64);
      if (v > m) m = v;
    }
    if (m){
      #pragma unroll
      for (int t = 0; t < 26; ++t) if (key[t] == m) key[t] = 0ULL;
    }
    if (lane == 0){
      if (m){
        top_fast[(size_t)i*CANT + c] = unordf((unsigned)(m >> 32));
        antes[(size_t)i*CANT + c]    = (int)(0xFFFFFFFFu - (unsigned)(m & 0xFFFFFFFFu));
      } else {
        top_fast[(size_t)i*CANT + c] = NEG_INF;
        antes[(size_t)i*CANT + c]    = c;
      }
    }
  }
}

// ------- comb[same*9+bin][512]: (spk+genre+dist) rows through ss_w1 + b1, pre-summed -------
__global__ __launch_bounds__(256) void k_dsmall(const float* __restrict__ ss_w1,
    const float* __restrict__ ss_b1, const float* __restrict__ spk_emb,
    const float* __restrict__ gen_emb, const float* __restrict__ dist_emb,
    const int* __restrict__ genre_id, float* __restrict__ comb)
{
  int r = blockIdx.x;             // 0..17
  int same = r / 9, bin = r % 9;
  const float* es = spk_emb + same*FEATD;
  const float* eg = gen_emb + genre_id[0]*FEATD;
  const float* ed = dist_emb + bin*FEATD;
  for (int h = threadIdx.x; h < HIDD; h += 256){
    float acc = ss_b1[h];
    const float* ws_ = ss_w1 + (size_t)3900*HIDD + h;
    const float* wg  = ss_w1 + (size_t)3920*HIDD + h;
    const float* wd  = ss_w1 + (size_t)3940*HIDD + h;
    for (int f = 0; f < FEATD; ++f){
      acc += es[f]*ws_[(size_t)f*HIDD];
      acc += eg[f]*wg[(size_t)f*HIDD];
      acc += ed[f]*wd[(size_t)f*HIDD];
    }
    comb[(size_t)r*HIDD + h] = acc;
  }
}

// ---------------- softmax over [0, ante_scores] + attended -> bf16 (vectorized) ----------------
__global__ __launch_bounds__(256) void k_d4a(const float* __restrict__ ante_sc,
    const int* __restrict__ antes, const u16* __restrict__ ment, u16* __restrict__ att_bf)
{
  int i = blockIdx.x;
  __shared__ float w[CANT+1];
  __shared__ int aj[CANT];
  if (threadIdx.x == 0){
    float s[CANT]; float m = 0.f;
    #pragma unroll
    for (int c = 0; c < CANT; ++c){ s[c] = ante_sc[i*CANT + c]; m = fmaxf(m, s[c]); }
    float e0 = expf(0.f - m);
    float sum = e0;
    float ex[CANT];
    #pragma unroll
    for (int c = 0; c < CANT; ++c){ ex[c] = expf(s[c] - m); sum += ex[c]; }
    float inv = 1.f/sum;
    w[0] = e0*inv;
    #pragma unroll
    for (int c = 0; c < CANT; ++c) w[c+1] = ex[c]*inv;
  }
  if (threadIdx.x < CANT) aj[threadIdx.x] = antes[i*CANT + threadIdx.x];
  __syncthreads();
  int v = threadIdx.x;
  if (v >= KPAD/8) return;
  int d0 = v*8;
  float r[8] = {};
  {
    uint4 x = *(const uint4*)(ment + (size_t)i*KPAD + d0);
    float w0 = w[0];
    const unsigned* px = (const unsigned*)&x;
    #pragma unroll
    for (int h = 0; h < 4; ++h){
      r[2*h]   = w0*__uint_as_float(px[h] << 16);
      r[2*h+1] = w0*__uint_as_float(px[h] & 0xffff0000u);
    }
  }
  for (int c = 0; c < CANT; ++c){
    uint4 x = *(const uint4*)(ment + (size_t)aj[c]*KPAD + d0);
    float wc_ = w[c+1];
    const unsigned* px = (const unsigned*)&x;
    #pragma unroll
    for (int h = 0; h < 4; ++h){
      r[2*h]   = fmaf(wc_, __uint_as_float(px[h] << 16), r[2*h]);
      r[2*h+1] = fmaf(wc_, __uint_as_float(px[h] & 0xffff0000u), r[2*h+1]);
    }
  }
  u16 o[8];
  #pragma unroll
  for (int h = 0; h < 8; ++h) o[h] = f2bf(r[h]);
  *(uint4*)(att_bf + (size_t)i*KPAD + d0) = *(const uint4*)o;
}

// ---------------- final output (sanitize non-finite) ----------------
__global__ __launch_bounds__(256) void k_out(const float* __restrict__ ante_sc, float* __restrict__ out){
  int idx = blockIdx.x*256 + threadIdx.x;
  if (idx >= KSEL*41) return;
  int i = idx / 41, c = idx % 41;
  float v = (c == 0) ? 0.f : ante_sc[i*CANT + (c-1)];
  if (!isfinite(v)) v = -3.0e38f;
  out[idx] = v;
}

__global__ void k_zero(float* out, int n){
  int i = blockIdx.x*256 + threadIdx.x;
  if (i < n) out[i] = 0.f;
}

extern "C" void kernel_launch(void* const* d_in, const int* in_sizes, int n_in,
                              void* d_out, int out_size, void* d_ws, size_t ws_size,
                              hipStream_t stream)
{
  const float* flat   = (const float*)d_in[0];
  const float* hdoc   = (const float*)d_in[1];
  const float* w_head = (const float*)d_in[2];
  const float* b_head = (const float*)d_in[3];
  const float* wemb   = (const float*)d_in[4];
  const float* ms_w1  = (const float*)d_in[5];
  const float* ms_b1  = (const float*)d_in[6];
  const float* ms_w2  = (const float*)d_in[7];
  const float* ms_b2  = (const float*)d_in[8];
  const float* ms_w3  = (const float*)d_in[9];
  const float* ms_b3  = (const float*)d_in[10];
  const float* fast_w = (const float*)d_in[11];
  const float* fast_b = (const float*)d_in[12];
  const float* ss_w1  = (const float*)d_in[13];
  const float* ss_b1  = (const float*)d_in[14];
  const float* ss_w2  = (const float*)d_in[15];
  const float* ss_b2  = (const float*)d_in[16];
  const float* ss_w3  = (const float*)d_in[17];
  const float* ss_b3  = (const float*)d_in[18];
  const float* gate_w = (const float*)d_in[19];
  const float* gate_b = (const float*)d_in[20];
  const float* spk_e  = (const float*)d_in[21];
  const float* gen_e  = (const float*)d_in[22];
  const float* dist_e = (const float*)d_in[23];
  const int* starts   = (const int*)d_in[24];
  const int* ends     = (const int*)d_in[25];
  const int* spk_ids  = (const int*)d_in[26];
  const int* genre_id = (const int*)d_in[27];
  float* out = (float*)d_out;

  size_t off = 0;
  char* base = (char*)d_ws;
  auto alloc = [&](size_t nbytes) -> void* {
    void* p = (void*)(base + off);
    off += ((nbytes + 255)/256)*256;
    return p;
  };
  float* head_sc = (float*)alloc((size_t)T_LEN*4);
  u16*   flatbf  = (u16*)alloc((size_t)T_LEN*FLATD*2);
  u16*   wembP   = (u16*)alloc((size_t)20*32*2);
  float* fbP     = (float*)alloc((size_t)KPAD*4);
  float* gbP     = (float*)alloc((size_t)KPAD*4);
  u16*   hemb    = (u16*)alloc((size_t)NCAND*HDD*2);
  float* cscores = (float*)alloc((size_t)NCAND*4);
  int*   top_idx = (int*)alloc(2048*4);
  unsigned* selws= (unsigned*)alloc(6160*4);
  int*   g_sel   = (int*)alloc((size_t)KSEL*4);
  unsigned* g_eq = (unsigned*)alloc(1024*4);
  int*   g_rank  = (int*)alloc((size_t)KSEL*4);
  u16*   ms1T    = (u16*)alloc((size_t)HIDD*KPAD*2);
  u16*   ms2T    = (u16*)alloc((size_t)HIDD*HIDD*2);
  u16*   fastT   = (u16*)alloc((size_t)MENTD*KPAD*2);
  u16*   ss1abT  = (u16*)alloc((size_t)1024*KPAD*2);
  u16*   sspT    = (u16*)alloc((size_t)HIDD*KPAD*2);
  u16*   ss2T    = (u16*)alloc((size_t)HIDD*HIDD*2);
  u16*   gateTall= (u16*)alloc((size_t)MENTD*2*KPAD*2);
  u16*   ment    = (u16*)alloc((size_t)KSEL*KPAD*2);
  u16*   mentB   = (u16*)alloc((size_t)KSEL*KPAD*2);
  u16*   srcb    = (u16*)alloc((size_t)KSEL*KPAD*2);
  float* mscore  = (float*)alloc((size_t)KSEL*4);
  int*   mspk    = (int*)alloc((size_t)KSEL*4);
  float* fastm   = (float*)alloc((size_t)KSEL*KSEL*4);
  float* top_fast= (float*)alloc((size_t)NPAIR*4);
  int*   antes   = (int*)alloc((size_t)NPAIR*4);
  float* ante_sc = (float*)alloc((size_t)NPAIR*4);
  float* A_meb   = (float*)alloc((size_t)KSEL*1024*4);
  float* comb    = (float*)alloc((size_t)18*HIDD*4);
  u16*   att_bf  = (u16*)alloc((size_t)KSEL*KPAD*2);
  u16*   bufH1   = (u16*)alloc((size_t)NPAIR*HIDD*2);

  if (ws_size < off){
    k_zero<<<(KSEL*41 + 255)/256, 256, 0, stream>>>(out, KSEL*41);
    return;
  }

  k_prep<<<(T_LEN*FLATD + 255)/256, 256, 0, stream>>>(flat, wemb, fast_b, gate_b,
                                                      flatbf, wembP, fbP, gbP, selws);
  k_transall<<<dim3(KPAD/32, 41, 9), 256, 0, stream>>>(ms_w1, ms_w2, fast_w, ss_w1, ss_w2, gate_w,
      ms1T, ms2T, fastT, ss1abT, sspT, ss2T, gateTall);

  k_head<<<T_LEN/4, 256, 0, stream>>>(flat, w_head, b_head, head_sc);
  k_cand<<<NCAND/4, 256, 0, stream>>>(head_sc, hdoc, starts, ends, hemb);

  // mention scorer (single pass over 30000 rows)
  k_mfma_cand<<<dim3(HIDD/128, (NCAND + 127)/128), 256, 0, stream>>>(
      flatbf, hemb, wembP, starts, ends, ms1T, NCAND, ms_b1, bufH1);
  k_mfma_rowdot<<<(NCAND + 127)/128, 256, 0, stream>>>(bufH1, ms2T, NCAND, ms_b2, ms_w3, ms_b3,
                                                       nullptr, cscores);

  // top-K selection pipeline
  k_hist<<<(NCAND + 255)/256, 256, 0, stream>>>(cscores, selws, 0);
  k_thresh<<<1, 1024, 0, stream>>>(selws, 0);
  k_hist<<<(NCAND + 255)/256, 256, 0, stream>>>(cscores, selws, 1);
  k_thresh<<<1, 1024, 0, stream>>>(selws, 1);
  k_hist<<<(NCAND + 255)/256, 256, 0, stream>>>(cscores, selws, 2);
  k_thresh<<<1, 1024, 0, stream>>>(selws, 2);
  k_compact<<<(NCAND + 255)/256, 256, 0, stream>>>(cscores, selws, g_sel, g_eq);
  k_eqrank<<<1, 1024, 0, stream>>>(selws, g_eq, g_sel);
  k_rank1<<<(KSEL + 255)/256, 256, 0, stream>>>(cscores, g_sel, g_rank);
  k_rank2<<<(KSEL + 255)/256, 256, 0, stream>>>(g_rank, starts, ends, top_idx);

  k_gather<<<KSEL, 256, 0, stream>>>(top_idx, flatbf, hemb, wembP, starts, ends, cscores, spk_ids,
                                     ment, mscore, mspk);

  // fast antecedent scores
  k_mfma<<<dim3((MENTD+127)/128, (KSEL+127)/128), 256, 0, stream>>>(
      ment, nullptr, fastT, KSEL, MENTD, KPAD, KPAD, fbP, nullptr,
      nullptr, 0, srcb, KPAD, KPAD, 0, nullptr, nullptr);
  k_mfma<<<dim3((KSEL+127)/128, (KSEL+127)/128), 256, 0, stream>>>(
      srcb, nullptr, ment, KSEL, KSEL, KPAD, KPAD, nullptr, mscore,
      fastm, KSEL, nullptr, 0, 0, MF_MASK, nullptr, nullptr);
  k_f3<<<(KSEL+3)/4, 256, 0, stream>>>(fastm, top_fast, antes);

  k_dsmall<<<18, 256, 0, stream>>>(ss_w1, ss_b1, spk_e, gen_e, dist_e, genre_id, comb);

  const u16* mcur = ment;
  for (int iter = 0; iter < 2; ++iter){
    k_mfma<<<dim3(8, (KSEL+127)/128), 256, 0, stream>>>(
        mcur, nullptr, ss1abT, KSEL, 1024, KPAD, KPAD, nullptr, nullptr,
        A_meb, 1024, nullptr, 0, 0, 0, nullptr, nullptr);
    k_d1_mfma<<<dim3(2, (NPAIR + 127)/128), 256, 0, stream>>>(
        NPAIR, mcur, antes, mspk, sspT, A_meb, comb, bufH1);
    k_mfma_rowdot<<<(NPAIR + 127)/128, 256, 0, stream>>>(bufH1, ss2T, NPAIR, ss_b2, ss_w3, ss_b3,
                                                         top_fast, ante_sc);
    if (iter == 0){
      k_d4a<<<KSEL, 256, 0, stream>>>(ante_sc, antes, mcur, att_bf);
      k_mfma<<<dim3((MENTD+127)/128, (KSEL+127)/128), 256, 0, stream>>>(
          ment, att_bf, gateTall, KSEL, MENTD, 2*KPAD, KPAD, gbP, nullptr,
          nullptr, 0, mentB, KPAD, KPAD, MF_GATE, att_bf, ment);
      mcur = mentB;
    }
  }

  k_out<<<(KSEL*41 + 255)/256, 256, 0, stream>>>(ante_sc, out);
}

// Round 8
// 1126.071 us; speedup vs baseline: 7.9885x; 1.1205x over previous
//
#include <hip/hip_runtime.h>
#include <math.h>

#define T_LEN 4096
#define FLATD 512
#define HDD 256
#define FEATD 20
#define NCAND 30000
#define HIDD 512
#define KSEL 1638
#define CANT 40
#define MENTD 1300
#define KPAD 1344
#define NPAIR (KSEL*CANT)
#define NEG_INF (-__builtin_inff())

#define MF_RELU 1
#define MF_MASK 4
#define MF_GATE 8

typedef unsigned short u16;
typedef __attribute__((ext_vector_type(8))) short bf16x8;
typedef __attribute__((ext_vector_type(4))) float f32x4;

__device__ __forceinline__ unsigned ordf(float f){
  unsigned u = __float_as_uint(f);
  return (u & 0x80000000u) ? ~u : (u | 0x80000000u);
}
__device__ __forceinline__ float unordf(unsigned u){
  return __uint_as_float((u & 0x80000000u) ? (u ^ 0x80000000u) : ~u);
}
__device__ __forceinline__ float bf2f(u16 h){ return __uint_as_float(((unsigned)h) << 16); }
__device__ __forceinline__ u16 f2bf(float f){
  unsigned u = __float_as_uint(f);
  u += 0x7fffu + ((u >> 16) & 1u);
  return (u16)(u >> 16);
}
__device__ __forceinline__ unsigned pkmul(unsigned a, unsigned b){
  float a0 = __uint_as_float(a << 16), a1 = __uint_as_float(a & 0xffff0000u);
  float b0 = __uint_as_float(b << 16), b1 = __uint_as_float(b & 0xffff0000u);
  float p0 = a0*b0, p1 = a1*b1;
  unsigned r;
  asm("v_cvt_pk_bf16_f32 %0, %1, %2" : "=v"(r) : "v"(p0), "v"(p1));
  return r;
}
// permuted feature layout [start512|end512|hemb256|wemb20|pad44] -> original source row
__device__ __forceinline__ int featsrc(int k){
  if (k < 1024) return k;
  if (k < 1280) return k + 20;
  if (k < 1300) return k - 256;
  return -1;
}
// BK=64 LDS: [rows][64] bf16. Stored slot s of row r holds source slot s^(r&7).
// staging: slot index S (=row*8+s): dest = S*8 (linear, gload_lds-compatible),
//          source k-elem offset within row = ((S&7)^((S>>3)&7))<<3
// read: fragment (half h, k8=l4) of row r at r*64 + ((((h<<2)|l4)^(r&7))<<3)
__device__ __forceinline__ int bsrc64(int S){
  return (((S & 7) ^ ((S >> 3) & 7)) << 3);
}
__device__ __forceinline__ int brd64(int row, int h, int k8){
  return row*64 + (((((h << 2) | k8)) ^ (row & 7)) << 3);
}
__device__ __forceinline__ void gload16(const u16* g, u16* l){
  __builtin_amdgcn_global_load_lds((const __attribute__((address_space(1))) void*)(g),
                                   (__attribute__((address_space(3))) void*)(l), 16, 0, 0);
}

// ---------------- prep: flat->bf16, padded wemb(20x64), permuted biases, selws zero ----------------
__global__ __launch_bounds__(256) void k_prep(const float* __restrict__ flat,
    const float* __restrict__ wemb, const float* __restrict__ fast_b, const float* __restrict__ gate_b,
    u16* __restrict__ flatbf, u16* __restrict__ wembP, float* __restrict__ fbP, float* __restrict__ gbP,
    unsigned* __restrict__ selws)
{
  int i = blockIdx.x*256 + threadIdx.x;
  if (i < T_LEN*FLATD) flatbf[i] = f2bf(flat[i]);
  if (i < 20*64) wembP[i] = ((i & 63) < 20) ? f2bf(wemb[(i >> 6)*FEATD + (i & 63)]) : (u16)0;
  if (i < KPAD){
    int s = featsrc(i);
    fbP[i] = (s >= 0) ? fast_b[s] : 0.f;
    gbP[i] = (s >= 0) ? gate_b[s] : 0.f;
  }
  if (i < 6156) selws[i] = 0;
}

// ---------------- head scores ----------------
__global__ __launch_bounds__(256) void k_head(const float* __restrict__ flat,
    const float* __restrict__ w, const float* __restrict__ b, float* __restrict__ hs)
{
  int lane = threadIdx.x & 63, wid = threadIdx.x >> 6;
  int row = blockIdx.x*4 + wid;
  if (row >= T_LEN) return;
  const float* x = flat + (size_t)row*FLATD;
  float s = 0.f;
  for (int j = lane; j < FLATD; j += 64) s += x[j]*w[j];
  #pragma unroll
  for (int o = 32; o; o >>= 1) s += __shfl_down(s, o, 64);
  if (lane == 0) hs[row] = s + b[0];
}

// ------------- per-candidate softmax head embedding -> bf16 (wave per candidate) -------------
__global__ __launch_bounds__(256) void k_cand(const float* __restrict__ hs,
    const float* __restrict__ hdoc, const int* __restrict__ starts, const int* __restrict__ ends,
    u16* __restrict__ hemb)
{
  int wid = threadIdx.x >> 6, lane = threadIdx.x & 63;
  int n = blockIdx.x*4 + wid;
  if (n >= NCAND) return;
  int s = starts[n], e = ends[n];
  int width = e - s + 1;
  float g[20];
  #pragma unroll
  for (int w2 = 0; w2 < 20; ++w2) g[w2] = (w2 < width) ? hs[min(s + w2, T_LEN-1)] : NEG_INF;
  float m = NEG_INF;
  #pragma unroll
  for (int w2 = 0; w2 < 20; ++w2) m = fmaxf(m, g[w2]);
  float sum = 0.f;
  #pragma unroll
  for (int w2 = 0; w2 < 20; ++w2){ g[w2] = expf(g[w2] - m); sum += g[w2]; }
  float inv = 1.f/sum;
  #pragma unroll
  for (int di = 0; di < 4; ++di){
    int d = lane + di*64;
    float acc = 0.f;
    #pragma unroll
    for (int w2 = 0; w2 < 20; ++w2)
      acc += g[w2]*hdoc[(size_t)min(s + w2, T_LEN-1)*HDD + d];
    hemb[(size_t)n*HDD + d] = f2bf(acc*inv);
  }
}

// ------------- batched weight transposes with feature permutation -------------
__global__ __launch_bounds__(256) void k_transall(const float* __restrict__ ms_w1,
    const float* __restrict__ ms_w2, const float* __restrict__ fast_w,
    const float* __restrict__ ss_w1, const float* __restrict__ ss_w2,
    const float* __restrict__ gate_w,
    u16* ms1T, u16* ms2T, u16* fastT, u16* ss1abT, u16* sspT,
    u16* ss2T, u16* gateTall)
{
  const float* B; u16* D; int Kb, N, srcN, ldD, kperm, nperm;
  switch (blockIdx.z){
    case 0: B = ms_w1; D = ms1T; Kb = KPAD; N = HIDD; srcN = HIDD; ldD = KPAD; kperm = 1; nperm = 0; break;
    case 1: B = ms_w2; D = ms2T; Kb = HIDD; N = HIDD; srcN = HIDD; ldD = HIDD; kperm = 0; nperm = 0; break;
    case 2: B = fast_w; D = fastT; Kb = KPAD; N = MENTD; srcN = MENTD; ldD = KPAD; kperm = 1; nperm = 1; break;
    case 3: B = ss_w1; D = ss1abT; Kb = KPAD; N = HIDD; srcN = HIDD; ldD = KPAD; kperm = 1; nperm = 0; break;
    case 4: B = ss_w1 + (size_t)MENTD*HIDD; D = ss1abT + (size_t)512*KPAD; Kb = KPAD; N = HIDD; srcN = HIDD; ldD = KPAD; kperm = 1; nperm = 0; break;
    case 5: B = ss_w1 + (size_t)2*MENTD*HIDD; D = sspT; Kb = KPAD; N = HIDD; srcN = HIDD; ldD = KPAD; kperm = 1; nperm = 0; break;
    case 6: B = ss_w2; D = ss2T; Kb = HIDD; N = HIDD; srcN = HIDD; ldD = HIDD; kperm = 0; nperm = 0; break;
    case 7: B = gate_w; D = gateTall; Kb = KPAD; N = MENTD; srcN = MENTD; ldD = 2*KPAD; kperm = 1; nperm = 1; break;
    default: B = gate_w + (size_t)MENTD*MENTD; D = gateTall + KPAD; Kb = KPAD; N = MENTD; srcN = MENTD; ldD = 2*KPAD; kperm = 1; nperm = 1; break;
  }
  int k0 = blockIdx.x*32, n0 = blockIdx.y*32;
  if (k0 >= Kb || n0 >= N) return;
  __shared__ float t[32][33];
  int tx = threadIdx.x & 31, ty = threadIdx.x >> 5;
  for (int r = ty; r < 32; r += 8){
    int gk = k0 + r, gn = n0 + tx;
    int sk = kperm ? featsrc(gk) : ((gk < Kb) ? gk : -1);
    int sn = nperm ? ((gn < N) ? featsrc(gn) : -1) : ((gn < N) ? gn : -1);
    t[r][tx] = (sk >= 0 && sn >= 0) ? B[(size_t)sk*srcN + sn] : 0.f;
  }
  __syncthreads();
  for (int r = ty; r < 32; r += 8){
    int gn = n0 + r, gk = k0 + tx;
    if (gn < N && gk < Kb) D[(size_t)gn*ldD + gk] = f2bf(t[tx][r]);
  }
}

// ------- mention-scorer layer1: A rows built on the fly, BK=64, gload_lds -------
__global__ __launch_bounds__(256) void k_mfma_cand(
    const u16* __restrict__ flatbf, const u16* __restrict__ hemb, const u16* __restrict__ wembP,
    const int* __restrict__ starts, const int* __restrict__ ends,
    const u16* __restrict__ Bt, int M, const float* __restrict__ bias, u16* __restrict__ Cbf)
{
  __shared__ alignas(16) u16 As[8192];
  __shared__ alignas(16) u16 Bs[8192];
  int tid = threadIdx.x;
  int row0 = blockIdx.y*128, col0 = blockIdx.x*128;
  int lane = tid & 63, wid = tid >> 6;
  int wr = wid >> 1, wc = wid & 1;
  int l15 = lane & 15, l4 = lane >> 4;

  int sS[4], eS[4], nS[4], so[4];
  const u16* pb[4];
  #pragma unroll
  for (int i = 0; i < 4; ++i){
    int S = tid + (i << 8);
    int r = S >> 3;
    so[i] = bsrc64(S);
    int n = row0 + r; if (n >= M) n = M - 1;
    sS[i] = starts[n]; eS[i] = ends[n]; nS[i] = n;
    pb[i] = Bt + (size_t)(col0 + r)*KPAD + so[i];
  }

  f32x4 acc[4][4];
  #pragma unroll
  for (int m = 0; m < 4; ++m)
    #pragma unroll
    for (int n = 0; n < 4; ++n)
      #pragma unroll
      for (int q = 0; q < 4; ++q) acc[m][n][q] = 0.f;

  for (int kt = 0; kt < KPAD/64; ++kt){
    int k0 = kt << 6;
    #pragma unroll
    for (int i = 0; i < 4; ++i){
      int f = k0 + so[i];
      const u16* src = (f < 512) ? flatbf + (size_t)sS[i]*FLATD + f
                     : (f < 1024) ? flatbf + (size_t)eS[i]*FLATD + (f - 512)
                     : (f < 1280) ? hemb + (size_t)nS[i]*HDD + (f - 1024)
                     : wembP + (eS[i] - sS[i])*64 + (f - 1280);
      gload16(src, As + (tid + (i << 8))*8);
      gload16(pb[i] + k0, Bs + (tid + (i << 8))*8);
    }
    __syncthreads();
    #pragma unroll
    for (int h = 0; h < 2; ++h){
      bf16x8 af[4], bfr[4];
      #pragma unroll
      for (int m = 0; m < 4; ++m) af[m] = *(const bf16x8*)(As + brd64(wr*64 + m*16 + l15, h, l4));
      #pragma unroll
      for (int n = 0; n < 4; ++n) bfr[n] = *(const bf16x8*)(Bs + brd64(wc*64 + n*16 + l15, h, l4));
      #pragma unroll
      for (int m = 0; m < 4; ++m)
        #pragma unroll
        for (int n = 0; n < 4; ++n)
          acc[m][n] = __builtin_amdgcn_mfma_f32_16x16x32_bf16(af[m], bfr[n], acc[m][n], 0, 0, 0);
    }
    __syncthreads();
  }
  #pragma unroll
  for (int m = 0; m < 4; ++m){
    #pragma unroll
    for (int q = 0; q < 4; ++q){
      int grow = row0 + wr*64 + m*16 + l4*4 + q;
      if (grow >= M) continue;
      #pragma unroll
      for (int n = 0; n < 4; ++n){
        int gcol = col0 + wc*64 + n*16 + l15;
        float v = fmaxf(acc[m][n][q] + bias[gcol], 0.f);
        Cbf[(size_t)grow*HIDD + gcol] = f2bf(v);
      }
    }
  }
}

// ---------------- generic bf16 MFMA GEMM, BK=64 (global_load_lds staging) ----------------
__global__ __launch_bounds__(256) void k_mfma(const u16* __restrict__ A,
    const u16* __restrict__ A2, const u16* __restrict__ Bt, int M, int N, int Kp, int ldA,
    const float* __restrict__ bias, const float* __restrict__ msc,
    float* __restrict__ Cf, int ldf, u16* __restrict__ Cbf, int ldbf, int Nstore, int flags,
    const u16* __restrict__ g_att, const u16* __restrict__ g_mo)
{
  __shared__ alignas(16) u16 As[8192];
  __shared__ alignas(16) u16 Bs[8192];
  int tid = threadIdx.x;
  int row0 = blockIdx.y*128, col0 = blockIdx.x*128;
  if ((flags & MF_MASK) && col0 >= row0 + 128) return;
  int lane = tid & 63, wid = tid >> 6;
  int wr = wid >> 1, wc = wid & 1;
  int l15 = lane & 15, l4 = lane >> 4;

  const u16 *pa[4], *qa[4], *pb[4];
  int kt1 = A2 ? (ldA >> 6) : (Kp >> 6);
  int koff = kt1 << 6;
  #pragma unroll
  for (int i = 0; i < 4; ++i){
    int S = tid + (i << 8);
    int r = S >> 3;
    int soi = bsrc64(S);
    int ra = row0 + r; if (ra >= M) ra = M - 1;
    int cb = col0 + r; if (cb >= N) cb = N - 1;
    pa[i] = A + (size_t)ra*ldA + soi;
    qa[i] = A2 ? (A2 + (size_t)ra*ldA + soi - koff) : pa[i];
    pb[i] = Bt + (size_t)cb*Kp + soi;
  }

  f32x4 acc[4][4];
  #pragma unroll
  for (int m = 0; m < 4; ++m)
    #pragma unroll
    for (int n = 0; n < 4; ++n)
      #pragma unroll
      for (int q = 0; q < 4; ++q) acc[m][n][q] = 0.f;

  int nkt = Kp >> 6;
  for (int kt = 0; kt < nkt; ++kt){
    int k0 = kt << 6;
    #pragma unroll
    for (int i = 0; i < 4; ++i){
      const u16* a = (kt < kt1) ? pa[i] : qa[i];
      gload16(a + k0, As + (tid + (i << 8))*8);
      gload16(pb[i] + k0, Bs + (tid + (i << 8))*8);
    }
    __syncthreads();
    #pragma unroll
    for (int h = 0; h < 2; ++h){
      bf16x8 af[4], bfr[4];
      #pragma unroll
      for (int m = 0; m < 4; ++m) af[m] = *(const bf16x8*)(As + brd64(wr*64 + m*16 + l15, h, l4));
      #pragma unroll
      for (int n = 0; n < 4; ++n) bfr[n] = *(const bf16x8*)(Bs + brd64(wc*64 + n*16 + l15, h, l4));
      #pragma unroll
      for (int m = 0; m < 4; ++m)
        #pragma unroll
        for (int n = 0; n < 4; ++n)
          acc[m][n] = __builtin_amdgcn_mfma_f32_16x16x32_bf16(af[m], bfr[n], acc[m][n], 0, 0, 0);
    }
    __syncthreads();
  }
  #pragma unroll
  for (int m = 0; m < 4; ++m){
    #pragma unroll
    for (int q = 0; q < 4; ++q){
      int grow = row0 + wr*64 + m*16 + l4*4 + q;
      if (grow >= M) continue;
      #pragma unroll
      for (int n = 0; n < 4; ++n){
        int gcol = col0 + wc*64 + n*16 + l15;
        if (gcol < N){
          float v = acc[m][n][q];
          if (bias) v += bias[gcol];
          if (flags & MF_MASK){ v += msc[grow] + msc[gcol]; if (gcol >= grow) v = NEG_INF; }
          if (flags & MF_RELU) v = fmaxf(v, 0.f);
          if (flags & MF_GATE){
            float f = 1.f/(1.f + expf(-v));
            float res = f*bf2f(g_att[(size_t)grow*ldbf + gcol])
                      + (1.f - f)*bf2f(g_mo[(size_t)grow*ldbf + gcol]);
            Cbf[(size_t)grow*ldbf + gcol] = f2bf(res);
          } else {
            if (Cf)  Cf[(size_t)grow*ldf + gcol] = v;
            if (Cbf) Cbf[(size_t)grow*ldbf + gcol] = f2bf(v);
          }
        } else if (Cbf && gcol < Nstore){
          Cbf[(size_t)grow*ldbf + gcol] = 0;
        }
      }
    }
  }
}

// ---- fused layer2 + w3 dot, full row per block, BK=64 ----
__global__ __launch_bounds__(256) void k_mfma_rowdot(const u16* __restrict__ A,
    const u16* __restrict__ Bt, int M, const float* __restrict__ b2,
    const float* __restrict__ w3, const float* __restrict__ b3,
    const float* __restrict__ add, float* __restrict__ out)
{
  __shared__ alignas(16) u16 As[8192];
  __shared__ alignas(16) u16 Bs[8192];
  __shared__ float rsum[128][2];
  int tid = threadIdx.x;
  int row0 = blockIdx.x*128;
  int lane = tid & 63, wid = tid >> 6;
  int wr = wid >> 1, wc = wid & 1;
  int l15 = lane & 15, l4 = lane >> 4;

  const u16* pa[4]; int so[4], rr[4];
  #pragma unroll
  for (int i = 0; i < 4; ++i){
    int S = tid + (i << 8);
    int r = S >> 3;
    so[i] = bsrc64(S); rr[i] = r;
    int ra = row0 + r; if (ra >= M) ra = M - 1;
    pa[i] = A + (size_t)ra*HIDD + so[i];
  }

  float rd[4][4] = {};
  for (int p = 0; p < 4; ++p){
    int col0 = p*128;
    f32x4 acc[4][4];
    #pragma unroll
    for (int m = 0; m < 4; ++m)
      #pragma unroll
      for (int n = 0; n < 4; ++n)
        #pragma unroll
        for (int q = 0; q < 4; ++q) acc[m][n][q] = 0.f;
    for (int kt = 0; kt < HIDD/64; ++kt){
      int k0 = kt << 6;
      #pragma unroll
      for (int i = 0; i < 4; ++i){
        gload16(pa[i] + k0, As + (tid + (i << 8))*8);
        gload16(Bt + (size_t)(col0 + rr[i])*HIDD + so[i] + k0, Bs + (tid + (i << 8))*8);
      }
      __syncthreads();
      #pragma unroll
      for (int h = 0; h < 2; ++h){
        bf16x8 af[4], bfr[4];
        #pragma unroll
        for (int m = 0; m < 4; ++m) af[m] = *(const bf16x8*)(As + brd64(wr*64 + m*16 + l15, h, l4));
        #pragma unroll
        for (int n = 0; n < 4; ++n) bfr[n] = *(const bf16x8*)(Bs + brd64(wc*64 + n*16 + l15, h, l4));
        #pragma unroll
        for (int m = 0; m < 4; ++m)
          #pragma unroll
          for (int n = 0; n < 4; ++n)
            acc[m][n] = __builtin_amdgcn_mfma_f32_16x16x32_bf16(af[m], bfr[n], acc[m][n], 0, 0, 0);
      }
      __syncthreads();
    }
    #pragma unroll
    for (int n = 0; n < 4; ++n){
      int gcol = col0 + wc*64 + n*16 + l15;
      float bb = b2[gcol], ww = w3[gcol];
      #pragma unroll
      for (int m = 0; m < 4; ++m)
        #pragma unroll
        for (int q = 0; q < 4; ++q){
          float v = fmaxf(acc[m][n][q] + bb, 0.f);
          rd[m][q] = fmaf(v, ww, rd[m][q]);
        }
    }
  }
  #pragma unroll
  for (int m = 0; m < 4; ++m)
    #pragma unroll
    for (int q = 0; q < 4; ++q){
      float s = rd[m][q];
      s += __shfl_xor(s, 1, 64); s += __shfl_xor(s, 2, 64);
      s += __shfl_xor(s, 4, 64); s += __shfl_xor(s, 8, 64);
      if (l15 == 0) rsum[wr*64 + m*16 + l4*4 + q][wc] = s;
    }
  __syncthreads();
  if (tid < 128){
    int gr = row0 + tid;
    if (gr < M){
      float v = rsum[tid][0] + rsum[tid][1] + b3[0];
      if (add) v += add[gr];
      out[gr] = v;
    }
  }
}

// ------- pair layer1 MFMA: 128x256 tile, BK=64, on-the-fly product A -------
__global__ __launch_bounds__(256, 2) void k_d1_mfma(int Mc,
    const u16* __restrict__ ment, const int* __restrict__ antes, const int* __restrict__ mspk,
    const u16* __restrict__ Bt, const float* __restrict__ A_meb,
    const float* __restrict__ comb, u16* __restrict__ H1)
{
  __shared__ alignas(16) u16 As[8192];    // 128 rows x 64
  __shared__ alignas(16) u16 Bs[16384];   // 256 cols x 64
  __shared__ int ri[128], rj[128], rcomb[128];
  int tid = threadIdx.x;
  int row0 = blockIdx.y*128;
  int col0 = blockIdx.x*256;
  if (tid < 128){
    int r = row0 + tid;
    int p = (r < Mc ? r : 0);
    int i = p / CANT;
    int j = antes[p];
    ri[tid] = i; rj[tid] = j;
    int same = (mspk[i] == mspk[j]) ? 1 : 0;
    int d = i - j; d = d < 0 ? 0 : (d > 64 ? 64 : d);
    int bin = (d <= 4) ? d : (d <= 8 ? 5 : (d <= 16 ? 6 : (d <= 32 ? 7 : 8)));
    rcomb[tid] = same*9 + bin;
  }
  __syncthreads();
  int lane = tid & 63, wid = tid >> 6;
  int wr = wid >> 1, wc = wid & 1;
  int l15 = lane & 15, l4 = lane >> 4;

  // A: 128x64 -> 1024 slots -> 4/thread (with product); B: 256x64 -> 2048 slots -> 8/thread
  const u16 *pi[4], *pj[4];
  #pragma unroll
  for (int i = 0; i < 4; ++i){
    int S = tid + (i << 8);
    int r = S >> 3;
    int soi = bsrc64(S);
    pi[i] = ment + (size_t)ri[r]*KPAD + soi;
    pj[i] = ment + (size_t)rj[r]*KPAD + soi;
  }
  int bo[8];
  #pragma unroll
  for (int i = 0; i < 8; ++i){
    int S = tid + (i << 8);
    int r = S >> 3;
    bo[i] = (col0 + r)*KPAD + bsrc64(S);
  }

  f32x4 acc[4][8];
  #pragma unroll
  for (int m = 0; m < 4; ++m)
    #pragma unroll
    for (int n = 0; n < 8; ++n)
      #pragma unroll
      for (int q = 0; q < 4; ++q) acc[m][n][q] = 0.f;

  int nkt = KPAD >> 6;
  for (int kt = 0; kt < nkt; ++kt){
    int k0 = kt << 6;
    #pragma unroll
    for (int i = 0; i < 8; ++i)
      gload16(Bt + bo[i] + k0, Bs + (tid + (i << 8))*8);
    #pragma unroll
    for (int i = 0; i < 4; ++i){
      uint4 va = *(const uint4*)(pi[i] + k0);
      uint4 vb = *(const uint4*)(pj[i] + k0);
      uint4 vo;
      vo.x = pkmul(va.x, vb.x); vo.y = pkmul(va.y, vb.y);
      vo.z = pkmul(va.z, vb.z); vo.w = pkmul(va.w, vb.w);
      *(uint4*)(As + (tid + (i << 8))*8) = vo;
    }
    __syncthreads();
    #pragma unroll
    for (int h = 0; h < 2; ++h){
      bf16x8 af[4];
      #pragma unroll
      for (int m = 0; m < 4; ++m) af[m] = *(const bf16x8*)(As + brd64(wr*64 + m*16 + l15, h, l4));
      #pragma unroll
      for (int n = 0; n < 8; ++n){
        bf16x8 bfr = *(const bf16x8*)(Bs + brd64(wc*128 + n*16 + l15, h, l4));
        #pragma unroll
        for (int m = 0; m < 4; ++m)
          acc[m][n] = __builtin_amdgcn_mfma_f32_16x16x32_bf16(af[m], bfr, acc[m][n], 0, 0, 0);
      }
    }
    __syncthreads();
  }
  #pragma unroll
  for (int m = 0; m < 4; ++m){
    #pragma unroll
    for (int q = 0; q < 4; ++q){
      int rl = wr*64 + m*16 + l4*4 + q;
      int grow = row0 + rl;
      if (grow >= Mc) continue;
      const float* me = A_meb + (size_t)ri[rl]*1024;
      const float* an = A_meb + (size_t)rj[rl]*1024 + 512;
      const float* cb = comb + (size_t)rcomb[rl]*HIDD;
      #pragma unroll
      for (int n = 0; n < 8; ++n){
        int gcol = col0 + wc*128 + n*16 + l15;
        float v = acc[m][n][q] + me[gcol] + an[gcol] + cb[gcol];
        H1[(size_t)grow*HIDD + gcol] = f2bf(fmaxf(v, 0.f));
      }
    }
  }
}

// ================= top-K selection pipeline (multi-kernel, multi-CU) =================
__global__ __launch_bounds__(256) void k_hist(const float* __restrict__ scores,
    unsigned* __restrict__ selws, int pass)
{
  int n = blockIdx.x*256 + threadIdx.x;
  if (n >= NCAND) return;
  unsigned u = ordf(scores[n]);
  const unsigned* meta = selws + 6144;
  if (pass == 0) atomicAdd(&selws[u >> 21], 1u);
  else if (pass == 1){ if ((u >> 21) == meta[0]) atomicAdd(&selws[2048 + ((u >> 10) & 0x7FFu)], 1u); }
  else { if ((u >> 10) == meta[2]) atomicAdd(&selws[4096 + (u & 0x3FFu)], 1u); }
}
__global__ __launch_bounds__(1024) void k_thresh(unsigned* __restrict__ selws, int mode){
  __shared__ unsigned a[2048], b[2048];
  int tid = threadIdx.x;
  unsigned* meta = selws + 6144;
  const unsigned* gbin = selws + (mode == 0 ? 0 : (mode == 1 ? 2048 : 4096));
  unsigned target = (mode == 0) ? (unsigned)KSEL : meta[mode == 1 ? 1 : 3];
  a[tid] = gbin[tid]; a[tid + 1024] = gbin[tid + 1024];
  unsigned *src = a, *dst = b;
  for (int step = 1; step < 2048; step <<= 1){
    __syncthreads();
    for (int i = tid; i < 2048; i += 1024)
      dst[i] = src[i] + ((i + step < 2048) ? src[i + step] : 0u);
    unsigned* t2 = src; src = dst; dst = t2;
  }
  __syncthreads();
  for (int i = tid; i < 2048; i += 1024){
    unsigned si = src[i], sn = (i < 2047) ? src[i+1] : 0u;
    if (si >= target && sn < target){
      if (mode == 0){ meta[0] = (unsigned)i; meta[1] = target - sn; }
      else if (mode == 1){ meta[2] = (meta[0] << 11) | (unsigned)i; meta[3] = target - sn; }
      else { meta[4] = (meta[2] << 10) | (unsigned)i; meta[5] = target - sn; }
    }
  }
}
__global__ __launch_bounds__(256) void k_compact(const float* __restrict__ scores,
    unsigned* __restrict__ selws, int* __restrict__ g_sel, unsigned* __restrict__ g_eq)
{
  int n = blockIdx.x*256 + threadIdx.x;
  if (n >= NCAND) return;
  unsigned kth = selws[6144 + 4];
  unsigned* cnt = selws + 6152;
  unsigned u = ordf(scores[n]);
  if (u > kth){ unsigned p = atomicAdd(&cnt[0], 1u); g_sel[p] = n; }
  else if (u == kth){ unsigned p = atomicAdd(&cnt[1], 1u); if (p < 1024) g_eq[p] = (unsigned)n; }
}
__global__ __launch_bounds__(1024) void k_eqrank(unsigned* __restrict__ selws,
    const unsigned* __restrict__ g_eq, int* __restrict__ g_sel)
{
  __shared__ unsigned eq[1024];
  int tid = threadIdx.x;
  unsigned neq = selws[6152 + 1]; if (neq > 1024u) neq = 1024u;
  unsigned E = selws[6144 + 5];
  unsigned G = selws[6152 + 0];
  eq[tid] = (tid < (int)neq) ? g_eq[tid] : 0xFFFFFFFFu;
  __syncthreads();
  if (tid < (int)neq){
    unsigned mine = eq[tid]; unsigned r = 0;
    for (unsigned j = 0; j < neq; ++j) r += (eq[j] < mine) ? 1u : 0u;
    if (r < E) g_sel[G + r] = (int)mine;
  }
}
__global__ __launch_bounds__(256) void k_rank1(const float* __restrict__ scores,
    const int* __restrict__ g_sel, int* __restrict__ ranked)
{
  __shared__ unsigned long long key[KSEL];
  int tid = threadIdx.x;
  for (int t = tid; t < KSEL; t += 256){
    int n = g_sel[t];
    key[t] = ((unsigned long long)(~ordf(scores[n])) << 32) | (unsigned)n;
  }
  __syncthreads();
  int t = blockIdx.x*256 + tid;
  if (t >= KSEL) return;
  unsigned long long mine = key[t];
  int r = 0;
  #pragma unroll 16
  for (int j = 0; j < KSEL; ++j) r += (key[j] < mine) ? 1 : 0;
  ranked[r] = (int)(mine & 0xFFFFFFFFu);
}
__global__ __launch_bounds__(256) void k_rank2(const int* __restrict__ ranked,
    const int* __restrict__ starts, const int* __restrict__ ends, int* __restrict__ top_idx)
{
  __shared__ unsigned long long key[KSEL];
  int tid = threadIdx.x;
  int elast = ends[NCAND-1];
  for (int t = tid; t < KSEL; t += 256){
    int n = ranked[t];
    unsigned mp = (unsigned)(starts[n]*elast + ends[n]);
    key[t] = ((unsigned long long)mp << 11) | (unsigned)t;
  }
  __syncthreads();
  int t = blockIdx.x*256 + tid;
  if (t >= KSEL) return;
  unsigned long long mine = key[t];
  int r = 0;
  #pragma unroll 16
  for (int j = 0; j < KSEL; ++j) r += (key[j] < mine) ? 1 : 0;
  top_idx[r] = ranked[t];
}

// ---------------- gather mention rows -> bf16 [KSEL][KPAD], permuted layout ----------------
__global__ __launch_bounds__(256) void k_gather(const int* __restrict__ top_idx,
    const u16* __restrict__ flatbf, const u16* __restrict__ hemb, const u16* __restrict__ wembP,
    const int* __restrict__ starts, const int* __restrict__ ends,
    const float* __restrict__ cscores, const int* __restrict__ spk_ids,
    u16* __restrict__ ment, float* __restrict__ mscore, int* __restrict__ mspk)
{
  int k = blockIdx.x; int n = top_idx[k];
  int s = starts[n], e = ends[n];
  int v = threadIdx.x;
  if (v < KPAD/8){
    int f0 = v*8;
    const u16* src = (f0 < 512) ? flatbf + (size_t)s*FLATD + f0
                   : (f0 < 1024) ? flatbf + (size_t)e*FLATD + (f0 - 512)
                   : (f0 < 1280) ? hemb + (size_t)n*HDD + (f0 - 1024)
                   : wembP + (e - s)*64 + (f0 - 1280);
    *(uint4*)(ment + (size_t)k*KPAD + f0) = *(const uint4*)src;
  }
  if (threadIdx.x == 0){ mscore[k] = cscores[n]; mspk[k] = spk_ids[s]; }
}

// ---------------- per-row top-40, wave-per-row, register keys ----------------
__global__ __launch_bounds__(256) void k_f3(const float* __restrict__ fast,
    float* __restrict__ top_fast, int* __restrict__ antes)
{
  int wid = threadIdx.x >> 6, lane = threadIdx.x & 63;
  int i = blockIdx.x*4 + wid;
  if (i >= KSEL) return;
  const float* row = fast + (size_t)i*KSEL;
  unsigned long long key[26];
  #pragma unroll
  for (int t = 0; t < 26; ++t){
    int j = lane + (t << 6);
    unsigned long long k2 = 0ULL;
    if (j < i) k2 = ((unsigned long long)ordf(row[j]) << 32) | (unsigned)(0xFFFFFFFFu - (unsigned)j);
    key[t] = k2;
  }
  for (int c = 0; c < CANT; ++c){
    unsigned long long m = 0ULL;
    #pragma unroll
    for (int t = 0; t < 26; ++t) if (key[t] > m) m = key[t];
    #pragma unroll
    for (int o = 32; o; o >>= 1){
      unsigned long long v = __shfl_xor(m, o, 64);
      if (v > m) m = v;
    }
    if (m){
      #pragma unroll
      for (int t = 0; t < 26; ++t) if (key[t] == m) key[t] = 0ULL;
    }
    if (lane == 0){
      if (m){
        top_fast[(size_t)i*CANT + c] = unordf((unsigned)(m >> 32));
        antes[(size_t)i*CANT + c]    = (int)(0xFFFFFFFFu - (unsigned)(m & 0xFFFFFFFFu));
      } else {
        top_fast[(size_t)i*CANT + c] = NEG_INF;
        antes[(size_t)i*CANT + c]    = c;
      }
    }
  }
}

// ------- comb[same*9+bin][512]: (spk+genre+dist) rows through ss_w1 + b1, pre-summed -------
__global__ __launch_bounds__(256) void k_dsmall(const float* __restrict__ ss_w1,
    const float* __restrict__ ss_b1, const float* __restrict__ spk_emb,
    const float* __restrict__ gen_emb, const float* __restrict__ dist_emb,
    const int* __restrict__ genre_id, float* __restrict__ comb)
{
  int r = blockIdx.x;             // 0..17
  int same = r / 9, bin = r % 9;
  const float* es = spk_emb + same*FEATD;
  const float* eg = gen_emb + genre_id[0]*FEATD;
  const float* ed = dist_emb + bin*FEATD;
  for (int h = threadIdx.x; h < HIDD; h += 256){
    float acc = ss_b1[h];
    const float* ws_ = ss_w1 + (size_t)3900*HIDD + h;
    const float* wg  = ss_w1 + (size_t)3920*HIDD + h;
    const float* wd  = ss_w1 + (size_t)3940*HIDD + h;
    for (int f = 0; f < FEATD; ++f){
      acc += es[f]*ws_[(size_t)f*HIDD];
      acc += eg[f]*wg[(size_t)f*HIDD];
      acc += ed[f]*wd[(size_t)f*HIDD];
    }
    comb[(size_t)r*HIDD + h] = acc;
  }
}

// ---------------- softmax over [0, ante_scores] + attended -> bf16 (vectorized) ----------------
__global__ __launch_bounds__(256) void k_d4a(const float* __restrict__ ante_sc,
    const int* __restrict__ antes, const u16* __restrict__ ment, u16* __restrict__ att_bf)
{
  int i = blockIdx.x;
  __shared__ float w[CANT+1];
  __shared__ int aj[CANT];
  if (threadIdx.x == 0){
    float s[CANT]; float m = 0.f;
    #pragma unroll
    for (int c = 0; c < CANT; ++c){ s[c] = ante_sc[i*CANT + c]; m = fmaxf(m, s[c]); }
    float e0 = expf(0.f - m);
    float sum = e0;
    float ex[CANT];
    #pragma unroll
    for (int c = 0; c < CANT; ++c){ ex[c] = expf(s[c] - m); sum += ex[c]; }
    float inv = 1.f/sum;
    w[0] = e0*inv;
    #pragma unroll
    for (int c = 0; c < CANT; ++c) w[c+1] = ex[c]*inv;
  }
  if (threadIdx.x < CANT) aj[threadIdx.x] = antes[i*CANT + threadIdx.x];
  __syncthreads();
  int v = threadIdx.x;
  if (v >= KPAD/8) return;
  int d0 = v*8;
  float r[8] = {};
  {
    uint4 x = *(const uint4*)(ment + (size_t)i*KPAD + d0);
    float w0 = w[0];
    const unsigned* px = (const unsigned*)&x;
    #pragma unroll
    for (int h = 0; h < 4; ++h){
      r[2*h]   = w0*__uint_as_float(px[h] << 16);
      r[2*h+1] = w0*__uint_as_float(px[h] & 0xffff0000u);
    }
  }
  for (int c = 0; c < CANT; ++c){
    uint4 x = *(const uint4*)(ment + (size_t)aj[c]*KPAD + d0);
    float wc_ = w[c+1];
    const unsigned* px = (const unsigned*)&x;
    #pragma unroll
    for (int h = 0; h < 4; ++h){
      r[2*h]   = fmaf(wc_, __uint_as_float(px[h] << 16), r[2*h]);
      r[2*h+1] = fmaf(wc_, __uint_as_float(px[h] & 0xffff0000u), r[2*h+1]);
    }
  }
  u16 o[8];
  #pragma unroll
  for (int h = 0; h < 8; ++h) o[h] = f2bf(r[h]);
  *(uint4*)(att_bf + (size_t)i*KPAD + d0) = *(const uint4*)o;
}

// ---------------- final output (sanitize non-finite) ----------------
__global__ __launch_bounds__(256) void k_out(const float* __restrict__ ante_sc, float* __restrict__ out){
  int idx = blockIdx.x*256 + threadIdx.x;
  if (idx >= KSEL*41) return;
  int i = idx / 41, c = idx % 41;
  float v = (c == 0) ? 0.f : ante_sc[i*CANT + (c-1)];
  if (!isfinite(v)) v = -3.0e38f;
  out[idx] = v;
}

__global__ void k_zero(float* out, int n){
  int i = blockIdx.x*256 + threadIdx.x;
  if (i < n) out[i] = 0.f;
}

extern "C" void kernel_launch(void* const* d_in, const int* in_sizes, int n_in,
                              void* d_out, int out_size, void* d_ws, size_t ws_size,
                              hipStream_t stream)
{
  const float* flat   = (const float*)d_in[0];
  const float* hdoc   = (const float*)d_in[1];
  const float* w_head = (const float*)d_in[2];
  const float* b_head = (const float*)d_in[3];
  const float* wemb   = (const float*)d_in[4];
  const float* ms_w1  = (const float*)d_in[5];
  const float* ms_b1  = (const float*)d_in[6];
  const float* ms_w2  = (const float*)d_in[7];
  const float* ms_b2  = (const float*)d_in[8];
  const float* ms_w3  = (const float*)d_in[9];
  const float* ms_b3  = (const float*)d_in[10];
  const float* fast_w = (const float*)d_in[11];
  const float* fast_b = (const float*)d_in[12];
  const float* ss_w1  = (const float*)d_in[13];
  const float* ss_b1  = (const float*)d_in[14];
  const float* ss_w2  = (const float*)d_in[15];
  const float* ss_b2  = (const float*)d_in[16];
  const float* ss_w3  = (const float*)d_in[17];
  const float* ss_b3  = (const float*)d_in[18];
  const float* gate_w = (const float*)d_in[19];
  const float* gate_b = (const float*)d_in[20];
  const float* spk_e  = (const float*)d_in[21];
  const float* gen_e  = (const float*)d_in[22];
  const float* dist_e = (const float*)d_in[23];
  const int* starts   = (const int*)d_in[24];
  const int* ends     = (const int*)d_in[25];
  const int* spk_ids  = (const int*)d_in[26];
  const int* genre_id = (const int*)d_in[27];
  float* out = (float*)d_out;

  size_t off = 0;
  char* base = (char*)d_ws;
  auto alloc = [&](size_t nbytes) -> void* {
    void* p = (void*)(base + off);
    off += ((nbytes + 255)/256)*256;
    return p;
  };
  float* head_sc = (float*)alloc((size_t)T_LEN*4);
  u16*   flatbf  = (u16*)alloc((size_t)T_LEN*FLATD*2);
  u16*   wembP   = (u16*)alloc((size_t)20*64*2);
  float* fbP     = (float*)alloc((size_t)KPAD*4);
  float* gbP     = (float*)alloc((size_t)KPAD*4);
  u16*   hemb    = (u16*)alloc((size_t)NCAND*HDD*2);
  float* cscores = (float*)alloc((size_t)NCAND*4);
  int*   top_idx = (int*)alloc(2048*4);
  unsigned* selws= (unsigned*)alloc(6160*4);
  int*   g_sel   = (int*)alloc((size_t)KSEL*4);
  unsigned* g_eq = (unsigned*)alloc(1024*4);
  int*   g_rank  = (int*)alloc((size_t)KSEL*4);
  u16*   ms1T    = (u16*)alloc((size_t)HIDD*KPAD*2);
  u16*   ms2T    = (u16*)alloc((size_t)HIDD*HIDD*2);
  u16*   fastT   = (u16*)alloc((size_t)MENTD*KPAD*2);
  u16*   ss1abT  = (u16*)alloc((size_t)1024*KPAD*2);
  u16*   sspT    = (u16*)alloc((size_t)HIDD*KPAD*2);
  u16*   ss2T    = (u16*)alloc((size_t)HIDD*HIDD*2);
  u16*   gateTall= (u16*)alloc((size_t)MENTD*2*KPAD*2);
  u16*   ment    = (u16*)alloc((size_t)KSEL*KPAD*2);
  u16*   mentB   = (u16*)alloc((size_t)KSEL*KPAD*2);
  u16*   srcb    = (u16*)alloc((size_t)KSEL*KPAD*2);
  float* mscore  = (float*)alloc((size_t)KSEL*4);
  int*   mspk    = (int*)alloc((size_t)KSEL*4);
  float* fastm   = (float*)alloc((size_t)KSEL*KSEL*4);
  float* top_fast= (float*)alloc((size_t)NPAIR*4);
  int*   antes   = (int*)alloc((size_t)NPAIR*4);
  float* ante_sc = (float*)alloc((size_t)NPAIR*4);
  float* A_meb   = (float*)alloc((size_t)KSEL*1024*4);
  float* comb    = (float*)alloc((size_t)18*HIDD*4);
  u16*   att_bf  = (u16*)alloc((size_t)KSEL*KPAD*2);
  u16*   bufH1   = (u16*)alloc((size_t)NPAIR*HIDD*2);

  if (ws_size < off){
    k_zero<<<(KSEL*41 + 255)/256, 256, 0, stream>>>(out, KSEL*41);
    return;
  }

  k_prep<<<(T_LEN*FLATD + 255)/256, 256, 0, stream>>>(flat, wemb, fast_b, gate_b,
                                                      flatbf, wembP, fbP, gbP, selws);
  k_transall<<<dim3(KPAD/32, 41, 9), 256, 0, stream>>>(ms_w1, ms_w2, fast_w, ss_w1, ss_w2, gate_w,
      ms1T, ms2T, fastT, ss1abT, sspT, ss2T, gateTall);

  k_head<<<T_LEN/4, 256, 0, stream>>>(flat, w_head, b_head, head_sc);
  k_cand<<<NCAND/4, 256, 0, stream>>>(head_sc, hdoc, starts, ends, hemb);

  // mention scorer (single pass over 30000 rows)
  k_mfma_cand<<<dim3(HIDD/128, (NCAND + 127)/128), 256, 0, stream>>>(
      flatbf, hemb, wembP, starts, ends, ms1T, NCAND, ms_b1, bufH1);
  k_mfma_rowdot<<<(NCAND + 127)/128, 256, 0, stream>>>(bufH1, ms2T, NCAND, ms_b2, ms_w3, ms_b3,
                                                       nullptr, cscores);

  // top-K selection pipeline
  k_hist<<<(NCAND + 255)/256, 256, 0, stream>>>(cscores, selws, 0);
  k_thresh<<<1, 1024, 0, stream>>>(selws, 0);
  k_hist<<<(NCAND + 255)/256, 256, 0, stream>>>(cscores, selws, 1);
  k_thresh<<<1, 1024, 0, stream>>>(selws, 1);
  k_hist<<<(NCAND + 255)/256, 256, 0, stream>>>(cscores, selws, 2);
  k_thresh<<<1, 1024, 0, stream>>>(selws, 2);
  k_compact<<<(NCAND + 255)/256, 256, 0, stream>>>(cscores, selws, g_sel, g_eq);
  k_eqrank<<<1, 1024, 0, stream>>>(selws, g_eq, g_sel);
  k_rank1<<<(KSEL + 255)/256, 256, 0, stream>>>(cscores, g_sel, g_rank);
  k_rank2<<<(KSEL + 255)/256, 256, 0, stream>>>(g_rank, starts, ends, top_idx);

  k_gather<<<KSEL, 256, 0, stream>>>(top_idx, flatbf, hemb, wembP, starts, ends, cscores, spk_ids,
                                     ment, mscore, mspk);

  // fast antecedent scores
  k_mfma<<<dim3((MENTD+127)/128, (KSEL+127)/128), 256, 0, stream>>>(
      ment, nullptr, fastT, KSEL, MENTD, KPAD, KPAD, fbP, nullptr,
      nullptr, 0, srcb, KPAD, KPAD, 0, nullptr, nullptr);
  k_mfma<<<dim3((KSEL+127)/128, (KSEL+127)/128), 256, 0, stream>>>(
      srcb, nullptr, ment, KSEL, KSEL, KPAD, KPAD, nullptr, mscore,
      fastm, KSEL, nullptr, 0, 0, MF_MASK, nullptr, nullptr);
  k_f3<<<(KSEL+3)/4, 256, 0, stream>>>(fastm, top_fast, antes);

  k_dsmall<<<18, 256, 0, stream>>>(ss_w1, ss_b1, spk_e, gen_e, dist_e, genre_id, comb);

  const u16* mcur = ment;
  for (int iter = 0; iter < 2; ++iter){
    k_mfma<<<dim3(8, (KSEL+127)/128), 256, 0, stream>>>(
        mcur, nullptr, ss1abT, KSEL, 1024, KPAD, KPAD, nullptr, nullptr,
        A_meb, 1024, nullptr, 0, 0, 0, nullptr, nullptr);
    k_d1_mfma<<<dim3(2, (NPAIR + 127)/128), 256, 0, stream>>>(
        NPAIR, mcur, antes, mspk, sspT, A_meb, comb, bufH1);
    k_mfma_rowdot<<<(NPAIR + 127)/128, 256, 0, stream>>>(bufH1, ss2T, NPAIR, ss_b2, ss_w3, ss_b3,
                                                         top_fast, ante_sc);
    if (iter == 0){
      k_d4a<<<KSEL, 256, 0, stream>>>(ante_sc, antes, mcur, att_bf);
      k_mfma<<<dim3((MENTD+127)/128, (KSEL+127)/128), 256, 0, stream>>>(
          ment, att_bf, gateTall, KSEL, MENTD, 2*KPAD, KPAD, gbP, nullptr,
          nullptr, 0, mentB, KPAD, KPAD, MF_GATE, att_bf, ment);
      mcur = mentB;
    }
  }

  k_out<<<(KSEL*41 + 255)/256, 256, 0, stream>>>(ante_sc, out);
}